// Round 1
// baseline (4582.858 us; speedup 1.0000x reference)
//
#include <hip/hip_runtime.h>
#include <cstdint>
#include <cstddef>

#define DEV __device__ __forceinline__

DEV float gelu_f(float x) { return 0.5f * x * (1.0f + erff(x * 0.70710678118654752f)); }

// ---------------------------------------------------------------------------
// Generic tiled fp32 GEMM: C[M,N] = A[M,K] @ B (+bias)(+gelu)(+res)(+pos)
//   BT=false: B stored [K][N]; BT=true: B stored [N][K] (i.e. computes A@B^T)
//   PATCH: A elements gathered from images [B,512,512,3] (ViT unfold)
//   SPLITK: grid.z splits K into chunks; partials written to C + z*M*N
// ---------------------------------------------------------------------------
template<int BM, int BN, int BK, int TM, int TN,
         bool BT, bool PATCH, bool BIAS, bool GELU, bool RES, bool POS, bool SPLITK>
__global__ __launch_bounds__(256)
void gemm_kernel(const float* __restrict__ A, const float* __restrict__ B,
                 float* __restrict__ C, const float* __restrict__ bias,
                 const float* __restrict__ res, const float* __restrict__ pos,
                 int M, int N, int K, int kchunk)
{
    constexpr int TX = BN / TN;
    constexpr int TY = BM / TM;
    static_assert(TX * TY == 256, "bad tile config");

    __shared__ float As[BK][BM + 4];
    __shared__ float Bs[BK][BN + 4];

    const int tid = threadIdx.x;
    const int tx  = tid % TX;
    const int ty  = tid / TX;
    const int bn0 = blockIdx.x * BN;
    const int bm0 = blockIdx.y * BM;

    int kstart = 0, kend = K;
    if (SPLITK) { kstart = blockIdx.z * kchunk; kend = kstart + kchunk; }

    float acc[TM][TN];
#pragma unroll
    for (int i = 0; i < TM; ++i)
#pragma unroll
        for (int j = 0; j < TN; ++j) acc[i][j] = 0.f;

    for (int k0 = kstart; k0 < kend; k0 += BK) {
        __syncthreads();
        // ---- stage A tile ----
        if constexpr (PATCH) {
            constexpr int AE = BM * BK / 256;
#pragma unroll
            for (int r = 0; r < AE; ++r) {
                int idx = tid + r * 256;
                int kk = idx % BK;
                int mm = idx / BK;
                int m = bm0 + mm;
                int k = k0 + kk;
                int bb = m >> 8, n = m & 255;
                int ph = k / 96, rem = k - ph * 96;
                int pw = rem / 3, c = rem - pw * 3;
                int prow = ((n >> 4) << 5) + ph;
                int pcol = ((n & 15) << 5) + pw;
                As[kk][mm] = A[(((size_t)bb * 512 + prow) * 512 + pcol) * 3 + c];
            }
        } else {
            constexpr int AV = BM * BK / 4 / 256;
#pragma unroll
            for (int r = 0; r < AV; ++r) {
                int idx = tid + r * 256;
                int k4 = idx % (BK / 4);
                int mm = idx / (BK / 4);
                float4 v = *(const float4*)(A + (size_t)(bm0 + mm) * K + k0 + k4 * 4);
                As[k4 * 4 + 0][mm] = v.x;
                As[k4 * 4 + 1][mm] = v.y;
                As[k4 * 4 + 2][mm] = v.z;
                As[k4 * 4 + 3][mm] = v.w;
            }
        }
        // ---- stage B tile ----
        if constexpr (!BT) {
            constexpr int BV = BK * BN / 4 / 256;
#pragma unroll
            for (int r = 0; r < BV; ++r) {
                int idx = tid + r * 256;
                int n4 = idx % (BN / 4);
                int kk = idx / (BN / 4);
                float4 v = *(const float4*)(B + (size_t)(k0 + kk) * N + bn0 + n4 * 4);
                *(float4*)&Bs[kk][n4 * 4] = v;
            }
        } else {
            constexpr int BV = BK * BN / 4 / 256;
#pragma unroll
            for (int r = 0; r < BV; ++r) {
                int idx = tid + r * 256;
                int k4 = idx % (BK / 4);
                int nn = idx / (BK / 4);
                float4 v = *(const float4*)(B + (size_t)(bn0 + nn) * K + k0 + k4 * 4);
                Bs[k4 * 4 + 0][nn] = v.x;
                Bs[k4 * 4 + 1][nn] = v.y;
                Bs[k4 * 4 + 2][nn] = v.z;
                Bs[k4 * 4 + 3][nn] = v.w;
            }
        }
        __syncthreads();
        // ---- compute ----
#pragma unroll
        for (int kk = 0; kk < BK; ++kk) {
            float a[TM], b[TN];
#pragma unroll
            for (int i = 0; i < TM; i += 4)
                *(float4*)&a[i] = *(const float4*)&As[kk][ty * TM + i];
#pragma unroll
            for (int j = 0; j < TN; j += 4)
                *(float4*)&b[j] = *(const float4*)&Bs[kk][tx * TN + j];
#pragma unroll
            for (int i = 0; i < TM; ++i)
#pragma unroll
                for (int j = 0; j < TN; ++j)
                    acc[i][j] = fmaf(a[i], b[j], acc[i][j]);
        }
    }

    // ---- epilogue ----
    float* Cb = C;
    if (SPLITK) Cb += (size_t)blockIdx.z * M * N;
#pragma unroll
    for (int i = 0; i < TM; ++i) {
        int m = bm0 + ty * TM + i;
#pragma unroll
        for (int j = 0; j < TN; j += 4) {
            int n = bn0 + tx * TN + j;
            float4 v;
            float* vp = &v.x;
#pragma unroll
            for (int q = 0; q < 4; ++q) {
                float x = acc[i][j + q];
                if (BIAS) x += bias[n + q];
                if (GELU) x = gelu_f(x);
                if (RES)  x += res[(size_t)m * N + n + q];
                if (POS)  x += pos[(size_t)(m & 255) * N + n + q];
                vp[q] = x;
            }
            *(float4*)(Cb + (size_t)m * N + n) = v;
        }
    }
}

// ---------------------------------------------------------------------------
// LayerNorm over rows of 512. One wave per row, 4 rows per 256-thread block.
// ---------------------------------------------------------------------------
__global__ __launch_bounds__(256)
void ln_kernel(const float* __restrict__ X, const float* __restrict__ g,
               const float* __restrict__ b, float* __restrict__ Y, int nrows)
{
    int wave = threadIdx.x >> 6;
    int lane = threadIdx.x & 63;
    int row = blockIdx.x * 4 + wave;
    if (row >= nrows) return;
    const float* x = X + (size_t)row * 512;
    float4 v0 = ((const float4*)x)[lane];
    float4 v1 = ((const float4*)x)[lane + 64];
    float s  = v0.x + v0.y + v0.z + v0.w + v1.x + v1.y + v1.z + v1.w;
    float sq = v0.x*v0.x + v0.y*v0.y + v0.z*v0.z + v0.w*v0.w
             + v1.x*v1.x + v1.y*v1.y + v1.z*v1.z + v1.w*v1.w;
#pragma unroll
    for (int off = 32; off > 0; off >>= 1) {
        s  += __shfl_down(s, off);
        sq += __shfl_down(sq, off);
    }
    s  = __shfl(s, 0);
    sq = __shfl(sq, 0);
    float mean = s * (1.f / 512.f);
    float var  = sq * (1.f / 512.f) - mean * mean;
    float rinv = rsqrtf(var + 1e-6f);
    float4 g0 = ((const float4*)g)[lane], g1 = ((const float4*)g)[lane + 64];
    float4 b0 = ((const float4*)b)[lane], b1 = ((const float4*)b)[lane + 64];
    float4 o0, o1;
    o0.x = (v0.x - mean) * rinv * g0.x + b0.x;
    o0.y = (v0.y - mean) * rinv * g0.y + b0.y;
    o0.z = (v0.z - mean) * rinv * g0.z + b0.z;
    o0.w = (v0.w - mean) * rinv * g0.w + b0.w;
    o1.x = (v1.x - mean) * rinv * g1.x + b1.x;
    o1.y = (v1.y - mean) * rinv * g1.y + b1.y;
    o1.z = (v1.z - mean) * rinv * g1.z + b1.z;
    o1.w = (v1.w - mean) * rinv * g1.w + b1.w;
    float* y = Y + (size_t)row * 512;
    ((float4*)y)[lane]      = o0;
    ((float4*)y)[lane + 64] = o1;
}

// ---------------------------------------------------------------------------
// Attention: one block per (batch,head). K,V staged in LDS (128 KB); one
// query per thread; single-pass softmax without max-subtraction (scores are
// LN-bounded, |s| < ~2, mathematically identical to reference).
// ---------------------------------------------------------------------------
__global__ __launch_bounds__(256)
void attn_kernel(const float* __restrict__ QKV, float* __restrict__ O)
{
    __shared__ float Ks[256][64];
    __shared__ float Vs[256][64];
    int bh = blockIdx.x;
    int b = bh >> 3, h = bh & 7;
    const float* base = QKV + (size_t)b * 256 * 1536;

    for (int i = threadIdx.x; i < 256 * 16; i += 256) {
        int r = i >> 4, d4 = i & 15;
        const float* krow = base + (size_t)r * 1536 + 512 + h * 64;
        const float* vrow = base + (size_t)r * 1536 + 1024 + h * 64;
        *(float4*)&Ks[r][d4 * 4] = *(const float4*)(krow + d4 * 4);
        *(float4*)&Vs[r][d4 * 4] = *(const float4*)(vrow + d4 * 4);
    }
    float q[64];
    const float* qp = base + (size_t)threadIdx.x * 1536 + h * 64;
#pragma unroll
    for (int i = 0; i < 16; ++i) *(float4*)&q[i * 4] = ((const float4*)qp)[i];
    __syncthreads();

    float o[64];
#pragma unroll
    for (int d = 0; d < 64; ++d) o[d] = 0.f;
    float l = 0.f;
#pragma unroll 2
    for (int k = 0; k < 256; ++k) {
        float s = 0.f;
#pragma unroll
        for (int d = 0; d < 64; ++d) s = fmaf(q[d], Ks[k][d], s);
        float e = __expf(s * 0.125f);
        l += e;
#pragma unroll
        for (int d = 0; d < 64; ++d) o[d] = fmaf(e, Vs[k][d], o[d]);
    }
    float inv = 1.f / l;
    float* op = O + ((size_t)b * 256 + threadIdx.x) * 512 + h * 64;
#pragma unroll
    for (int i = 0; i < 16; ++i) {
        float4 t;
        t.x = o[i * 4 + 0] * inv;
        t.y = o[i * 4 + 1] * inv;
        t.z = o[i * 4 + 2] * inv;
        t.w = o[i * 4 + 3] * inv;
        ((float4*)op)[i] = t;
    }
}

// ---------------------------------------------------------------------------
// Split-K reduce + bias + gelu for head layer 1
// ---------------------------------------------------------------------------
__global__ __launch_bounds__(256)
void reduce_gelu_kernel(const float* __restrict__ P, const float* __restrict__ bias,
                        float* __restrict__ Y, int total, int chunks, int N)
{
    int idx = blockIdx.x * 256 + threadIdx.x;
    if (idx >= total) return;
    float s = 0.f;
    for (int c = 0; c < chunks; ++c) s += P[(size_t)c * total + idx];
    s += bias[idx % N];
    Y[idx] = gelu_f(s);
}

// ---------------------------------------------------------------------------
// Tiny tail GEMMs (M=32): one thread per output element
// ---------------------------------------------------------------------------
template<bool GELU>
__global__ __launch_bounds__(256)
void small_gemm_kernel(const float* __restrict__ A, const float* __restrict__ B,
                       const float* __restrict__ bias, float* __restrict__ C,
                       int M, int N, int K)
{
    int idx = blockIdx.x * 256 + threadIdx.x;
    if (idx >= M * N) return;
    int m = idx / N, n = idx % N;
    const float* a = A + (size_t)m * K;
    float s = 0.f;
    for (int k = 0; k < K; ++k) s = fmaf(a[k], B[(size_t)k * N + n], s);
    s += bias[n];
    if (GELU) s = gelu_f(s);
    C[idx] = s;
}

// ---------------------------------------------------------------------------
extern "C" void kernel_launch(void* const* d_in, const int* in_sizes, int n_in,
                              void* d_out, int out_size, void* d_ws, size_t ws_size,
                              hipStream_t stream)
{
    const float* images     = (const float*)d_in[0];
    const float* W_proj     = (const float*)d_in[1];
    const float* b_proj     = (const float*)d_in[2];
    const float* pos_emb    = (const float*)d_in[3];
    const float* ln1_g      = (const float*)d_in[4];
    const float* ln1_b      = (const float*)d_in[5];
    const float* qkv_w      = (const float*)d_in[6];
    const float* qkv_b      = (const float*)d_in[7];
    const float* attn_out_w = (const float*)d_in[8];
    const float* attn_out_b = (const float*)d_in[9];
    const float* ln2_g      = (const float*)d_in[10];
    const float* ln2_b      = (const float*)d_in[11];
    const float* mlp_w1     = (const float*)d_in[12];
    const float* mlp_b1     = (const float*)d_in[13];
    const float* mlp_w2     = (const float*)d_in[14];
    const float* mlp_b2     = (const float*)d_in[15];
    const float* lnf_g      = (const float*)d_in[16];
    const float* lnf_b      = (const float*)d_in[17];
    const float* hW1 = (const float*)d_in[18];
    const float* hb1 = (const float*)d_in[19];
    const float* hW2 = (const float*)d_in[20];
    const float* hb2 = (const float*)d_in[21];
    const float* hW3 = (const float*)d_in[22];
    const float* hb3 = (const float*)d_in[23];
    const float* hW4 = (const float*)d_in[24];
    const float* hb4 = (const float*)d_in[25];
    const float* hW5 = (const float*)d_in[26];
    const float* hb5 = (const float*)d_in[27];
    const float* bbW = (const float*)d_in[28];
    const float* bbb = (const float*)d_in[29];

    // workspace layout (floats)
    float* ws  = (float*)d_ws;
    float* X   = ws;                       // 8192*512
    float* T   = X + 8192 * 512;           // 8192*512
    float* QKV = T + 8192 * 512;           // 8192*1536 (aliased later: mlp hidden, head bufs)
    float* O   = QKV + 8192 * 1536;        // 8192*512
    // head buffers alias the (dead) QKV region
    float* F1p = QKV;                      // 32 * 32*2048 = 2,097,152
    float* F1  = F1p + 2097152;            // 65536
    float* F2  = F1 + 65536;               // 32768
    float* F3  = F2 + 32768;               // 16384
    float* F4  = F3 + 16384;               // 2048
    float* F5  = F4 + 2048;                // 1024

    dim3 blk(256);

    // patch embed: X = patches @ W_proj + b_proj + pos_emb   [8192,512]
    gemm_kernel<128, 128, 16, 16, 4, false, true, true, false, false, true, false>
        <<<dim3(512 / 128, 8192 / 128), blk, 0, stream>>>(
            images, W_proj, X, b_proj, nullptr, pos_emb, 8192, 512, 3072, 0);

    for (int l = 0; l < 4; ++l) {
        // x1 = LN1(x)
        ln_kernel<<<2048, blk, 0, stream>>>(X, ln1_g + l * 512, ln1_b + l * 512, T, 8192);
        // qkv = x1 @ qkv_w^T + qkv_b   [8192,1536]
        gemm_kernel<128, 128, 16, 16, 4, true, false, true, false, false, false, false>
            <<<dim3(1536 / 128, 8192 / 128), blk, 0, stream>>>(
                T, qkv_w + (size_t)l * 1536 * 512, QKV, qkv_b + l * 1536,
                nullptr, nullptr, 8192, 1536, 512, 0);
        // attention
        attn_kernel<<<256, blk, 0, stream>>>(QKV, O);
        // x2 = o @ out_w^T + out_b + x   (writes X in place)
        gemm_kernel<128, 128, 16, 16, 4, true, false, true, false, true, false, false>
            <<<dim3(512 / 128, 8192 / 128), blk, 0, stream>>>(
                O, attn_out_w + (size_t)l * 512 * 512, X, attn_out_b + l * 512,
                X, nullptr, 8192, 512, 512, 0);
        // x3 = LN2(x2)
        ln_kernel<<<2048, blk, 0, stream>>>(X, ln2_g + l * 512, ln2_b + l * 512, T, 8192);
        // h = gelu(x3 @ w1 + b1)   [8192,1024]  (into QKV region)
        gemm_kernel<128, 128, 16, 16, 4, false, false, true, true, false, false, false>
            <<<dim3(1024 / 128, 8192 / 128), blk, 0, stream>>>(
                T, mlp_w1 + (size_t)l * 512 * 1024, QKV, mlp_b1 + l * 1024,
                nullptr, nullptr, 8192, 1024, 512, 0);
        // x = gelu(h @ w2 + b2) + x2   (writes X in place)
        gemm_kernel<128, 128, 16, 16, 4, false, false, true, true, true, false, false>
            <<<dim3(512 / 128, 8192 / 128), blk, 0, stream>>>(
                QKV, mlp_w2 + (size_t)l * 1024 * 512, X, mlp_b2 + l * 512,
                X, nullptr, 8192, 512, 1024, 0);
    }

    // rep = LN_f(x)  -> T viewed as [32, 131072]
    ln_kernel<<<2048, blk, 0, stream>>>(X, lnf_g, lnf_b, T, 8192);

    // head layer 1: split-K GEMM [32,131072]x[131072,2048], 32 K-chunks
    gemm_kernel<32, 128, 32, 4, 4, false, false, false, false, false, false, true>
        <<<dim3(2048 / 128, 1, 32), blk, 0, stream>>>(
            T, hW1, F1p, nullptr, nullptr, nullptr, 32, 2048, 131072, 131072 / 32);
    reduce_gelu_kernel<<<(65536 + 255) / 256, blk, 0, stream>>>(F1p, hb1, F1, 65536, 32, 2048);

    // head layers 2-5 + bbox
    small_gemm_kernel<true><<<(32 * 1024 + 255) / 256, blk, 0, stream>>>(F1, hW2, hb2, F2, 32, 1024, 2048);
    small_gemm_kernel<true><<<(32 * 512 + 255) / 256, blk, 0, stream>>>(F2, hW3, hb3, F3, 32, 512, 1024);
    small_gemm_kernel<true><<<(32 * 64 + 255) / 256, blk, 0, stream>>>(F3, hW4, hb4, F4, 32, 64, 512);
    small_gemm_kernel<true><<<(32 * 32 + 255) / 256, blk, 0, stream>>>(F4, hW5, hb5, F5, 32, 32, 64);
    small_gemm_kernel<false><<<1, blk, 0, stream>>>(F5, bbW, bbb, (float*)d_out, 32, 4, 32);
}

// Round 2
// 3485.838 us; speedup vs baseline: 1.3147x; 1.3147x over previous
//
#include <hip/hip_runtime.h>
#include <cstdint>
#include <cstddef>

#define DEV __device__ __forceinline__

DEV float gelu_f(float x) { return 0.5f * x * (1.0f + erff(x * 0.70710678118654752f)); }

// ---------------------------------------------------------------------------
// Generic tiled fp32 GEMM: C[M,N] = A[M,K] @ B (+bias)(+gelu)(+res)(+pos)
//   BT=false: B stored [K][N]; BT=true: B stored [N][K] (i.e. computes A@B^T)
//   PATCH: A elements gathered from images [B,512,512,3] (ViT unfold)
//   SPLITK: grid.z splits K into chunks; partials written to C + z*M*N
// ---------------------------------------------------------------------------
template<int BM, int BN, int BK, int TM, int TN,
         bool BT, bool PATCH, bool BIAS, bool GELU, bool RES, bool POS, bool SPLITK>
__global__ __launch_bounds__(256)
void gemm_kernel(const float* __restrict__ A, const float* __restrict__ B,
                 float* __restrict__ C, const float* __restrict__ bias,
                 const float* __restrict__ res, const float* __restrict__ pos,
                 int M, int N, int K, int kchunk)
{
    constexpr int TX = BN / TN;
    constexpr int TY = BM / TM;
    static_assert(TX * TY == 256, "bad tile config");

    __shared__ float As[BK][BM + 4];
    __shared__ float Bs[BK][BN + 4];

    const int tid = threadIdx.x;
    const int tx  = tid % TX;
    const int ty  = tid / TX;
    const int bn0 = blockIdx.x * BN;
    const int bm0 = blockIdx.y * BM;

    int kstart = 0, kend = K;
    if (SPLITK) { kstart = blockIdx.z * kchunk; kend = kstart + kchunk; }

    float acc[TM][TN];
#pragma unroll
    for (int i = 0; i < TM; ++i)
#pragma unroll
        for (int j = 0; j < TN; ++j) acc[i][j] = 0.f;

    for (int k0 = kstart; k0 < kend; k0 += BK) {
        __syncthreads();
        // ---- stage A tile ----
        if constexpr (PATCH) {
            constexpr int AE = BM * BK / 256;
#pragma unroll
            for (int r = 0; r < AE; ++r) {
                int idx = tid + r * 256;
                int kk = idx % BK;
                int mm = idx / BK;
                int m = bm0 + mm;
                int k = k0 + kk;
                int bb = m >> 8, n = m & 255;
                int ph = k / 96, rem = k - ph * 96;
                int pw = rem / 3, c = rem - pw * 3;
                int prow = ((n >> 4) << 5) + ph;
                int pcol = ((n & 15) << 5) + pw;
                As[kk][mm] = A[(((size_t)bb * 512 + prow) * 512 + pcol) * 3 + c];
            }
        } else {
            constexpr int AV = BM * BK / 4 / 256;
#pragma unroll
            for (int r = 0; r < AV; ++r) {
                int idx = tid + r * 256;
                int k4 = idx % (BK / 4);
                int mm = idx / (BK / 4);
                float4 v = *(const float4*)(A + (size_t)(bm0 + mm) * K + k0 + k4 * 4);
                As[k4 * 4 + 0][mm] = v.x;
                As[k4 * 4 + 1][mm] = v.y;
                As[k4 * 4 + 2][mm] = v.z;
                As[k4 * 4 + 3][mm] = v.w;
            }
        }
        // ---- stage B tile ----
        if constexpr (!BT) {
            constexpr int BV = BK * BN / 4 / 256;
#pragma unroll
            for (int r = 0; r < BV; ++r) {
                int idx = tid + r * 256;
                int n4 = idx % (BN / 4);
                int kk = idx / (BN / 4);
                float4 v = *(const float4*)(B + (size_t)(k0 + kk) * N + bn0 + n4 * 4);
                *(float4*)&Bs[kk][n4 * 4] = v;
            }
        } else {
            constexpr int BV = BK * BN / 4 / 256;
#pragma unroll
            for (int r = 0; r < BV; ++r) {
                int idx = tid + r * 256;
                int k4 = idx % (BK / 4);
                int nn = idx / (BK / 4);
                float4 v = *(const float4*)(B + (size_t)(bn0 + nn) * K + k0 + k4 * 4);
                Bs[k4 * 4 + 0][nn] = v.x;
                Bs[k4 * 4 + 1][nn] = v.y;
                Bs[k4 * 4 + 2][nn] = v.z;
                Bs[k4 * 4 + 3][nn] = v.w;
            }
        }
        __syncthreads();
        // ---- compute ----
#pragma unroll
        for (int kk = 0; kk < BK; ++kk) {
            float a[TM], b[TN];
#pragma unroll
            for (int i = 0; i < TM; i += 4)
                *(float4*)&a[i] = *(const float4*)&As[kk][ty * TM + i];
#pragma unroll
            for (int j = 0; j < TN; j += 4)
                *(float4*)&b[j] = *(const float4*)&Bs[kk][tx * TN + j];
#pragma unroll
            for (int i = 0; i < TM; ++i)
#pragma unroll
                for (int j = 0; j < TN; ++j)
                    acc[i][j] = fmaf(a[i], b[j], acc[i][j]);
        }
    }

    // ---- epilogue ----
    float* Cb = C;
    if (SPLITK) Cb += (size_t)blockIdx.z * M * N;
#pragma unroll
    for (int i = 0; i < TM; ++i) {
        int m = bm0 + ty * TM + i;
#pragma unroll
        for (int j = 0; j < TN; j += 4) {
            int n = bn0 + tx * TN + j;
            float4 v;
            float* vp = &v.x;
#pragma unroll
            for (int q = 0; q < 4; ++q) {
                float x = acc[i][j + q];
                if (BIAS) x += bias[n + q];
                if (GELU) x = gelu_f(x);
                if (RES)  x += res[(size_t)m * N + n + q];
                if (POS)  x += pos[(size_t)(m & 255) * N + n + q];
                vp[q] = x;
            }
            *(float4*)(Cb + (size_t)m * N + n) = v;
        }
    }
}

// ---------------------------------------------------------------------------
// Skinny split-K GEMM for the MLP head tail: M=32 rows, 64-col tiles.
// grid = (N/64, K/kchunk). Each block: full 32 rows x 64 cols over one
// K-chunk; A (32 x 32-step) staged in LDS, B read coalesced (64 consecutive
// floats per wave). Partials to P[z*M*N + ...]; reduce_gelu sums chunks.
// ---------------------------------------------------------------------------
__global__ __launch_bounds__(256)
void skinny_gemm_kernel(const float* __restrict__ A, const float* __restrict__ B,
                        float* __restrict__ P, int M, int N, int K, int kchunk)
{
    __shared__ float As[32][36];
    const int tid = threadIdx.x;
    const int tx  = tid & 63;   // column within 64-wide tile
    const int ty  = tid >> 6;   // row group: 4 groups x 8 rows
    const int bn0 = blockIdx.x * 64;
    const int kstart = blockIdx.y * kchunk;
    const int kend   = kstart + kchunk;

    float acc[8];
#pragma unroll
    for (int i = 0; i < 8; ++i) acc[i] = 0.f;

    for (int k0 = kstart; k0 < kend; k0 += 32) {
        __syncthreads();
        {   // stage A: 32 rows x 32 k, one float4 per thread
            int row = tid >> 3;       // 0..31
            int k4  = tid & 7;        // 0..7
            float4 v = *(const float4*)(A + (size_t)row * K + k0 + k4 * 4);
            *(float4*)&As[row][k4 * 4] = v;
        }
        __syncthreads();
#pragma unroll 8
        for (int kk = 0; kk < 32; ++kk) {
            float b = B[(size_t)(k0 + kk) * N + bn0 + tx];
#pragma unroll
            for (int i = 0; i < 8; ++i)
                acc[i] = fmaf(As[ty * 8 + i][kk], b, acc[i]);
        }
    }

    float* Pb = P + (size_t)blockIdx.y * M * N;
#pragma unroll
    for (int i = 0; i < 8; ++i)
        Pb[(size_t)(ty * 8 + i) * N + bn0 + tx] = acc[i];
}

// ---------------------------------------------------------------------------
// LayerNorm over rows of 512. One wave per row, 4 rows per 256-thread block.
// ---------------------------------------------------------------------------
__global__ __launch_bounds__(256)
void ln_kernel(const float* __restrict__ X, const float* __restrict__ g,
               const float* __restrict__ b, float* __restrict__ Y, int nrows)
{
    int wave = threadIdx.x >> 6;
    int lane = threadIdx.x & 63;
    int row = blockIdx.x * 4 + wave;
    if (row >= nrows) return;
    const float* x = X + (size_t)row * 512;
    float4 v0 = ((const float4*)x)[lane];
    float4 v1 = ((const float4*)x)[lane + 64];
    float s  = v0.x + v0.y + v0.z + v0.w + v1.x + v1.y + v1.z + v1.w;
    float sq = v0.x*v0.x + v0.y*v0.y + v0.z*v0.z + v0.w*v0.w
             + v1.x*v1.x + v1.y*v1.y + v1.z*v1.z + v1.w*v1.w;
#pragma unroll
    for (int off = 32; off > 0; off >>= 1) {
        s  += __shfl_down(s, off);
        sq += __shfl_down(sq, off);
    }
    s  = __shfl(s, 0);
    sq = __shfl(sq, 0);
    float mean = s * (1.f / 512.f);
    float var  = sq * (1.f / 512.f) - mean * mean;
    float rinv = rsqrtf(var + 1e-6f);
    float4 g0 = ((const float4*)g)[lane], g1 = ((const float4*)g)[lane + 64];
    float4 b0 = ((const float4*)b)[lane], b1 = ((const float4*)b)[lane + 64];
    float4 o0, o1;
    o0.x = (v0.x - mean) * rinv * g0.x + b0.x;
    o0.y = (v0.y - mean) * rinv * g0.y + b0.y;
    o0.z = (v0.z - mean) * rinv * g0.z + b0.z;
    o0.w = (v0.w - mean) * rinv * g0.w + b0.w;
    o1.x = (v1.x - mean) * rinv * g1.x + b1.x;
    o1.y = (v1.y - mean) * rinv * g1.y + b1.y;
    o1.z = (v1.z - mean) * rinv * g1.z + b1.z;
    o1.w = (v1.w - mean) * rinv * g1.w + b1.w;
    float* y = Y + (size_t)row * 512;
    ((float4*)y)[lane]      = o0;
    ((float4*)y)[lane + 64] = o1;
}

// ---------------------------------------------------------------------------
// Attention: one block per (batch,head). K,V staged in LDS (128 KB); one
// query per thread; single-pass softmax without max-subtraction (scores are
// LN-bounded, |s| < ~2, mathematically identical to reference).
// ---------------------------------------------------------------------------
__global__ __launch_bounds__(256)
void attn_kernel(const float* __restrict__ QKV, float* __restrict__ O)
{
    __shared__ float Ks[256][64];
    __shared__ float Vs[256][64];
    int bh = blockIdx.x;
    int b = bh >> 3, h = bh & 7;
    const float* base = QKV + (size_t)b * 256 * 1536;

    for (int i = threadIdx.x; i < 256 * 16; i += 256) {
        int r = i >> 4, d4 = i & 15;
        const float* krow = base + (size_t)r * 1536 + 512 + h * 64;
        const float* vrow = base + (size_t)r * 1536 + 1024 + h * 64;
        *(float4*)&Ks[r][d4 * 4] = *(const float4*)(krow + d4 * 4);
        *(float4*)&Vs[r][d4 * 4] = *(const float4*)(vrow + d4 * 4);
    }
    float q[64];
    const float* qp = base + (size_t)threadIdx.x * 1536 + h * 64;
#pragma unroll
    for (int i = 0; i < 16; ++i) *(float4*)&q[i * 4] = ((const float4*)qp)[i];
    __syncthreads();

    float o[64];
#pragma unroll
    for (int d = 0; d < 64; ++d) o[d] = 0.f;
    float l = 0.f;
#pragma unroll 2
    for (int k = 0; k < 256; ++k) {
        float s = 0.f;
#pragma unroll
        for (int d = 0; d < 64; ++d) s = fmaf(q[d], Ks[k][d], s);
        float e = __expf(s * 0.125f);
        l += e;
#pragma unroll
        for (int d = 0; d < 64; ++d) o[d] = fmaf(e, Vs[k][d], o[d]);
    }
    float inv = 1.f / l;
    float* op = O + ((size_t)b * 256 + threadIdx.x) * 512 + h * 64;
#pragma unroll
    for (int i = 0; i < 16; ++i) {
        float4 t;
        t.x = o[i * 4 + 0] * inv;
        t.y = o[i * 4 + 1] * inv;
        t.z = o[i * 4 + 2] * inv;
        t.w = o[i * 4 + 3] * inv;
        ((float4*)op)[i] = t;
    }
}

// ---------------------------------------------------------------------------
// Split-K reduce + bias + gelu
// ---------------------------------------------------------------------------
__global__ __launch_bounds__(256)
void reduce_gelu_kernel(const float* __restrict__ P, const float* __restrict__ bias,
                        float* __restrict__ Y, int total, int chunks, int N)
{
    int idx = blockIdx.x * 256 + threadIdx.x;
    if (idx >= total) return;
    float s = 0.f;
    for (int c = 0; c < chunks; ++c) s += P[(size_t)c * total + idx];
    s += bias[idx % N];
    Y[idx] = gelu_f(s);
}

// ---------------------------------------------------------------------------
// Tiny tail GEMMs (very small K): one thread per output element
// ---------------------------------------------------------------------------
template<bool GELU>
__global__ __launch_bounds__(256)
void small_gemm_kernel(const float* __restrict__ A, const float* __restrict__ B,
                       const float* __restrict__ bias, float* __restrict__ C,
                       int M, int N, int K)
{
    int idx = blockIdx.x * 256 + threadIdx.x;
    if (idx >= M * N) return;
    int m = idx / N, n = idx % N;
    const float* a = A + (size_t)m * K;
    float s = 0.f;
    for (int k = 0; k < K; ++k) s = fmaf(a[k], B[(size_t)k * N + n], s);
    s += bias[n];
    if (GELU) s = gelu_f(s);
    C[idx] = s;
}

// ---------------------------------------------------------------------------
extern "C" void kernel_launch(void* const* d_in, const int* in_sizes, int n_in,
                              void* d_out, int out_size, void* d_ws, size_t ws_size,
                              hipStream_t stream)
{
    const float* images     = (const float*)d_in[0];
    const float* W_proj     = (const float*)d_in[1];
    const float* b_proj     = (const float*)d_in[2];
    const float* pos_emb    = (const float*)d_in[3];
    const float* ln1_g      = (const float*)d_in[4];
    const float* ln1_b      = (const float*)d_in[5];
    const float* qkv_w      = (const float*)d_in[6];
    const float* qkv_b      = (const float*)d_in[7];
    const float* attn_out_w = (const float*)d_in[8];
    const float* attn_out_b = (const float*)d_in[9];
    const float* ln2_g      = (const float*)d_in[10];
    const float* ln2_b      = (const float*)d_in[11];
    const float* mlp_w1     = (const float*)d_in[12];
    const float* mlp_b1     = (const float*)d_in[13];
    const float* mlp_w2     = (const float*)d_in[14];
    const float* mlp_b2     = (const float*)d_in[15];
    const float* lnf_g      = (const float*)d_in[16];
    const float* lnf_b      = (const float*)d_in[17];
    const float* hW1 = (const float*)d_in[18];
    const float* hb1 = (const float*)d_in[19];
    const float* hW2 = (const float*)d_in[20];
    const float* hb2 = (const float*)d_in[21];
    const float* hW3 = (const float*)d_in[22];
    const float* hb3 = (const float*)d_in[23];
    const float* hW4 = (const float*)d_in[24];
    const float* hb4 = (const float*)d_in[25];
    const float* hW5 = (const float*)d_in[26];
    const float* hb5 = (const float*)d_in[27];
    const float* bbW = (const float*)d_in[28];
    const float* bbb = (const float*)d_in[29];

    // workspace layout (floats)
    float* ws  = (float*)d_ws;
    float* X   = ws;                       // 8192*512
    float* T   = X + 8192 * 512;           // 8192*512
    float* QKV = T + 8192 * 512;           // 8192*1536 (aliased later by head bufs)
    float* O   = QKV + 8192 * 1536;        // 8192*512
    // head buffers alias the (dead) QKV region (12,582,912 floats available)
    float* F1p = QKV;                      // 64 * 65536   = 4,194,304
    float* F1  = F1p + 4194304;            // 65,536
    float* P2  = F1  + 65536;              // 64 * 32768   = 2,097,152
    float* F2  = P2  + 2097152;            // 32,768
    float* P3  = F2  + 32768;              // 32 * 16384   =   524,288
    float* F3  = P3  + 524288;             // 16,384
    float* P4  = F3  + 16384;              // 16 * 2048    =    32,768
    float* F4  = P4  + 32768;              // 2,048
    float* F5  = F4  + 2048;               // 1,024

    dim3 blk(256);

    // patch embed: X = patches @ W_proj + b_proj + pos_emb   [8192,512]
    gemm_kernel<128, 128, 16, 16, 4, false, true, true, false, false, true, false>
        <<<dim3(512 / 128, 8192 / 128), blk, 0, stream>>>(
            images, W_proj, X, b_proj, nullptr, pos_emb, 8192, 512, 3072, 0);

    for (int l = 0; l < 4; ++l) {
        // x1 = LN1(x)
        ln_kernel<<<2048, blk, 0, stream>>>(X, ln1_g + l * 512, ln1_b + l * 512, T, 8192);
        // qkv = x1 @ qkv_w^T + qkv_b   [8192,1536]
        gemm_kernel<128, 128, 16, 16, 4, true, false, true, false, false, false, false>
            <<<dim3(1536 / 128, 8192 / 128), blk, 0, stream>>>(
                T, qkv_w + (size_t)l * 1536 * 512, QKV, qkv_b + l * 1536,
                nullptr, nullptr, 8192, 1536, 512, 0);
        // attention
        attn_kernel<<<256, blk, 0, stream>>>(QKV, O);
        // x2 = o @ out_w^T + out_b + x   (writes X in place)
        gemm_kernel<128, 128, 16, 16, 4, true, false, true, false, true, false, false>
            <<<dim3(512 / 128, 8192 / 128), blk, 0, stream>>>(
                O, attn_out_w + (size_t)l * 512 * 512, X, attn_out_b + l * 512,
                X, nullptr, 8192, 512, 512, 0);
        // x3 = LN2(x2)
        ln_kernel<<<2048, blk, 0, stream>>>(X, ln2_g + l * 512, ln2_b + l * 512, T, 8192);
        // h = gelu(x3 @ w1 + b1)   [8192,1024]  (into QKV region)
        gemm_kernel<128, 128, 16, 16, 4, false, false, true, true, false, false, false>
            <<<dim3(1024 / 128, 8192 / 128), blk, 0, stream>>>(
                T, mlp_w1 + (size_t)l * 512 * 1024, QKV, mlp_b1 + l * 1024,
                nullptr, nullptr, 8192, 1024, 512, 0);
        // x = gelu(h @ w2 + b2) + x2   (writes X in place)
        gemm_kernel<128, 128, 16, 16, 4, false, false, true, true, true, false, false>
            <<<dim3(512 / 128, 8192 / 128), blk, 0, stream>>>(
                QKV, mlp_w2 + (size_t)l * 1024 * 512, X, mlp_b2 + l * 512,
                X, nullptr, 8192, 512, 1024, 0);
    }

    // rep = LN_f(x)  -> T viewed as [32, 131072]
    ln_kernel<<<2048, blk, 0, stream>>>(X, lnf_g, lnf_b, T, 8192);

    // head layer 1: split-K GEMM [32,131072]x[131072,2048], 64 K-chunks
    gemm_kernel<32, 128, 32, 4, 4, false, false, false, false, false, false, true>
        <<<dim3(2048 / 128, 1, 64), blk, 0, stream>>>(
            T, hW1, F1p, nullptr, nullptr, nullptr, 32, 2048, 131072, 131072 / 64);
    reduce_gelu_kernel<<<(65536 + 255) / 256, blk, 0, stream>>>(F1p, hb1, F1, 65536, 64, 2048);

    // head layer 2: [32,2048]x[2048,1024], skinny split-K (16 col-tiles x 64 chunks)
    skinny_gemm_kernel<<<dim3(1024 / 64, 2048 / 32), blk, 0, stream>>>(
        F1, hW2, P2, 32, 1024, 2048, 32);
    reduce_gelu_kernel<<<(32768 + 255) / 256, blk, 0, stream>>>(P2, hb2, F2, 32768, 64, 1024);

    // head layer 3: [32,1024]x[1024,512]
    skinny_gemm_kernel<<<dim3(512 / 64, 1024 / 32), blk, 0, stream>>>(
        F2, hW3, P3, 32, 512, 1024, 32);
    reduce_gelu_kernel<<<(16384 + 255) / 256, blk, 0, stream>>>(P3, hb3, F3, 16384, 32, 512);

    // head layer 4: [32,512]x[512,64]
    skinny_gemm_kernel<<<dim3(64 / 64, 512 / 32), blk, 0, stream>>>(
        F3, hW4, P4, 32, 64, 512, 32);
    reduce_gelu_kernel<<<(2048 + 255) / 256, blk, 0, stream>>>(P4, hb4, F4, 2048, 16, 64);

    // head layer 5 + bbox (trivial K)
    small_gemm_kernel<true><<<(32 * 32 + 255) / 256, blk, 0, stream>>>(F4, hW5, hb5, F5, 32, 32, 64);
    small_gemm_kernel<false><<<1, blk, 0, stream>>>(F5, bbW, bbb, (float*)d_out, 32, 4, 32);
}

// Round 3
// 1885.578 us; speedup vs baseline: 2.4305x; 1.8487x over previous
//
#include <hip/hip_runtime.h>
#include <cstdint>
#include <cstddef>

#define DEV __device__ __forceinline__

typedef float f32x4 __attribute__((ext_vector_type(4)));
typedef short s16x8 __attribute__((ext_vector_type(8)));

DEV float gelu_f(float x) { return 0.5f * x * (1.0f + erff(x * 0.70710678118654752f)); }

DEV uint32_t fbits(float x) { return __builtin_bit_cast(uint32_t, x); }
DEV float bcast_f(uint32_t u) { return __builtin_bit_cast(float, u); }

// split x into hi (bf16-truncate) and lo (bf16-truncate of residual)
DEV void split_bf16(float x, uint16_t& h, uint16_t& lo) {
    uint32_t xb = fbits(x);
    h = (uint16_t)(xb >> 16);
    float r = x - bcast_f(xb & 0xFFFF0000u);
    lo = (uint16_t)(fbits(r) >> 16);
}

DEV void gload16(const void* g, void* l) {
    __builtin_amdgcn_global_load_lds(
        (const __attribute__((address_space(1))) uint32_t*)g,
        (__attribute__((address_space(3))) uint32_t*)l, 16, 0, 0);
}

// ---------------------------------------------------------------------------
// Split-bf16 MFMA GEMM.  A-planes [M][K] bf16 hi/lo, B-planes [N][K] bf16
// hi/lo (k-major).  C = A@B^T_planes with fp32 accumulate via 3 MFMA passes.
// LDS layout per plane: [rows][4 slots of 16B], slot XOR-swizzled via the
// per-lane GLOBAL source address (LDS linear for global_load_lds).
// ---------------------------------------------------------------------------
template<int BM, int BN, bool BIAS, bool GELU, bool RES, bool POS, bool OUTF32, bool OUTPL>
__global__ __launch_bounds__(256)
void mfma_gemm(const uint16_t* __restrict__ Ah, const uint16_t* __restrict__ Al,
               const uint16_t* __restrict__ Bh, const uint16_t* __restrict__ Bl,
               float* __restrict__ C, uint16_t* __restrict__ Chi, uint16_t* __restrict__ Clo,
               const float* __restrict__ bias, const float* __restrict__ res,
               const float* __restrict__ pos, int M, int N, int K)
{
    constexpr int WTM = BM / 2, WTN = BN / 2;
    constexpr int FM = WTM / 16, FN = WTN / 16;
    constexpr int NA = BM / 16, NB = BN / 16;      // 1KB chunks per A/B plane
    constexpr int TI = 2 * NA + 2 * NB;            // total gload instrs per K-step
    constexpr int TI4 = TI / 4;                    // per wave

    __shared__ __align__(16) uint8_t smem[(2 * BM + 2 * BN) * 64];
    constexpr int offAh = 0, offAl = BM * 64, offBh = 2 * BM * 64, offBl = 2 * BM * 64 + BN * 64;

    const int tid = threadIdx.x;
    const int w = tid >> 6, l = tid & 63;
    const int wr = w >> 1, wc = w & 1;
    const int bm0 = blockIdx.y * BM, bn0 = blockIdx.x * BN;
    const size_t sK = (size_t)K * 2;               // row stride in bytes

    // ---- staging descriptors (per-lane global addr, wave-uniform LDS off) ----
    const int srow  = l >> 2;
    const int sslot = (l & 3) ^ ((l >> 3) & 3);
    const uint8_t* gsrc[TI4];
    uint32_t loff[TI4];
#pragma unroll
    for (int j = 0; j < TI4; ++j) {
        int f = w * TI4 + j;
        int p = (f < NA) ? 0 : (f < 2 * NA) ? 1 : (f < 2 * NA + NB) ? 2 : 3;
        int c = f - (p == 0 ? 0 : p == 1 ? NA : p == 2 ? 2 * NA : 2 * NA + NB);
        const uint16_t* base = p == 0 ? Ah : p == 1 ? Al : p == 2 ? Bh : Bl;
        int rb = (p < 2) ? bm0 : bn0;
        gsrc[j] = (const uint8_t*)base + (size_t)(rb + c * 16 + srow) * sK + sslot * 16;
        loff[j] = (uint32_t)((p == 0 ? offAh : p == 1 ? offAl : p == 2 ? offBh : offBl) + c * 1024);
    }

    // ---- fragment read offsets ----
    const int lr = l & 15;
    const int sl16 = ((l >> 4) ^ ((lr >> 1) & 3)) * 16;
    const int aofs = (wr * WTM + lr) * 64 + sl16;
    const int bofs = (wc * WTN + lr) * 64 + sl16;

    f32x4 acc[FM][FN];
#pragma unroll
    for (int m = 0; m < FM; ++m)
#pragma unroll
        for (int n = 0; n < FN; ++n) acc[m][n] = (f32x4){0.f, 0.f, 0.f, 0.f};

    for (int k0 = 0; k0 < K; k0 += 32) {
        __syncthreads();
        const size_t kb = (size_t)k0 * 2;
#pragma unroll
        for (int j = 0; j < TI4; ++j)
            gload16(gsrc[j] + kb, smem + loff[j]);
        __syncthreads();

        s16x8 ah[FM], al[FM], bh[FN], bl[FN];
#pragma unroll
        for (int m = 0; m < FM; ++m) {
            ah[m] = *(const s16x8*)(smem + offAh + aofs + m * 1024);
            al[m] = *(const s16x8*)(smem + offAl + aofs + m * 1024);
        }
#pragma unroll
        for (int n = 0; n < FN; ++n) {
            bh[n] = *(const s16x8*)(smem + offBh + bofs + n * 1024);
            bl[n] = *(const s16x8*)(smem + offBl + bofs + n * 1024);
        }
#pragma unroll
        for (int m = 0; m < FM; ++m)
#pragma unroll
            for (int n = 0; n < FN; ++n)
                acc[m][n] = __builtin_amdgcn_mfma_f32_16x16x32_bf16(ah[m], bh[n], acc[m][n], 0, 0, 0);
#pragma unroll
        for (int m = 0; m < FM; ++m)
#pragma unroll
            for (int n = 0; n < FN; ++n)
                acc[m][n] = __builtin_amdgcn_mfma_f32_16x16x32_bf16(ah[m], bl[n], acc[m][n], 0, 0, 0);
#pragma unroll
        for (int m = 0; m < FM; ++m)
#pragma unroll
            for (int n = 0; n < FN; ++n)
                acc[m][n] = __builtin_amdgcn_mfma_f32_16x16x32_bf16(al[m], bh[n], acc[m][n], 0, 0, 0);
    }

    // ---- epilogue: C/D layout col=lane&15, row=(lane>>4)*4+reg ----
    const int r4 = (l >> 4) * 4;
#pragma unroll
    for (int m = 0; m < FM; ++m) {
#pragma unroll
        for (int n = 0; n < FN; ++n) {
            int nn = bn0 + wc * WTN + n * 16 + lr;
#pragma unroll
            for (int r = 0; r < 4; ++r) {
                int mm = bm0 + wr * WTM + m * 16 + r4 + r;
                float x = acc[m][n][r];
                if (BIAS) x += bias[nn];
                if (GELU) x = gelu_f(x);
                if (RES)  x += res[(size_t)mm * N + nn];
                if (POS)  x += pos[(size_t)(mm & 255) * N + nn];
                size_t o = (size_t)mm * N + nn;
                if (OUTF32) C[o] = x;
                if (OUTPL) {
                    uint16_t h, lo;
                    split_bf16(x, h, lo);
                    Chi[o] = h; Clo[o] = lo;
                }
            }
        }
    }
}

// ---------------------------------------------------------------------------
// Prep: images -> patch-gathered bf16 hi/lo planes [8192][3072]
// ---------------------------------------------------------------------------
__global__ __launch_bounds__(256)
void img2planes_kernel(const float* __restrict__ img, uint16_t* __restrict__ Ph,
                       uint16_t* __restrict__ Pl)
{
    int idx = blockIdx.x * 256 + threadIdx.x;   // over 8192*768
    if (idx >= 8192 * 768) return;
    int m = idx / 768, q = idx - (idx / 768) * 768;
    int k = q * 4;
    int bb = m >> 8, n = m & 255;
    int ph = k / 96, rem = k - ph * 96;
    int prow = ((n >> 4) << 5) + ph;
    int pcol0 = (n & 15) << 5;
    const float* s = img + (((size_t)bb * 512 + prow) * 512 + pcol0) * 3 + rem;
    float4 v = *(const float4*)s;
    ushort4 hh, ll;
    uint16_t h, lo;
    split_bf16(v.x, h, lo); hh.x = h; ll.x = lo;
    split_bf16(v.y, h, lo); hh.y = h; ll.y = lo;
    split_bf16(v.z, h, lo); hh.z = h; ll.z = lo;
    split_bf16(v.w, h, lo); hh.w = h; ll.w = lo;
    size_t o = (size_t)m * 3072 + k;
    *(ushort4*)(Ph + o) = hh;
    *(ushort4*)(Pl + o) = ll;
}

// ---------------------------------------------------------------------------
// Prep: direct convert fp32 [N][K] -> bf16 hi/lo planes (same layout)
// ---------------------------------------------------------------------------
__global__ __launch_bounds__(256)
void conv_direct_kernel(const float* __restrict__ src, uint16_t* __restrict__ dh,
                        uint16_t* __restrict__ dl, int total4)
{
    int idx = blockIdx.x * 256 + threadIdx.x;
    if (idx >= total4) return;
    float4 v = *(const float4*)(src + (size_t)idx * 4);
    ushort4 hh, ll;
    uint16_t h, lo;
    split_bf16(v.x, h, lo); hh.x = h; ll.x = lo;
    split_bf16(v.y, h, lo); hh.y = h; ll.y = lo;
    split_bf16(v.z, h, lo); hh.z = h; ll.z = lo;
    split_bf16(v.w, h, lo); hh.w = h; ll.w = lo;
    *(ushort4*)(dh + (size_t)idx * 4) = hh;
    *(ushort4*)(dl + (size_t)idx * 4) = ll;
}

// ---------------------------------------------------------------------------
// Prep: transpose-convert fp32 [K][N] -> bf16 hi/lo planes [N][K]
// grid (K/32, N/32, layers)
// ---------------------------------------------------------------------------
__global__ __launch_bounds__(256)
void conv_transpose_kernel(const float* __restrict__ src, uint16_t* __restrict__ dh,
                           uint16_t* __restrict__ dl, int K, int N)
{
    __shared__ float t[32][33];
    int k0 = blockIdx.x * 32, n0 = blockIdx.y * 32;
    const float* s = src + (size_t)blockIdx.z * K * N;
    size_t dbase = (size_t)blockIdx.z * N * K;
    int tid = threadIdx.x;
    {
        int kk = tid / 8, n4 = tid % 8;
        float4 v = *(const float4*)(s + (size_t)(k0 + kk) * N + n0 + n4 * 4);
        t[kk][n4 * 4 + 0] = v.x; t[kk][n4 * 4 + 1] = v.y;
        t[kk][n4 * 4 + 2] = v.z; t[kk][n4 * 4 + 3] = v.w;
    }
    __syncthreads();
    int nn = tid / 8, k4 = tid % 8;
    ushort4 hh, ll;
    uint16_t h, lo;
    float x0 = t[k4 * 4 + 0][nn], x1 = t[k4 * 4 + 1][nn], x2 = t[k4 * 4 + 2][nn], x3 = t[k4 * 4 + 3][nn];
    split_bf16(x0, h, lo); hh.x = h; ll.x = lo;
    split_bf16(x1, h, lo); hh.y = h; ll.y = lo;
    split_bf16(x2, h, lo); hh.z = h; ll.z = lo;
    split_bf16(x3, h, lo); hh.w = h; ll.w = lo;
    size_t o = dbase + (size_t)(n0 + nn) * K + k0 + k4 * 4;
    *(ushort4*)(dh + o) = hh;
    *(ushort4*)(dl + o) = ll;
}

// ---------------------------------------------------------------------------
// LayerNorm over rows of 512; optionally emit bf16 hi/lo planes.
// ---------------------------------------------------------------------------
template<bool PLANES>
__global__ __launch_bounds__(256)
void ln_kernel(const float* __restrict__ X, const float* __restrict__ g,
               const float* __restrict__ b, float* __restrict__ Y,
               uint16_t* __restrict__ Yh, uint16_t* __restrict__ Yl, int nrows)
{
    int wave = threadIdx.x >> 6;
    int lane = threadIdx.x & 63;
    int row = blockIdx.x * 4 + wave;
    if (row >= nrows) return;
    const float* x = X + (size_t)row * 512;
    float4 v0 = ((const float4*)x)[lane];
    float4 v1 = ((const float4*)x)[lane + 64];
    float s  = v0.x + v0.y + v0.z + v0.w + v1.x + v1.y + v1.z + v1.w;
    float sq = v0.x*v0.x + v0.y*v0.y + v0.z*v0.z + v0.w*v0.w
             + v1.x*v1.x + v1.y*v1.y + v1.z*v1.z + v1.w*v1.w;
#pragma unroll
    for (int off = 32; off > 0; off >>= 1) {
        s  += __shfl_down(s, off);
        sq += __shfl_down(sq, off);
    }
    s  = __shfl(s, 0);
    sq = __shfl(sq, 0);
    float mean = s * (1.f / 512.f);
    float var  = sq * (1.f / 512.f) - mean * mean;
    float rinv = rsqrtf(var + 1e-6f);
    float4 g0 = ((const float4*)g)[lane], g1 = ((const float4*)g)[lane + 64];
    float4 b0 = ((const float4*)b)[lane], b1 = ((const float4*)b)[lane + 64];
    float4 o0, o1;
    o0.x = (v0.x - mean) * rinv * g0.x + b0.x;
    o0.y = (v0.y - mean) * rinv * g0.y + b0.y;
    o0.z = (v0.z - mean) * rinv * g0.z + b0.z;
    o0.w = (v0.w - mean) * rinv * g0.w + b0.w;
    o1.x = (v1.x - mean) * rinv * g1.x + b1.x;
    o1.y = (v1.y - mean) * rinv * g1.y + b1.y;
    o1.z = (v1.z - mean) * rinv * g1.z + b1.z;
    o1.w = (v1.w - mean) * rinv * g1.w + b1.w;
    if (PLANES) {
        ushort4 hh0, ll0, hh1, ll1;
        uint16_t h, lo;
        split_bf16(o0.x, h, lo); hh0.x = h; ll0.x = lo;
        split_bf16(o0.y, h, lo); hh0.y = h; ll0.y = lo;
        split_bf16(o0.z, h, lo); hh0.z = h; ll0.z = lo;
        split_bf16(o0.w, h, lo); hh0.w = h; ll0.w = lo;
        split_bf16(o1.x, h, lo); hh1.x = h; ll1.x = lo;
        split_bf16(o1.y, h, lo); hh1.y = h; ll1.y = lo;
        split_bf16(o1.z, h, lo); hh1.z = h; ll1.z = lo;
        split_bf16(o1.w, h, lo); hh1.w = h; ll1.w = lo;
        size_t base = (size_t)row * 512;
        *(ushort4*)(Yh + base + lane * 4)       = hh0;
        *(ushort4*)(Yl + base + lane * 4)       = ll0;
        *(ushort4*)(Yh + base + 256 + lane * 4) = hh1;
        *(ushort4*)(Yl + base + 256 + lane * 4) = ll1;
    } else {
        float* y = Y + (size_t)row * 512;
        ((float4*)y)[lane]      = o0;
        ((float4*)y)[lane + 64] = o1;
    }
}

// ---------------------------------------------------------------------------
// Attention: one block per (batch,head); K,V in LDS; one query per thread.
// Emits O as bf16 hi/lo planes.
// ---------------------------------------------------------------------------
__global__ __launch_bounds__(256)
void attn_kernel(const float* __restrict__ QKV, uint16_t* __restrict__ Oh,
                 uint16_t* __restrict__ Ol)
{
    __shared__ float Ks[256][64];
    __shared__ float Vs[256][64];
    int bh = blockIdx.x;
    int b = bh >> 3, h = bh & 7;
    const float* base = QKV + (size_t)b * 256 * 1536;

    for (int i = threadIdx.x; i < 256 * 16; i += 256) {
        int r = i >> 4, d4 = i & 15;
        const float* krow = base + (size_t)r * 1536 + 512 + h * 64;
        const float* vrow = base + (size_t)r * 1536 + 1024 + h * 64;
        *(float4*)&Ks[r][d4 * 4] = *(const float4*)(krow + d4 * 4);
        *(float4*)&Vs[r][d4 * 4] = *(const float4*)(vrow + d4 * 4);
    }
    float q[64];
    const float* qp = base + (size_t)threadIdx.x * 1536 + h * 64;
#pragma unroll
    for (int i = 0; i < 16; ++i) *(float4*)&q[i * 4] = ((const float4*)qp)[i];
    __syncthreads();

    float o[64];
#pragma unroll
    for (int d = 0; d < 64; ++d) o[d] = 0.f;
    float den = 0.f;
#pragma unroll 2
    for (int k = 0; k < 256; ++k) {
        float sc = 0.f;
#pragma unroll
        for (int d = 0; d < 64; ++d) sc = fmaf(q[d], Ks[k][d], sc);
        float e = __expf(sc * 0.125f);
        den += e;
#pragma unroll
        for (int d = 0; d < 64; ++d) o[d] = fmaf(e, Vs[k][d], o[d]);
    }
    float inv = 1.f / den;
    size_t ob = ((size_t)b * 256 + threadIdx.x) * 512 + h * 64;
#pragma unroll
    for (int i4 = 0; i4 < 16; ++i4) {
        ushort4 hh, ll;
        uint16_t h16, lo16;
        split_bf16(o[i4 * 4 + 0] * inv, h16, lo16); hh.x = h16; ll.x = lo16;
        split_bf16(o[i4 * 4 + 1] * inv, h16, lo16); hh.y = h16; ll.y = lo16;
        split_bf16(o[i4 * 4 + 2] * inv, h16, lo16); hh.z = h16; ll.z = lo16;
        split_bf16(o[i4 * 4 + 3] * inv, h16, lo16); hh.w = h16; ll.w = lo16;
        *(ushort4*)(Oh + ob + i4 * 4) = hh;
        *(ushort4*)(Ol + ob + i4 * 4) = ll;
    }
}

// ---------------------------------------------------------------------------
// fp32 tiled GEMM (kept for head layer 1 split-K)
// ---------------------------------------------------------------------------
template<int BM, int BN, int BK, int TM, int TN, bool SPLITK>
__global__ __launch_bounds__(256)
void gemm_kernel(const float* __restrict__ A, const float* __restrict__ B,
                 float* __restrict__ C, int M, int N, int K, int kchunk)
{
    constexpr int TX = BN / TN;
    constexpr int TY = BM / TM;
    static_assert(TX * TY == 256, "bad tile config");
    __shared__ float As[BK][BM + 4];
    __shared__ float Bs[BK][BN + 4];
    const int tid = threadIdx.x;
    const int tx  = tid % TX;
    const int ty  = tid / TX;
    const int bn0 = blockIdx.x * BN;
    const int bm0 = blockIdx.y * BM;
    int kstart = 0, kend = K;
    if (SPLITK) { kstart = blockIdx.z * kchunk; kend = kstart + kchunk; }
    float acc[TM][TN];
#pragma unroll
    for (int i = 0; i < TM; ++i)
#pragma unroll
        for (int j = 0; j < TN; ++j) acc[i][j] = 0.f;
    for (int k0 = kstart; k0 < kend; k0 += BK) {
        __syncthreads();
        constexpr int AV = BM * BK / 4 / 256;
#pragma unroll
        for (int r = 0; r < AV; ++r) {
            int idx = tid + r * 256;
            int k4 = idx % (BK / 4);
            int mm = idx / (BK / 4);
            float4 v = *(const float4*)(A + (size_t)(bm0 + mm) * K + k0 + k4 * 4);
            As[k4 * 4 + 0][mm] = v.x;
            As[k4 * 4 + 1][mm] = v.y;
            As[k4 * 4 + 2][mm] = v.z;
            As[k4 * 4 + 3][mm] = v.w;
        }
        constexpr int BV = BK * BN / 4 / 256;
#pragma unroll
        for (int r = 0; r < BV; ++r) {
            int idx = tid + r * 256;
            int n4 = idx % (BN / 4);
            int kk = idx / (BN / 4);
            float4 v = *(const float4*)(B + (size_t)(k0 + kk) * N + bn0 + n4 * 4);
            *(float4*)&Bs[kk][n4 * 4] = v;
        }
        __syncthreads();
#pragma unroll
        for (int kk = 0; kk < BK; ++kk) {
            float a[TM], b[TN];
#pragma unroll
            for (int i = 0; i < TM; i += 4)
                *(float4*)&a[i] = *(const float4*)&As[kk][ty * TM + i];
#pragma unroll
            for (int j = 0; j < TN; j += 4)
                *(float4*)&b[j] = *(const float4*)&Bs[kk][tx * TN + j];
#pragma unroll
            for (int i = 0; i < TM; ++i)
#pragma unroll
                for (int j = 0; j < TN; ++j)
                    acc[i][j] = fmaf(a[i], b[j], acc[i][j]);
        }
    }
    float* Cb = C;
    if (SPLITK) Cb += (size_t)blockIdx.z * M * N;
#pragma unroll
    for (int i = 0; i < TM; ++i) {
        int m = bm0 + ty * TM + i;
#pragma unroll
        for (int j = 0; j < TN; j += 4) {
            int n = bn0 + tx * TN + j;
            float4 v;
            v.x = acc[i][j + 0]; v.y = acc[i][j + 1];
            v.z = acc[i][j + 2]; v.w = acc[i][j + 3];
            *(float4*)(Cb + (size_t)m * N + n) = v;
        }
    }
}

__global__ __launch_bounds__(256)
void skinny_gemm_kernel(const float* __restrict__ A, const float* __restrict__ B,
                        float* __restrict__ P, int M, int N, int K, int kchunk)
{
    __shared__ float As[32][36];
    const int tid = threadIdx.x;
    const int tx  = tid & 63;
    const int ty  = tid >> 6;
    const int bn0 = blockIdx.x * 64;
    const int kstart = blockIdx.y * kchunk;
    const int kend   = kstart + kchunk;
    float acc[8];
#pragma unroll
    for (int i = 0; i < 8; ++i) acc[i] = 0.f;
    for (int k0 = kstart; k0 < kend; k0 += 32) {
        __syncthreads();
        {
            int row = tid >> 3;
            int k4  = tid & 7;
            float4 v = *(const float4*)(A + (size_t)row * K + k0 + k4 * 4);
            *(float4*)&As[row][k4 * 4] = v;
        }
        __syncthreads();
#pragma unroll 8
        for (int kk = 0; kk < 32; ++kk) {
            float b = B[(size_t)(k0 + kk) * N + bn0 + tx];
#pragma unroll
            for (int i = 0; i < 8; ++i)
                acc[i] = fmaf(As[ty * 8 + i][kk], b, acc[i]);
        }
    }
    float* Pb = P + (size_t)blockIdx.y * M * N;
#pragma unroll
    for (int i = 0; i < 8; ++i)
        Pb[(size_t)(ty * 8 + i) * N + bn0 + tx] = acc[i];
}

__global__ __launch_bounds__(256)
void reduce_gelu_kernel(const float* __restrict__ P, const float* __restrict__ bias,
                        float* __restrict__ Y, int total, int chunks, int N)
{
    int idx = blockIdx.x * 256 + threadIdx.x;
    if (idx >= total) return;
    float s = 0.f;
    for (int c = 0; c < chunks; ++c) s += P[(size_t)c * total + idx];
    s += bias[idx % N];
    Y[idx] = gelu_f(s);
}

template<bool GELU>
__global__ __launch_bounds__(256)
void small_gemm_kernel(const float* __restrict__ A, const float* __restrict__ B,
                       const float* __restrict__ bias, float* __restrict__ C,
                       int M, int N, int K)
{
    int idx = blockIdx.x * 256 + threadIdx.x;
    if (idx >= M * N) return;
    int m = idx / N, n = idx % N;
    const float* a = A + (size_t)m * K;
    float s = 0.f;
    for (int k = 0; k < K; ++k) s = fmaf(a[k], B[(size_t)k * N + n], s);
    s += bias[n];
    if (GELU) s = gelu_f(s);
    C[idx] = s;
}

// ---------------------------------------------------------------------------
extern "C" void kernel_launch(void* const* d_in, const int* in_sizes, int n_in,
                              void* d_out, int out_size, void* d_ws, size_t ws_size,
                              hipStream_t stream)
{
    const float* images     = (const float*)d_in[0];
    const float* W_proj     = (const float*)d_in[1];
    const float* b_proj     = (const float*)d_in[2];
    const float* pos_emb    = (const float*)d_in[3];
    const float* ln1_g      = (const float*)d_in[4];
    const float* ln1_b      = (const float*)d_in[5];
    const float* qkv_w      = (const float*)d_in[6];
    const float* qkv_b      = (const float*)d_in[7];
    const float* attn_out_w = (const float*)d_in[8];
    const float* attn_out_b = (const float*)d_in[9];
    const float* ln2_g      = (const float*)d_in[10];
    const float* ln2_b      = (const float*)d_in[11];
    const float* mlp_w1     = (const float*)d_in[12];
    const float* mlp_b1     = (const float*)d_in[13];
    const float* mlp_w2     = (const float*)d_in[14];
    const float* mlp_b2     = (const float*)d_in[15];
    const float* lnf_g      = (const float*)d_in[16];
    const float* lnf_b      = (const float*)d_in[17];
    const float* hW1 = (const float*)d_in[18];
    const float* hb1 = (const float*)d_in[19];
    const float* hW2 = (const float*)d_in[20];
    const float* hb2 = (const float*)d_in[21];
    const float* hW3 = (const float*)d_in[22];
    const float* hb3 = (const float*)d_in[23];
    const float* hW4 = (const float*)d_in[24];
    const float* hb4 = (const float*)d_in[25];
    const float* hW5 = (const float*)d_in[26];
    const float* hb5 = (const float*)d_in[27];
    const float* bbW = (const float*)d_in[28];
    const float* bbb = (const float*)d_in[29];

    // ---- workspace layout ----
    uint8_t* wsb = (uint8_t*)d_ws;
    size_t off = 0;
    auto alloc = [&](size_t bytes) { uint8_t* p = wsb + off; off += (bytes + 255) & ~(size_t)255; return p; };
    float*    X    = (float*)alloc(8192ull * 512 * 4);
    float*    QKV  = (float*)alloc(8192ull * 1536 * 4);
    float*    T    = (float*)alloc(8192ull * 512 * 4);
    uint16_t* Xh   = (uint16_t*)alloc(8192ull * 512 * 2);
    uint16_t* Xl   = (uint16_t*)alloc(8192ull * 512 * 2);
    uint16_t* Ohp  = (uint16_t*)alloc(8192ull * 512 * 2);
    uint16_t* Olp  = (uint16_t*)alloc(8192ull * 512 * 2);
    uint16_t* Hh   = (uint16_t*)alloc(8192ull * 1024 * 2);
    uint16_t* Hl   = (uint16_t*)alloc(8192ull * 1024 * 2);
    uint16_t* Ph   = (uint16_t*)alloc(8192ull * 3072 * 2);
    uint16_t* Pl   = (uint16_t*)alloc(8192ull * 3072 * 2);
    uint16_t* WqH  = (uint16_t*)alloc(4ull * 1536 * 512 * 2);
    uint16_t* WqL  = (uint16_t*)alloc(4ull * 1536 * 512 * 2);
    uint16_t* WaH  = (uint16_t*)alloc(4ull * 512 * 512 * 2);
    uint16_t* WaL  = (uint16_t*)alloc(4ull * 512 * 512 * 2);
    uint16_t* WpH  = (uint16_t*)alloc(512ull * 3072 * 2);
    uint16_t* WpL  = (uint16_t*)alloc(512ull * 3072 * 2);
    uint16_t* W1H  = (uint16_t*)alloc(4ull * 1024 * 512 * 2);
    uint16_t* W1L  = (uint16_t*)alloc(4ull * 1024 * 512 * 2);
    uint16_t* W2H  = (uint16_t*)alloc(4ull * 512 * 1024 * 2);
    uint16_t* W2L  = (uint16_t*)alloc(4ull * 512 * 1024 * 2);
    float*    F1p  = (float*)alloc(64ull * 65536 * 4);
    float*    F1   = (float*)alloc(65536ull * 4);
    float*    P2   = (float*)alloc(64ull * 32768 * 4);
    float*    F2   = (float*)alloc(32768ull * 4);
    float*    P3   = (float*)alloc(32ull * 16384 * 4);
    float*    F3   = (float*)alloc(16384ull * 4);
    float*    P4   = (float*)alloc(16ull * 2048 * 4);
    float*    F4   = (float*)alloc(2048ull * 4);
    float*    F5   = (float*)alloc(1024ull * 4);

    dim3 blk(256);

    // ---- prep: convert weights + images to bf16 hi/lo planes ----
    img2planes_kernel<<<(8192 * 768 + 255) / 256, blk, 0, stream>>>(images, Ph, Pl);
    conv_direct_kernel<<<(4 * 1536 * 512 / 4 + 255) / 256, blk, 0, stream>>>(qkv_w, WqH, WqL, 4 * 1536 * 512 / 4);
    conv_direct_kernel<<<(4 * 512 * 512 / 4 + 255) / 256, blk, 0, stream>>>(attn_out_w, WaH, WaL, 4 * 512 * 512 / 4);
    conv_transpose_kernel<<<dim3(3072 / 32, 512 / 32, 1), blk, 0, stream>>>(W_proj, WpH, WpL, 3072, 512);
    conv_transpose_kernel<<<dim3(512 / 32, 1024 / 32, 4), blk, 0, stream>>>(mlp_w1, W1H, W1L, 512, 1024);
    conv_transpose_kernel<<<dim3(1024 / 32, 512 / 32, 4), blk, 0, stream>>>(mlp_w2, W2H, W2L, 1024, 512);

    // ---- patch embed: X = patches @ W_proj + b_proj + pos ----
    mfma_gemm<64, 128, true, false, false, true, true, false>
        <<<dim3(512 / 128, 8192 / 64), blk, 0, stream>>>(
            Ph, Pl, WpH, WpL, X, nullptr, nullptr, b_proj, nullptr, pos_emb, 8192, 512, 3072);

    for (int l = 0; l < 4; ++l) {
        ln_kernel<true><<<2048, blk, 0, stream>>>(X, ln1_g + l * 512, ln1_b + l * 512,
                                                  nullptr, Xh, Xl, 8192);
        mfma_gemm<128, 128, true, false, false, false, true, false>
            <<<dim3(1536 / 128, 8192 / 128), blk, 0, stream>>>(
                Xh, Xl, WqH + (size_t)l * 1536 * 512, WqL + (size_t)l * 1536 * 512,
                QKV, nullptr, nullptr, qkv_b + l * 1536, nullptr, nullptr, 8192, 1536, 512);
        attn_kernel<<<256, blk, 0, stream>>>(QKV, Ohp, Olp);
        mfma_gemm<64, 128, true, false, true, false, true, false>
            <<<dim3(512 / 128, 8192 / 64), blk, 0, stream>>>(
                Ohp, Olp, WaH + (size_t)l * 512 * 512, WaL + (size_t)l * 512 * 512,
                X, nullptr, nullptr, attn_out_b + l * 512, X, nullptr, 8192, 512, 512);
        ln_kernel<true><<<2048, blk, 0, stream>>>(X, ln2_g + l * 512, ln2_b + l * 512,
                                                  nullptr, Xh, Xl, 8192);
        mfma_gemm<128, 128, true, true, false, false, false, true>
            <<<dim3(1024 / 128, 8192 / 128), blk, 0, stream>>>(
                Xh, Xl, W1H + (size_t)l * 1024 * 512, W1L + (size_t)l * 1024 * 512,
                nullptr, Hh, Hl, mlp_b1 + l * 1024, nullptr, nullptr, 8192, 1024, 512);
        mfma_gemm<64, 128, true, true, true, false, true, false>
            <<<dim3(512 / 128, 8192 / 64), blk, 0, stream>>>(
                Hh, Hl, W2H + (size_t)l * 512 * 1024, W2L + (size_t)l * 512 * 1024,
                X, nullptr, nullptr, mlp_b2 + l * 512, X, nullptr, 8192, 512, 1024);
    }

    // ---- final LN -> fp32 T ([32, 131072]) ----
    ln_kernel<false><<<2048, blk, 0, stream>>>(X, lnf_g, lnf_b, T, nullptr, nullptr, 8192);

    // ---- MLP head ----
    gemm_kernel<32, 128, 32, 4, 4, true>
        <<<dim3(2048 / 128, 1, 64), blk, 0, stream>>>(
            T, hW1, F1p, 32, 2048, 131072, 131072 / 64);
    reduce_gelu_kernel<<<(65536 + 255) / 256, blk, 0, stream>>>(F1p, hb1, F1, 65536, 64, 2048);

    skinny_gemm_kernel<<<dim3(1024 / 64, 2048 / 32), blk, 0, stream>>>(F1, hW2, P2, 32, 1024, 2048, 32);
    reduce_gelu_kernel<<<(32768 + 255) / 256, blk, 0, stream>>>(P2, hb2, F2, 32768, 64, 1024);

    skinny_gemm_kernel<<<dim3(512 / 64, 1024 / 32), blk, 0, stream>>>(F2, hW3, P3, 32, 512, 1024, 32);
    reduce_gelu_kernel<<<(16384 + 255) / 256, blk, 0, stream>>>(P3, hb3, F3, 16384, 32, 512);

    skinny_gemm_kernel<<<dim3(64 / 64, 512 / 32), blk, 0, stream>>>(F3, hW4, P4, 32, 64, 512, 32);
    reduce_gelu_kernel<<<(2048 + 255) / 256, blk, 0, stream>>>(P4, hb4, F4, 2048, 16, 64);

    small_gemm_kernel<true><<<(32 * 32 + 255) / 256, blk, 0, stream>>>(F4, hW5, hb5, F5, 32, 32, 64);
    small_gemm_kernel<false><<<1, blk, 0, stream>>>(F5, bbW, bbb, (float*)d_out, 32, 4, 32);
}

// Round 4
// 1825.511 us; speedup vs baseline: 2.5105x; 1.0329x over previous
//
#include <hip/hip_runtime.h>
#include <cstdint>
#include <cstddef>

#define DEV __device__ __forceinline__

typedef float f32x4 __attribute__((ext_vector_type(4)));
typedef short s16x8 __attribute__((ext_vector_type(8)));

DEV float gelu_f(float x) { return 0.5f * x * (1.0f + erff(x * 0.70710678118654752f)); }

DEV uint32_t fbits(float x) { return __builtin_bit_cast(uint32_t, x); }
DEV float bcast_f(uint32_t u) { return __builtin_bit_cast(float, u); }

// split x into hi (bf16-truncate) and lo (bf16-truncate of residual)
DEV void split_bf16(float x, uint16_t& h, uint16_t& lo) {
    uint32_t xb = fbits(x);
    h = (uint16_t)(xb >> 16);
    float r = x - bcast_f(xb & 0xFFFF0000u);
    lo = (uint16_t)(fbits(r) >> 16);
}

DEV void gload16(const void* g, void* l) {
    __builtin_amdgcn_global_load_lds(
        (const __attribute__((address_space(1))) uint32_t*)g,
        (__attribute__((address_space(3))) uint32_t*)l, 16, 0, 0);
}

// ---------------------------------------------------------------------------
// Split-bf16 MFMA GEMM.  A-planes [M][K] bf16 hi/lo, B-planes [N][K] bf16
// hi/lo (k-major).  C = A@B^T_planes with fp32 accumulate via 3 MFMA passes.
// 2-phase double-buffered pipeline: global_load_lds for K-tile t+1 issued
// BEFORE ds_read+MFMA of tile t; one vmcnt(0)+s_barrier per K-step.
// LDS layout per plane: [rows][4 slots of 16B], slot XOR-swizzled via the
// per-lane GLOBAL source address (LDS linear for global_load_lds).
// ---------------------------------------------------------------------------
template<int BM, int BN, bool BIAS, bool GELU, bool RES, bool POS, bool OUTF32, bool OUTPL>
__global__ __launch_bounds__(256)
void mfma_gemm(const uint16_t* __restrict__ Ah, const uint16_t* __restrict__ Al,
               const uint16_t* __restrict__ Bh, const uint16_t* __restrict__ Bl,
               float* __restrict__ C, uint16_t* __restrict__ Chi, uint16_t* __restrict__ Clo,
               const float* __restrict__ bias, const float* __restrict__ res,
               const float* __restrict__ pos, int M, int N, int K)
{
    constexpr int WTM = BM / 2, WTN = BN / 2;
    constexpr int FM = WTM / 16, FN = WTN / 16;
    constexpr int NA = BM / 16, NB = BN / 16;      // 1KB chunks per A/B plane
    constexpr int TI = 2 * NA + 2 * NB;            // total gload instrs per K-step
    constexpr int TI4 = TI / 4;                    // per wave
    constexpr int HALF = (2 * BM + 2 * BN) * 64;   // bytes per K-step plane set

    __shared__ __align__(16) uint8_t smem[2 * HALF];
    constexpr int offAh = 0, offAl = BM * 64, offBh = 2 * BM * 64, offBl = 2 * BM * 64 + BN * 64;

    const int tid = threadIdx.x;
    const int w = tid >> 6, l = tid & 63;
    const int wr = w >> 1, wc = w & 1;
    const int bm0 = blockIdx.y * BM, bn0 = blockIdx.x * BN;
    const size_t sK = (size_t)K * 2;               // row stride in bytes

    // ---- staging descriptors (per-lane global addr, wave-uniform LDS off) ----
    const int srow  = l >> 2;
    const int sslot = (l & 3) ^ ((l >> 3) & 3);
    const uint8_t* gsrc[TI4];
    uint32_t loff[TI4];
#pragma unroll
    for (int j = 0; j < TI4; ++j) {
        int f = w * TI4 + j;
        int p = (f < NA) ? 0 : (f < 2 * NA) ? 1 : (f < 2 * NA + NB) ? 2 : 3;
        int c = f - (p == 0 ? 0 : p == 1 ? NA : p == 2 ? 2 * NA : 2 * NA + NB);
        const uint16_t* base = p == 0 ? Ah : p == 1 ? Al : p == 2 ? Bh : Bl;
        int rb = (p < 2) ? bm0 : bn0;
        gsrc[j] = (const uint8_t*)base + (size_t)(rb + c * 16 + srow) * sK + sslot * 16;
        loff[j] = (uint32_t)((p == 0 ? offAh : p == 1 ? offAl : p == 2 ? offBh : offBl) + c * 1024);
    }

    // ---- fragment read offsets ----
    const int lr = l & 15;
    const int sl16 = ((l >> 4) ^ ((lr >> 1) & 3)) * 16;
    const int aofs = (wr * WTM + lr) * 64 + sl16;
    const int bofs = (wc * WTN + lr) * 64 + sl16;

    f32x4 acc[FM][FN];
#pragma unroll
    for (int m = 0; m < FM; ++m)
#pragma unroll
        for (int n = 0; n < FN; ++n) acc[m][n] = (f32x4){0.f, 0.f, 0.f, 0.f};

    // ---- prologue: stage K-tile 0 into buffer 0 ----
    {
        const uint8_t* s0 = smem;
#pragma unroll
        for (int j = 0; j < TI4; ++j)
            gload16(gsrc[j], (void*)(s0 + loff[j]));
    }
    asm volatile("s_waitcnt vmcnt(0)" ::: "memory");
    __builtin_amdgcn_s_barrier();

    int cur = 0;
    for (int k0 = 0; k0 < K; k0 += 32) {
        const bool more = (k0 + 32 < K);
        // ---- issue prefetch of next K-tile into the other buffer ----
        if (more) {
            const size_t kb = (size_t)(k0 + 32) * 2;
            uint8_t* dst = smem + (cur ^ 1) * HALF;
#pragma unroll
            for (int j = 0; j < TI4; ++j)
                gload16(gsrc[j] + kb, dst + loff[j]);
        }
        // ---- fragments from current buffer ----
        const uint8_t* sb = smem + cur * HALF;
        s16x8 ah[FM], al[FM], bh[FN], bl[FN];
#pragma unroll
        for (int m = 0; m < FM; ++m) {
            ah[m] = *(const s16x8*)(sb + offAh + aofs + m * 1024);
            al[m] = *(const s16x8*)(sb + offAl + aofs + m * 1024);
        }
#pragma unroll
        for (int n = 0; n < FN; ++n) {
            bh[n] = *(const s16x8*)(sb + offBh + bofs + n * 1024);
            bl[n] = *(const s16x8*)(sb + offBl + bofs + n * 1024);
        }
#pragma unroll
        for (int m = 0; m < FM; ++m)
#pragma unroll
            for (int n = 0; n < FN; ++n)
                acc[m][n] = __builtin_amdgcn_mfma_f32_16x16x32_bf16(ah[m], bh[n], acc[m][n], 0, 0, 0);
#pragma unroll
        for (int m = 0; m < FM; ++m)
#pragma unroll
            for (int n = 0; n < FN; ++n)
                acc[m][n] = __builtin_amdgcn_mfma_f32_16x16x32_bf16(ah[m], bl[n], acc[m][n], 0, 0, 0);
#pragma unroll
        for (int m = 0; m < FM; ++m)
#pragma unroll
            for (int n = 0; n < FN; ++n)
                acc[m][n] = __builtin_amdgcn_mfma_f32_16x16x32_bf16(al[m], bh[n], acc[m][n], 0, 0, 0);

        if (more) {
            asm volatile("s_waitcnt vmcnt(0)" ::: "memory");
            __builtin_amdgcn_s_barrier();
        }
        cur ^= 1;
    }

    // ---- epilogue: C/D layout col=lane&15, row=(lane>>4)*4+reg ----
    const int r4 = (l >> 4) * 4;
#pragma unroll
    for (int m = 0; m < FM; ++m) {
#pragma unroll
        for (int n = 0; n < FN; ++n) {
            int nn = bn0 + wc * WTN + n * 16 + lr;
#pragma unroll
            for (int r = 0; r < 4; ++r) {
                int mm = bm0 + wr * WTM + m * 16 + r4 + r;
                float x = acc[m][n][r];
                if (BIAS) x += bias[nn];
                if (GELU) x = gelu_f(x);
                if (RES)  x += res[(size_t)mm * N + nn];
                if (POS)  x += pos[(size_t)(mm & 255) * N + nn];
                size_t o = (size_t)mm * N + nn;
                if (OUTF32) C[o] = x;
                if (OUTPL) {
                    uint16_t h, lo;
                    split_bf16(x, h, lo);
                    Chi[o] = h; Clo[o] = lo;
                }
            }
        }
    }
}

// ---------------------------------------------------------------------------
// Prep: images -> patch-gathered bf16 hi/lo planes [8192][3072]
// ---------------------------------------------------------------------------
__global__ __launch_bounds__(256)
void img2planes_kernel(const float* __restrict__ img, uint16_t* __restrict__ Ph,
                       uint16_t* __restrict__ Pl)
{
    int idx = blockIdx.x * 256 + threadIdx.x;   // over 8192*768
    if (idx >= 8192 * 768) return;
    int m = idx / 768, q = idx - (idx / 768) * 768;
    int k = q * 4;
    int bb = m >> 8, n = m & 255;
    int ph = k / 96, rem = k - ph * 96;
    int prow = ((n >> 4) << 5) + ph;
    int pcol0 = (n & 15) << 5;
    const float* s = img + (((size_t)bb * 512 + prow) * 512 + pcol0) * 3 + rem;
    float4 v = *(const float4*)s;
    ushort4 hh, ll;
    uint16_t h, lo;
    split_bf16(v.x, h, lo); hh.x = h; ll.x = lo;
    split_bf16(v.y, h, lo); hh.y = h; ll.y = lo;
    split_bf16(v.z, h, lo); hh.z = h; ll.z = lo;
    split_bf16(v.w, h, lo); hh.w = h; ll.w = lo;
    size_t o = (size_t)m * 3072 + k;
    *(ushort4*)(Ph + o) = hh;
    *(ushort4*)(Pl + o) = ll;
}

// ---------------------------------------------------------------------------
// Prep: direct convert fp32 [N][K] -> bf16 hi/lo planes (same layout)
// ---------------------------------------------------------------------------
__global__ __launch_bounds__(256)
void conv_direct_kernel(const float* __restrict__ src, uint16_t* __restrict__ dh,
                        uint16_t* __restrict__ dl, int total4)
{
    int idx = blockIdx.x * 256 + threadIdx.x;
    if (idx >= total4) return;
    float4 v = *(const float4*)(src + (size_t)idx * 4);
    ushort4 hh, ll;
    uint16_t h, lo;
    split_bf16(v.x, h, lo); hh.x = h; ll.x = lo;
    split_bf16(v.y, h, lo); hh.y = h; ll.y = lo;
    split_bf16(v.z, h, lo); hh.z = h; ll.z = lo;
    split_bf16(v.w, h, lo); hh.w = h; ll.w = lo;
    *(ushort4*)(dh + (size_t)idx * 4) = hh;
    *(ushort4*)(dl + (size_t)idx * 4) = ll;
}

// ---------------------------------------------------------------------------
// Prep: transpose-convert fp32 [K][N] -> bf16 hi/lo planes [N][K]
// grid (K/32, N/32, layers)
// ---------------------------------------------------------------------------
__global__ __launch_bounds__(256)
void conv_transpose_kernel(const float* __restrict__ src, uint16_t* __restrict__ dh,
                           uint16_t* __restrict__ dl, int K, int N)
{
    __shared__ float t[32][33];
    int k0 = blockIdx.x * 32, n0 = blockIdx.y * 32;
    const float* s = src + (size_t)blockIdx.z * K * N;
    size_t dbase = (size_t)blockIdx.z * N * K;
    int tid = threadIdx.x;
    {
        int kk = tid / 8, n4 = tid % 8;
        float4 v = *(const float4*)(s + (size_t)(k0 + kk) * N + n0 + n4 * 4);
        t[kk][n4 * 4 + 0] = v.x; t[kk][n4 * 4 + 1] = v.y;
        t[kk][n4 * 4 + 2] = v.z; t[kk][n4 * 4 + 3] = v.w;
    }
    __syncthreads();
    int nn = tid / 8, k4 = tid % 8;
    ushort4 hh, ll;
    uint16_t h, lo;
    float x0 = t[k4 * 4 + 0][nn], x1 = t[k4 * 4 + 1][nn], x2 = t[k4 * 4 + 2][nn], x3 = t[k4 * 4 + 3][nn];
    split_bf16(x0, h, lo); hh.x = h; ll.x = lo;
    split_bf16(x1, h, lo); hh.y = h; ll.y = lo;
    split_bf16(x2, h, lo); hh.z = h; ll.z = lo;
    split_bf16(x3, h, lo); hh.w = h; ll.w = lo;
    size_t o = dbase + (size_t)(n0 + nn) * K + k0 + k4 * 4;
    *(ushort4*)(dh + o) = hh;
    *(ushort4*)(dl + o) = ll;
}

// ---------------------------------------------------------------------------
// LayerNorm over rows of 512; optionally emit bf16 hi/lo planes.
// ---------------------------------------------------------------------------
template<bool PLANES>
__global__ __launch_bounds__(256)
void ln_kernel(const float* __restrict__ X, const float* __restrict__ g,
               const float* __restrict__ b, float* __restrict__ Y,
               uint16_t* __restrict__ Yh, uint16_t* __restrict__ Yl, int nrows)
{
    int wave = threadIdx.x >> 6;
    int lane = threadIdx.x & 63;
    int row = blockIdx.x * 4 + wave;
    if (row >= nrows) return;
    const float* x = X + (size_t)row * 512;
    float4 v0 = ((const float4*)x)[lane];
    float4 v1 = ((const float4*)x)[lane + 64];
    float s  = v0.x + v0.y + v0.z + v0.w + v1.x + v1.y + v1.z + v1.w;
    float sq = v0.x*v0.x + v0.y*v0.y + v0.z*v0.z + v0.w*v0.w
             + v1.x*v1.x + v1.y*v1.y + v1.z*v1.z + v1.w*v1.w;
#pragma unroll
    for (int off = 32; off > 0; off >>= 1) {
        s  += __shfl_down(s, off);
        sq += __shfl_down(sq, off);
    }
    s  = __shfl(s, 0);
    sq = __shfl(sq, 0);
    float mean = s * (1.f / 512.f);
    float var  = sq * (1.f / 512.f) - mean * mean;
    float rinv = rsqrtf(var + 1e-6f);
    float4 g0 = ((const float4*)g)[lane], g1 = ((const float4*)g)[lane + 64];
    float4 b0 = ((const float4*)b)[lane], b1 = ((const float4*)b)[lane + 64];
    float4 o0, o1;
    o0.x = (v0.x - mean) * rinv * g0.x + b0.x;
    o0.y = (v0.y - mean) * rinv * g0.y + b0.y;
    o0.z = (v0.z - mean) * rinv * g0.z + b0.z;
    o0.w = (v0.w - mean) * rinv * g0.w + b0.w;
    o1.x = (v1.x - mean) * rinv * g1.x + b1.x;
    o1.y = (v1.y - mean) * rinv * g1.y + b1.y;
    o1.z = (v1.z - mean) * rinv * g1.z + b1.z;
    o1.w = (v1.w - mean) * rinv * g1.w + b1.w;
    if (PLANES) {
        ushort4 hh0, ll0, hh1, ll1;
        uint16_t h, lo;
        split_bf16(o0.x, h, lo); hh0.x = h; ll0.x = lo;
        split_bf16(o0.y, h, lo); hh0.y = h; ll0.y = lo;
        split_bf16(o0.z, h, lo); hh0.z = h; ll0.z = lo;
        split_bf16(o0.w, h, lo); hh0.w = h; ll0.w = lo;
        split_bf16(o1.x, h, lo); hh1.x = h; ll1.x = lo;
        split_bf16(o1.y, h, lo); hh1.y = h; ll1.y = lo;
        split_bf16(o1.z, h, lo); hh1.z = h; ll1.z = lo;
        split_bf16(o1.w, h, lo); hh1.w = h; ll1.w = lo;
        size_t base = (size_t)row * 512;
        *(ushort4*)(Yh + base + lane * 4)       = hh0;
        *(ushort4*)(Yl + base + lane * 4)       = ll0;
        *(ushort4*)(Yh + base + 256 + lane * 4) = hh1;
        *(ushort4*)(Yl + base + 256 + lane * 4) = ll1;
    } else {
        float* y = Y + (size_t)row * 512;
        ((float4*)y)[lane]      = o0;
        ((float4*)y)[lane + 64] = o1;
    }
}

// ---------------------------------------------------------------------------
// Attention: one block per (batch,head); K,V in LDS; one query per thread.
// Emits O as bf16 hi/lo planes.
// ---------------------------------------------------------------------------
__global__ __launch_bounds__(256)
void attn_kernel(const float* __restrict__ QKV, uint16_t* __restrict__ Oh,
                 uint16_t* __restrict__ Ol)
{
    __shared__ float Ks[256][64];
    __shared__ float Vs[256][64];
    int bh = blockIdx.x;
    int b = bh >> 3, h = bh & 7;
    const float* base = QKV + (size_t)b * 256 * 1536;

    for (int i = threadIdx.x; i < 256 * 16; i += 256) {
        int r = i >> 4, d4 = i & 15;
        const float* krow = base + (size_t)r * 1536 + 512 + h * 64;
        const float* vrow = base + (size_t)r * 1536 + 1024 + h * 64;
        *(float4*)&Ks[r][d4 * 4] = *(const float4*)(krow + d4 * 4);
        *(float4*)&Vs[r][d4 * 4] = *(const float4*)(vrow + d4 * 4);
    }
    float q[64];
    const float* qp = base + (size_t)threadIdx.x * 1536 + h * 64;
#pragma unroll
    for (int i = 0; i < 16; ++i) *(float4*)&q[i * 4] = ((const float4*)qp)[i];
    __syncthreads();

    float o[64];
#pragma unroll
    for (int d = 0; d < 64; ++d) o[d] = 0.f;
    float den = 0.f;
#pragma unroll 2
    for (int k = 0; k < 256; ++k) {
        float sc = 0.f;
#pragma unroll
        for (int d = 0; d < 64; ++d) sc = fmaf(q[d], Ks[k][d], sc);
        float e = __expf(sc * 0.125f);
        den += e;
#pragma unroll
        for (int d = 0; d < 64; ++d) o[d] = fmaf(e, Vs[k][d], o[d]);
    }
    float inv = 1.f / den;
    size_t ob = ((size_t)b * 256 + threadIdx.x) * 512 + h * 64;
#pragma unroll
    for (int i4 = 0; i4 < 16; ++i4) {
        ushort4 hh, ll;
        uint16_t h16, lo16;
        split_bf16(o[i4 * 4 + 0] * inv, h16, lo16); hh.x = h16; ll.x = lo16;
        split_bf16(o[i4 * 4 + 1] * inv, h16, lo16); hh.y = h16; ll.y = lo16;
        split_bf16(o[i4 * 4 + 2] * inv, h16, lo16); hh.z = h16; ll.z = lo16;
        split_bf16(o[i4 * 4 + 3] * inv, h16, lo16); hh.w = h16; ll.w = lo16;
        *(ushort4*)(Oh + ob + i4 * 4) = hh;
        *(ushort4*)(Ol + ob + i4 * 4) = ll;
    }
}

// ---------------------------------------------------------------------------
// fp32 tiled GEMM (kept for head layer 1 split-K)
// ---------------------------------------------------------------------------
template<int BM, int BN, int BK, int TM, int TN, bool SPLITK>
__global__ __launch_bounds__(256)
void gemm_kernel(const float* __restrict__ A, const float* __restrict__ B,
                 float* __restrict__ C, int M, int N, int K, int kchunk)
{
    constexpr int TX = BN / TN;
    constexpr int TY = BM / TM;
    static_assert(TX * TY == 256, "bad tile config");
    __shared__ float As[BK][BM + 4];
    __shared__ float Bs[BK][BN + 4];
    const int tid = threadIdx.x;
    const int tx  = tid % TX;
    const int ty  = tid / TX;
    const int bn0 = blockIdx.x * BN;
    const int bm0 = blockIdx.y * BM;
    int kstart = 0, kend = K;
    if (SPLITK) { kstart = blockIdx.z * kchunk; kend = kstart + kchunk; }
    float acc[TM][TN];
#pragma unroll
    for (int i = 0; i < TM; ++i)
#pragma unroll
        for (int j = 0; j < TN; ++j) acc[i][j] = 0.f;
    for (int k0 = kstart; k0 < kend; k0 += BK) {
        __syncthreads();
        constexpr int AV = BM * BK / 4 / 256;
#pragma unroll
        for (int r = 0; r < AV; ++r) {
            int idx = tid + r * 256;
            int k4 = idx % (BK / 4);
            int mm = idx / (BK / 4);
            float4 v = *(const float4*)(A + (size_t)(bm0 + mm) * K + k0 + k4 * 4);
            As[k4 * 4 + 0][mm] = v.x;
            As[k4 * 4 + 1][mm] = v.y;
            As[k4 * 4 + 2][mm] = v.z;
            As[k4 * 4 + 3][mm] = v.w;
        }
        constexpr int BV = BK * BN / 4 / 256;
#pragma unroll
        for (int r = 0; r < BV; ++r) {
            int idx = tid + r * 256;
            int n4 = idx % (BN / 4);
            int kk = idx / (BN / 4);
            float4 v = *(const float4*)(B + (size_t)(k0 + kk) * N + bn0 + n4 * 4);
            *(float4*)&Bs[kk][n4 * 4] = v;
        }
        __syncthreads();
#pragma unroll
        for (int kk = 0; kk < BK; ++kk) {
            float a[TM], b[TN];
#pragma unroll
            for (int i = 0; i < TM; i += 4)
                *(float4*)&a[i] = *(const float4*)&As[kk][ty * TM + i];
#pragma unroll
            for (int j = 0; j < TN; j += 4)
                *(float4*)&b[j] = *(const float4*)&Bs[kk][tx * TN + j];
#pragma unroll
            for (int i = 0; i < TM; ++i)
#pragma unroll
                for (int j = 0; j < TN; ++j)
                    acc[i][j] = fmaf(a[i], b[j], acc[i][j]);
        }
    }
    float* Cb = C;
    if (SPLITK) Cb += (size_t)blockIdx.z * M * N;
#pragma unroll
    for (int i = 0; i < TM; ++i) {
        int m = bm0 + ty * TM + i;
#pragma unroll
        for (int j = 0; j < TN; j += 4) {
            int n = bn0 + tx * TN + j;
            float4 v;
            v.x = acc[i][j + 0]; v.y = acc[i][j + 1];
            v.z = acc[i][j + 2]; v.w = acc[i][j + 3];
            *(float4*)(Cb + (size_t)m * N + n) = v;
        }
    }
}

__global__ __launch_bounds__(256)
void skinny_gemm_kernel(const float* __restrict__ A, const float* __restrict__ B,
                        float* __restrict__ P, int M, int N, int K, int kchunk)
{
    __shared__ float As[32][36];
    const int tid = threadIdx.x;
    const int tx  = tid & 63;
    const int ty  = tid >> 6;
    const int bn0 = blockIdx.x * 64;
    const int kstart = blockIdx.y * kchunk;
    const int kend   = kstart + kchunk;
    float acc[8];
#pragma unroll
    for (int i = 0; i < 8; ++i) acc[i] = 0.f;
    for (int k0 = kstart; k0 < kend; k0 += 32) {
        __syncthreads();
        {
            int row = tid >> 3;
            int k4  = tid & 7;
            float4 v = *(const float4*)(A + (size_t)row * K + k0 + k4 * 4);
            *(float4*)&As[row][k4 * 4] = v;
        }
        __syncthreads();
#pragma unroll 8
        for (int kk = 0; kk < 32; ++kk) {
            float b = B[(size_t)(k0 + kk) * N + bn0 + tx];
#pragma unroll
            for (int i = 0; i < 8; ++i)
                acc[i] = fmaf(As[ty * 8 + i][kk], b, acc[i]);
        }
    }
    float* Pb = P + (size_t)blockIdx.y * M * N;
#pragma unroll
    for (int i = 0; i < 8; ++i)
        Pb[(size_t)(ty * 8 + i) * N + bn0 + tx] = acc[i];
}

__global__ __launch_bounds__(256)
void reduce_gelu_kernel(const float* __restrict__ P, const float* __restrict__ bias,
                        float* __restrict__ Y, int total, int chunks, int N)
{
    int idx = blockIdx.x * 256 + threadIdx.x;
    if (idx >= total) return;
    float s = 0.f;
    for (int c = 0; c < chunks; ++c) s += P[(size_t)c * total + idx];
    s += bias[idx % N];
    Y[idx] = gelu_f(s);
}

template<bool GELU>
__global__ __launch_bounds__(256)
void small_gemm_kernel(const float* __restrict__ A, const float* __restrict__ B,
                       const float* __restrict__ bias, float* __restrict__ C,
                       int M, int N, int K)
{
    int idx = blockIdx.x * 256 + threadIdx.x;
    if (idx >= M * N) return;
    int m = idx / N, n = idx % N;
    const float* a = A + (size_t)m * K;
    float s = 0.f;
    for (int k = 0; k < K; ++k) s = fmaf(a[k], B[(size_t)k * N + n], s);
    s += bias[n];
    if (GELU) s = gelu_f(s);
    C[idx] = s;
}

// ---------------------------------------------------------------------------
extern "C" void kernel_launch(void* const* d_in, const int* in_sizes, int n_in,
                              void* d_out, int out_size, void* d_ws, size_t ws_size,
                              hipStream_t stream)
{
    const float* images     = (const float*)d_in[0];
    const float* W_proj     = (const float*)d_in[1];
    const float* b_proj     = (const float*)d_in[2];
    const float* pos_emb    = (const float*)d_in[3];
    const float* ln1_g      = (const float*)d_in[4];
    const float* ln1_b      = (const float*)d_in[5];
    const float* qkv_w      = (const float*)d_in[6];
    const float* qkv_b      = (const float*)d_in[7];
    const float* attn_out_w = (const float*)d_in[8];
    const float* attn_out_b = (const float*)d_in[9];
    const float* ln2_g      = (const float*)d_in[10];
    const float* ln2_b      = (const float*)d_in[11];
    const float* mlp_w1     = (const float*)d_in[12];
    const float* mlp_b1     = (const float*)d_in[13];
    const float* mlp_w2     = (const float*)d_in[14];
    const float* mlp_b2     = (const float*)d_in[15];
    const float* lnf_g      = (const float*)d_in[16];
    const float* lnf_b      = (const float*)d_in[17];
    const float* hW1 = (const float*)d_in[18];
    const float* hb1 = (const float*)d_in[19];
    const float* hW2 = (const float*)d_in[20];
    const float* hb2 = (const float*)d_in[21];
    const float* hW3 = (const float*)d_in[22];
    const float* hb3 = (const float*)d_in[23];
    const float* hW4 = (const float*)d_in[24];
    const float* hb4 = (const float*)d_in[25];
    const float* hW5 = (const float*)d_in[26];
    const float* hb5 = (const float*)d_in[27];
    const float* bbW = (const float*)d_in[28];
    const float* bbb = (const float*)d_in[29];

    // ---- workspace layout ----
    uint8_t* wsb = (uint8_t*)d_ws;
    size_t off = 0;
    auto alloc = [&](size_t bytes) { uint8_t* p = wsb + off; off += (bytes + 255) & ~(size_t)255; return p; };
    float*    X    = (float*)alloc(8192ull * 512 * 4);
    float*    QKV  = (float*)alloc(8192ull * 1536 * 4);
    float*    T    = (float*)alloc(8192ull * 512 * 4);
    uint16_t* Xh   = (uint16_t*)alloc(8192ull * 512 * 2);
    uint16_t* Xl   = (uint16_t*)alloc(8192ull * 512 * 2);
    uint16_t* Ohp  = (uint16_t*)alloc(8192ull * 512 * 2);
    uint16_t* Olp  = (uint16_t*)alloc(8192ull * 512 * 2);
    uint16_t* Hh   = (uint16_t*)alloc(8192ull * 1024 * 2);
    uint16_t* Hl   = (uint16_t*)alloc(8192ull * 1024 * 2);
    uint16_t* Ph   = (uint16_t*)alloc(8192ull * 3072 * 2);
    uint16_t* Pl   = (uint16_t*)alloc(8192ull * 3072 * 2);
    uint16_t* WqH  = (uint16_t*)alloc(4ull * 1536 * 512 * 2);
    uint16_t* WqL  = (uint16_t*)alloc(4ull * 1536 * 512 * 2);
    uint16_t* WaH  = (uint16_t*)alloc(4ull * 512 * 512 * 2);
    uint16_t* WaL  = (uint16_t*)alloc(4ull * 512 * 512 * 2);
    uint16_t* WpH  = (uint16_t*)alloc(512ull * 3072 * 2);
    uint16_t* WpL  = (uint16_t*)alloc(512ull * 3072 * 2);
    uint16_t* W1H  = (uint16_t*)alloc(4ull * 1024 * 512 * 2);
    uint16_t* W1L  = (uint16_t*)alloc(4ull * 1024 * 512 * 2);
    uint16_t* W2H  = (uint16_t*)alloc(4ull * 512 * 1024 * 2);
    uint16_t* W2L  = (uint16_t*)alloc(4ull * 512 * 1024 * 2);
    float*    F1p  = (float*)alloc(64ull * 65536 * 4);
    float*    F1   = (float*)alloc(65536ull * 4);
    float*    P2   = (float*)alloc(64ull * 32768 * 4);
    float*    F2   = (float*)alloc(32768ull * 4);
    float*    P3   = (float*)alloc(32ull * 16384 * 4);
    float*    F3   = (float*)alloc(16384ull * 4);
    float*    P4   = (float*)alloc(16ull * 2048 * 4);
    float*    F4   = (float*)alloc(2048ull * 4);
    float*    F5   = (float*)alloc(1024ull * 4);

    dim3 blk(256);

    // ---- prep: convert weights + images to bf16 hi/lo planes ----
    img2planes_kernel<<<(8192 * 768 + 255) / 256, blk, 0, stream>>>(images, Ph, Pl);
    conv_direct_kernel<<<(4 * 1536 * 512 / 4 + 255) / 256, blk, 0, stream>>>(qkv_w, WqH, WqL, 4 * 1536 * 512 / 4);
    conv_direct_kernel<<<(4 * 512 * 512 / 4 + 255) / 256, blk, 0, stream>>>(attn_out_w, WaH, WaL, 4 * 512 * 512 / 4);
    conv_transpose_kernel<<<dim3(3072 / 32, 512 / 32, 1), blk, 0, stream>>>(W_proj, WpH, WpL, 3072, 512);
    conv_transpose_kernel<<<dim3(512 / 32, 1024 / 32, 4), blk, 0, stream>>>(mlp_w1, W1H, W1L, 512, 1024);
    conv_transpose_kernel<<<dim3(1024 / 32, 512 / 32, 4), blk, 0, stream>>>(mlp_w2, W2H, W2L, 1024, 512);

    // ---- patch embed: X = patches @ W_proj + b_proj + pos ----
    mfma_gemm<64, 128, true, false, false, true, true, false>
        <<<dim3(512 / 128, 8192 / 64), blk, 0, stream>>>(
            Ph, Pl, WpH, WpL, X, nullptr, nullptr, b_proj, nullptr, pos_emb, 8192, 512, 3072);

    for (int l = 0; l < 4; ++l) {
        ln_kernel<true><<<2048, blk, 0, stream>>>(X, ln1_g + l * 512, ln1_b + l * 512,
                                                  nullptr, Xh, Xl, 8192);
        mfma_gemm<128, 128, true, false, false, false, true, false>
            <<<dim3(1536 / 128, 8192 / 128), blk, 0, stream>>>(
                Xh, Xl, WqH + (size_t)l * 1536 * 512, WqL + (size_t)l * 1536 * 512,
                QKV, nullptr, nullptr, qkv_b + l * 1536, nullptr, nullptr, 8192, 1536, 512);
        attn_kernel<<<256, blk, 0, stream>>>(QKV, Ohp, Olp);
        mfma_gemm<64, 128, true, false, true, false, true, false>
            <<<dim3(512 / 128, 8192 / 64), blk, 0, stream>>>(
                Ohp, Olp, WaH + (size_t)l * 512 * 512, WaL + (size_t)l * 512 * 512,
                X, nullptr, nullptr, attn_out_b + l * 512, X, nullptr, 8192, 512, 512);
        ln_kernel<true><<<2048, blk, 0, stream>>>(X, ln2_g + l * 512, ln2_b + l * 512,
                                                  nullptr, Xh, Xl, 8192);
        mfma_gemm<128, 128, true, true, false, false, false, true>
            <<<dim3(1024 / 128, 8192 / 128), blk, 0, stream>>>(
                Xh, Xl, W1H + (size_t)l * 1024 * 512, W1L + (size_t)l * 1024 * 512,
                nullptr, Hh, Hl, mlp_b1 + l * 1024, nullptr, nullptr, 8192, 1024, 512);
        mfma_gemm<64, 128, true, true, true, false, true, false>
            <<<dim3(512 / 128, 8192 / 64), blk, 0, stream>>>(
                Hh, Hl, W2H + (size_t)l * 512 * 1024, W2L + (size_t)l * 512 * 1024,
                X, nullptr, nullptr, mlp_b2 + l * 512, X, nullptr, 8192, 512, 1024);
    }

    // ---- final LN -> fp32 T ([32, 131072]) ----
    ln_kernel<false><<<2048, blk, 0, stream>>>(X, lnf_g, lnf_b, T, nullptr, nullptr, 8192);

    // ---- MLP head ----
    gemm_kernel<32, 128, 32, 4, 4, true>
        <<<dim3(2048 / 128, 1, 64), blk, 0, stream>>>(
            T, hW1, F1p, 32, 2048, 131072, 131072 / 64);
    reduce_gelu_kernel<<<(65536 + 255) / 256, blk, 0, stream>>>(F1p, hb1, F1, 65536, 64, 2048);

    skinny_gemm_kernel<<<dim3(1024 / 64, 2048 / 32), blk, 0, stream>>>(F1, hW2, P2, 32, 1024, 2048, 32);
    reduce_gelu_kernel<<<(32768 + 255) / 256, blk, 0, stream>>>(P2, hb2, F2, 32768, 64, 1024);

    skinny_gemm_kernel<<<dim3(512 / 64, 1024 / 32), blk, 0, stream>>>(F2, hW3, P3, 32, 512, 1024, 32);
    reduce_gelu_kernel<<<(16384 + 255) / 256, blk, 0, stream>>>(P3, hb3, F3, 16384, 32, 512);

    skinny_gemm_kernel<<<dim3(64 / 64, 512 / 32), blk, 0, stream>>>(F3, hW4, P4, 32, 64, 512, 32);
    reduce_gelu_kernel<<<(2048 + 255) / 256, blk, 0, stream>>>(P4, hb4, F4, 2048, 16, 64);

    small_gemm_kernel<true><<<(32 * 32 + 255) / 256, blk, 0, stream>>>(F4, hW5, hb5, F5, 32, 32, 64);
    small_gemm_kernel<false><<<1, blk, 0, stream>>>(F5, bbW, bbb, (float*)d_out, 32, 4, 32);
}

// Round 5
// 1822.282 us; speedup vs baseline: 2.5149x; 1.0018x over previous
//
#include <hip/hip_runtime.h>
#include <cstdint>
#include <cstddef>

#define DEV __device__ __forceinline__

typedef float f32x4 __attribute__((ext_vector_type(4)));
typedef short s16x8 __attribute__((ext_vector_type(8)));

DEV float gelu_f(float x) { return 0.5f * x * (1.0f + erff(x * 0.70710678118654752f)); }

DEV uint32_t fbits(float x) { return __builtin_bit_cast(uint32_t, x); }
DEV float bcast_f(uint32_t u) { return __builtin_bit_cast(float, u); }

// split x into hi (bf16-truncate) and lo (bf16-truncate of residual)
DEV void split_bf16(float x, uint16_t& h, uint16_t& lo) {
    uint32_t xb = fbits(x);
    h = (uint16_t)(xb >> 16);
    float r = x - bcast_f(xb & 0xFFFF0000u);
    lo = (uint16_t)(fbits(r) >> 16);
}

DEV void gload16(const void* g, void* l) {
    __builtin_amdgcn_global_load_lds(
        (const __attribute__((address_space(1))) uint32_t*)g,
        (__attribute__((address_space(3))) uint32_t*)l, 16, 0, 0);
}

// ---------------------------------------------------------------------------
// Split-bf16 MFMA GEMM.  A-planes [M][K] bf16 hi/lo, B-planes [N][K] bf16
// hi/lo (k-major).  C = A@B^T_planes with fp32 accumulate via 3 MFMA passes.
// 2-phase double-buffered pipeline; one vmcnt(0)+s_barrier per K-step.
// Epilogue: acc bounced through LDS ([BM][BN+4] f32) so global stores are
// coalesced float4 / ushort4 (the MFMA C-layout gives per-lane column runs,
// which would otherwise force scalar stores).
// ---------------------------------------------------------------------------
template<int BM, int BN, bool BIAS, bool GELU, bool RES, bool POS, bool OUTF32, bool OUTPL>
__global__ __launch_bounds__(256)
void mfma_gemm(const uint16_t* __restrict__ Ah, const uint16_t* __restrict__ Al,
               const uint16_t* __restrict__ Bh, const uint16_t* __restrict__ Bl,
               float* __restrict__ C, uint16_t* __restrict__ Chi, uint16_t* __restrict__ Clo,
               const float* __restrict__ bias, const float* __restrict__ res,
               const float* __restrict__ pos, int M, int N, int K)
{
    constexpr int WTM = BM / 2, WTN = BN / 2;
    constexpr int FM = WTM / 16, FN = WTN / 16;
    constexpr int NA = BM / 16, NB = BN / 16;      // 1KB chunks per A/B plane
    constexpr int TI = 2 * NA + 2 * NB;            // total gload instrs per K-step
    constexpr int TI4 = TI / 4;                    // per wave
    constexpr int HALF = (2 * BM + 2 * BN) * 64;   // bytes per K-step plane set
    constexpr int BNP = BN + 4;                    // padded bounce row
    constexpr int SMEM_BYTES = (2 * HALF > BM * BNP * 4) ? 2 * HALF : BM * BNP * 4;

    __shared__ __align__(16) uint8_t smem[SMEM_BYTES];
    constexpr int offAh = 0, offAl = BM * 64, offBh = 2 * BM * 64, offBl = 2 * BM * 64 + BN * 64;

    const int tid = threadIdx.x;
    const int w = tid >> 6, l = tid & 63;
    const int wr = w >> 1, wc = w & 1;
    const int bm0 = blockIdx.y * BM, bn0 = blockIdx.x * BN;
    const size_t sK = (size_t)K * 2;               // row stride in bytes

    // ---- staging descriptors (per-lane global addr, wave-uniform LDS off) ----
    const int srow  = l >> 2;
    const int sslot = (l & 3) ^ ((l >> 3) & 3);
    const uint8_t* gsrc[TI4];
    uint32_t loff[TI4];
#pragma unroll
    for (int j = 0; j < TI4; ++j) {
        int f = w * TI4 + j;
        int p = (f < NA) ? 0 : (f < 2 * NA) ? 1 : (f < 2 * NA + NB) ? 2 : 3;
        int c = f - (p == 0 ? 0 : p == 1 ? NA : p == 2 ? 2 * NA : 2 * NA + NB);
        const uint16_t* base = p == 0 ? Ah : p == 1 ? Al : p == 2 ? Bh : Bl;
        int rb = (p < 2) ? bm0 : bn0;
        gsrc[j] = (const uint8_t*)base + (size_t)(rb + c * 16 + srow) * sK + sslot * 16;
        loff[j] = (uint32_t)((p == 0 ? offAh : p == 1 ? offAl : p == 2 ? offBh : offBl) + c * 1024);
    }

    // ---- fragment read offsets ----
    const int lr = l & 15;
    const int sl16 = ((l >> 4) ^ ((lr >> 1) & 3)) * 16;
    const int aofs = (wr * WTM + lr) * 64 + sl16;
    const int bofs = (wc * WTN + lr) * 64 + sl16;

    f32x4 acc[FM][FN];
#pragma unroll
    for (int m = 0; m < FM; ++m)
#pragma unroll
        for (int n = 0; n < FN; ++n) acc[m][n] = (f32x4){0.f, 0.f, 0.f, 0.f};

    // ---- prologue: stage K-tile 0 into buffer 0 ----
    {
        const uint8_t* s0 = smem;
#pragma unroll
        for (int j = 0; j < TI4; ++j)
            gload16(gsrc[j], (void*)(s0 + loff[j]));
    }
    asm volatile("s_waitcnt vmcnt(0)" ::: "memory");
    __builtin_amdgcn_s_barrier();

    int cur = 0;
    for (int k0 = 0; k0 < K; k0 += 32) {
        const bool more = (k0 + 32 < K);
        // ---- issue prefetch of next K-tile into the other buffer ----
        if (more) {
            const size_t kb = (size_t)(k0 + 32) * 2;
            uint8_t* dst = smem + (cur ^ 1) * HALF;
#pragma unroll
            for (int j = 0; j < TI4; ++j)
                gload16(gsrc[j] + kb, dst + loff[j]);
        }
        // ---- fragments from current buffer ----
        const uint8_t* sb = smem + cur * HALF;
        s16x8 ah[FM], al[FM], bh[FN], bl[FN];
#pragma unroll
        for (int m = 0; m < FM; ++m) {
            ah[m] = *(const s16x8*)(sb + offAh + aofs + m * 1024);
            al[m] = *(const s16x8*)(sb + offAl + aofs + m * 1024);
        }
#pragma unroll
        for (int n = 0; n < FN; ++n) {
            bh[n] = *(const s16x8*)(sb + offBh + bofs + n * 1024);
            bl[n] = *(const s16x8*)(sb + offBl + bofs + n * 1024);
        }
#pragma unroll
        for (int m = 0; m < FM; ++m)
#pragma unroll
            for (int n = 0; n < FN; ++n)
                acc[m][n] = __builtin_amdgcn_mfma_f32_16x16x32_bf16(ah[m], bh[n], acc[m][n], 0, 0, 0);
#pragma unroll
        for (int m = 0; m < FM; ++m)
#pragma unroll
            for (int n = 0; n < FN; ++n)
                acc[m][n] = __builtin_amdgcn_mfma_f32_16x16x32_bf16(ah[m], bl[n], acc[m][n], 0, 0, 0);
#pragma unroll
        for (int m = 0; m < FM; ++m)
#pragma unroll
            for (int n = 0; n < FN; ++n)
                acc[m][n] = __builtin_amdgcn_mfma_f32_16x16x32_bf16(al[m], bh[n], acc[m][n], 0, 0, 0);

        if (more) {
            asm volatile("s_waitcnt vmcnt(0)" ::: "memory");
            __builtin_amdgcn_s_barrier();
        }
        cur ^= 1;
    }

    // ---- epilogue: bounce acc through LDS for coalesced stores ----
    __syncthreads();   // all waves done with K-loop LDS reads
    float* lf = (float*)smem;
    const int r4 = (l >> 4) * 4;
#pragma unroll
    for (int m = 0; m < FM; ++m) {
#pragma unroll
        for (int n = 0; n < FN; ++n) {
            int row = wr * WTM + m * 16 + r4;
            int col = wc * WTN + n * 16 + lr;
#pragma unroll
            for (int r = 0; r < 4; ++r)
                lf[(row + r) * BNP + col] = acc[m][n][r];
        }
    }
    __syncthreads();

    constexpr int C4PR = BN / 4;          // float4 per row
    constexpr int RPP  = 256 / C4PR;      // rows per pass
    constexpr int NP   = BM / RPP;        // passes
    const int rr = tid / C4PR, c4 = tid % C4PR;
    const int nn = bn0 + c4 * 4;

    float4 bv = {0.f, 0.f, 0.f, 0.f};
    if (BIAS) bv = *(const float4*)(bias + nn);

#pragma unroll
    for (int p = 0; p < NP; ++p) {
        int row = p * RPP + rr;
        int mm = bm0 + row;
        float4 v = *(const float4*)&lf[row * BNP + c4 * 4];
        float* vp = &v.x;
        const float* bp = &bv.x;
#pragma unroll
        for (int q = 0; q < 4; ++q) {
            float x = vp[q];
            if (BIAS) x += bp[q];
            if (GELU) x = gelu_f(x);
            vp[q] = x;
        }
        if (RES) {
            float4 rv = *(const float4*)(res + (size_t)mm * N + nn);
            v.x += rv.x; v.y += rv.y; v.z += rv.z; v.w += rv.w;
        }
        if (POS) {
            float4 pv = *(const float4*)(pos + (size_t)(mm & 255) * N + nn);
            v.x += pv.x; v.y += pv.y; v.z += pv.z; v.w += pv.w;
        }
        size_t o = (size_t)mm * N + nn;
        if (OUTF32) *(float4*)(C + o) = v;
        if (OUTPL) {
            ushort4 hh, ll;
            uint16_t h, lo;
            split_bf16(v.x, h, lo); hh.x = h; ll.x = lo;
            split_bf16(v.y, h, lo); hh.y = h; ll.y = lo;
            split_bf16(v.z, h, lo); hh.z = h; ll.z = lo;
            split_bf16(v.w, h, lo); hh.w = h; ll.w = lo;
            *(ushort4*)(Chi + o) = hh;
            *(ushort4*)(Clo + o) = ll;
        }
    }
}

// ---------------------------------------------------------------------------
// Prep: images -> patch-gathered bf16 hi/lo planes [8192][3072]
// ---------------------------------------------------------------------------
__global__ __launch_bounds__(256)
void img2planes_kernel(const float* __restrict__ img, uint16_t* __restrict__ Ph,
                       uint16_t* __restrict__ Pl)
{
    int idx = blockIdx.x * 256 + threadIdx.x;   // over 8192*768
    if (idx >= 8192 * 768) return;
    int m = idx / 768, q = idx - (idx / 768) * 768;
    int k = q * 4;
    int bb = m >> 8, n = m & 255;
    int ph = k / 96, rem = k - ph * 96;
    int prow = ((n >> 4) << 5) + ph;
    int pcol0 = (n & 15) << 5;
    const float* s = img + (((size_t)bb * 512 + prow) * 512 + pcol0) * 3 + rem;
    float4 v = *(const float4*)s;
    ushort4 hh, ll;
    uint16_t h, lo;
    split_bf16(v.x, h, lo); hh.x = h; ll.x = lo;
    split_bf16(v.y, h, lo); hh.y = h; ll.y = lo;
    split_bf16(v.z, h, lo); hh.z = h; ll.z = lo;
    split_bf16(v.w, h, lo); hh.w = h; ll.w = lo;
    size_t o = (size_t)m * 3072 + k;
    *(ushort4*)(Ph + o) = hh;
    *(ushort4*)(Pl + o) = ll;
}

// ---------------------------------------------------------------------------
// Prep: direct convert fp32 [N][K] -> bf16 hi/lo planes (same layout)
// ---------------------------------------------------------------------------
__global__ __launch_bounds__(256)
void conv_direct_kernel(const float* __restrict__ src, uint16_t* __restrict__ dh,
                        uint16_t* __restrict__ dl, int total4)
{
    int idx = blockIdx.x * 256 + threadIdx.x;
    if (idx >= total4) return;
    float4 v = *(const float4*)(src + (size_t)idx * 4);
    ushort4 hh, ll;
    uint16_t h, lo;
    split_bf16(v.x, h, lo); hh.x = h; ll.x = lo;
    split_bf16(v.y, h, lo); hh.y = h; ll.y = lo;
    split_bf16(v.z, h, lo); hh.z = h; ll.z = lo;
    split_bf16(v.w, h, lo); hh.w = h; ll.w = lo;
    *(ushort4*)(dh + (size_t)idx * 4) = hh;
    *(ushort4*)(dl + (size_t)idx * 4) = ll;
}

// ---------------------------------------------------------------------------
// Prep: transpose-convert fp32 [K][N] -> bf16 hi/lo planes [N][K]
// grid (K/32, N/32, layers)
// ---------------------------------------------------------------------------
__global__ __launch_bounds__(256)
void conv_transpose_kernel(const float* __restrict__ src, uint16_t* __restrict__ dh,
                           uint16_t* __restrict__ dl, int K, int N)
{
    __shared__ float t[32][33];
    int k0 = blockIdx.x * 32, n0 = blockIdx.y * 32;
    const float* s = src + (size_t)blockIdx.z * K * N;
    size_t dbase = (size_t)blockIdx.z * N * K;
    int tid = threadIdx.x;
    {
        int kk = tid / 8, n4 = tid % 8;
        float4 v = *(const float4*)(s + (size_t)(k0 + kk) * N + n0 + n4 * 4);
        t[kk][n4 * 4 + 0] = v.x; t[kk][n4 * 4 + 1] = v.y;
        t[kk][n4 * 4 + 2] = v.z; t[kk][n4 * 4 + 3] = v.w;
    }
    __syncthreads();
    int nn = tid / 8, k4 = tid % 8;
    ushort4 hh, ll;
    uint16_t h, lo;
    float x0 = t[k4 * 4 + 0][nn], x1 = t[k4 * 4 + 1][nn], x2 = t[k4 * 4 + 2][nn], x3 = t[k4 * 4 + 3][nn];
    split_bf16(x0, h, lo); hh.x = h; ll.x = lo;
    split_bf16(x1, h, lo); hh.y = h; ll.y = lo;
    split_bf16(x2, h, lo); hh.z = h; ll.z = lo;
    split_bf16(x3, h, lo); hh.w = h; ll.w = lo;
    size_t o = dbase + (size_t)(n0 + nn) * K + k0 + k4 * 4;
    *(ushort4*)(dh + o) = hh;
    *(ushort4*)(dl + o) = ll;
}

// ---------------------------------------------------------------------------
// LayerNorm over rows of 512; optionally emit bf16 hi/lo planes.
// ---------------------------------------------------------------------------
template<bool PLANES>
__global__ __launch_bounds__(256)
void ln_kernel(const float* __restrict__ X, const float* __restrict__ g,
               const float* __restrict__ b, float* __restrict__ Y,
               uint16_t* __restrict__ Yh, uint16_t* __restrict__ Yl, int nrows)
{
    int wave = threadIdx.x >> 6;
    int lane = threadIdx.x & 63;
    int row = blockIdx.x * 4 + wave;
    if (row >= nrows) return;
    const float* x = X + (size_t)row * 512;
    float4 v0 = ((const float4*)x)[lane];
    float4 v1 = ((const float4*)x)[lane + 64];
    float s  = v0.x + v0.y + v0.z + v0.w + v1.x + v1.y + v1.z + v1.w;
    float sq = v0.x*v0.x + v0.y*v0.y + v0.z*v0.z + v0.w*v0.w
             + v1.x*v1.x + v1.y*v1.y + v1.z*v1.z + v1.w*v1.w;
#pragma unroll
    for (int off = 32; off > 0; off >>= 1) {
        s  += __shfl_down(s, off);
        sq += __shfl_down(sq, off);
    }
    s  = __shfl(s, 0);
    sq = __shfl(sq, 0);
    float mean = s * (1.f / 512.f);
    float var  = sq * (1.f / 512.f) - mean * mean;
    float rinv = rsqrtf(var + 1e-6f);
    float4 g0 = ((const float4*)g)[lane], g1 = ((const float4*)g)[lane + 64];
    float4 b0 = ((const float4*)b)[lane], b1 = ((const float4*)b)[lane + 64];
    float4 o0, o1;
    o0.x = (v0.x - mean) * rinv * g0.x + b0.x;
    o0.y = (v0.y - mean) * rinv * g0.y + b0.y;
    o0.z = (v0.z - mean) * rinv * g0.z + b0.z;
    o0.w = (v0.w - mean) * rinv * g0.w + b0.w;
    o1.x = (v1.x - mean) * rinv * g1.x + b1.x;
    o1.y = (v1.y - mean) * rinv * g1.y + b1.y;
    o1.z = (v1.z - mean) * rinv * g1.z + b1.z;
    o1.w = (v1.w - mean) * rinv * g1.w + b1.w;
    if (PLANES) {
        ushort4 hh0, ll0, hh1, ll1;
        uint16_t h, lo;
        split_bf16(o0.x, h, lo); hh0.x = h; ll0.x = lo;
        split_bf16(o0.y, h, lo); hh0.y = h; ll0.y = lo;
        split_bf16(o0.z, h, lo); hh0.z = h; ll0.z = lo;
        split_bf16(o0.w, h, lo); hh0.w = h; ll0.w = lo;
        split_bf16(o1.x, h, lo); hh1.x = h; ll1.x = lo;
        split_bf16(o1.y, h, lo); hh1.y = h; ll1.y = lo;
        split_bf16(o1.z, h, lo); hh1.z = h; ll1.z = lo;
        split_bf16(o1.w, h, lo); hh1.w = h; ll1.w = lo;
        size_t base = (size_t)row * 512;
        *(ushort4*)(Yh + base + lane * 4)       = hh0;
        *(ushort4*)(Yl + base + lane * 4)       = ll0;
        *(ushort4*)(Yh + base + 256 + lane * 4) = hh1;
        *(ushort4*)(Yl + base + 256 + lane * 4) = ll1;
    } else {
        float* y = Y + (size_t)row * 512;
        ((float4*)y)[lane]      = o0;
        ((float4*)y)[lane + 64] = o1;
    }
}

// ---------------------------------------------------------------------------
// Attention: one block per (batch,head); K,V in LDS; one query per thread.
// Emits O as bf16 hi/lo planes.
// ---------------------------------------------------------------------------
__global__ __launch_bounds__(256)
void attn_kernel(const float* __restrict__ QKV, uint16_t* __restrict__ Oh,
                 uint16_t* __restrict__ Ol)
{
    __shared__ float Ks[256][64];
    __shared__ float Vs[256][64];
    int bh = blockIdx.x;
    int b = bh >> 3, h = bh & 7;
    const float* base = QKV + (size_t)b * 256 * 1536;

    for (int i = threadIdx.x; i < 256 * 16; i += 256) {
        int r = i >> 4, d4 = i & 15;
        const float* krow = base + (size_t)r * 1536 + 512 + h * 64;
        const float* vrow = base + (size_t)r * 1536 + 1024 + h * 64;
        *(float4*)&Ks[r][d4 * 4] = *(const float4*)(krow + d4 * 4);
        *(float4*)&Vs[r][d4 * 4] = *(const float4*)(vrow + d4 * 4);
    }
    float q[64];
    const float* qp = base + (size_t)threadIdx.x * 1536 + h * 64;
#pragma unroll
    for (int i = 0; i < 16; ++i) *(float4*)&q[i * 4] = ((const float4*)qp)[i];
    __syncthreads();

    float o[64];
#pragma unroll
    for (int d = 0; d < 64; ++d) o[d] = 0.f;
    float den = 0.f;
#pragma unroll 2
    for (int k = 0; k < 256; ++k) {
        float sc = 0.f;
#pragma unroll
        for (int d = 0; d < 64; ++d) sc = fmaf(q[d], Ks[k][d], sc);
        float e = __expf(sc * 0.125f);
        den += e;
#pragma unroll
        for (int d = 0; d < 64; ++d) o[d] = fmaf(e, Vs[k][d], o[d]);
    }
    float inv = 1.f / den;
    size_t ob = ((size_t)b * 256 + threadIdx.x) * 512 + h * 64;
#pragma unroll
    for (int i4 = 0; i4 < 16; ++i4) {
        ushort4 hh, ll;
        uint16_t h16, lo16;
        split_bf16(o[i4 * 4 + 0] * inv, h16, lo16); hh.x = h16; ll.x = lo16;
        split_bf16(o[i4 * 4 + 1] * inv, h16, lo16); hh.y = h16; ll.y = lo16;
        split_bf16(o[i4 * 4 + 2] * inv, h16, lo16); hh.z = h16; ll.z = lo16;
        split_bf16(o[i4 * 4 + 3] * inv, h16, lo16); hh.w = h16; ll.w = lo16;
        *(ushort4*)(Oh + ob + i4 * 4) = hh;
        *(ushort4*)(Ol + ob + i4 * 4) = ll;
    }
}

// ---------------------------------------------------------------------------
// fp32 tiled GEMM (kept for head layer 1 split-K)
// ---------------------------------------------------------------------------
template<int BM, int BN, int BK, int TM, int TN, bool SPLITK>
__global__ __launch_bounds__(256)
void gemm_kernel(const float* __restrict__ A, const float* __restrict__ B,
                 float* __restrict__ C, int M, int N, int K, int kchunk)
{
    constexpr int TX = BN / TN;
    constexpr int TY = BM / TM;
    static_assert(TX * TY == 256, "bad tile config");
    __shared__ float As[BK][BM + 4];
    __shared__ float Bs[BK][BN + 4];
    const int tid = threadIdx.x;
    const int tx  = tid % TX;
    const int ty  = tid / TX;
    const int bn0 = blockIdx.x * BN;
    const int bm0 = blockIdx.y * BM;
    int kstart = 0, kend = K;
    if (SPLITK) { kstart = blockIdx.z * kchunk; kend = kstart + kchunk; }
    float acc[TM][TN];
#pragma unroll
    for (int i = 0; i < TM; ++i)
#pragma unroll
        for (int j = 0; j < TN; ++j) acc[i][j] = 0.f;
    for (int k0 = kstart; k0 < kend; k0 += BK) {
        __syncthreads();
        constexpr int AV = BM * BK / 4 / 256;
#pragma unroll
        for (int r = 0; r < AV; ++r) {
            int idx = tid + r * 256;
            int k4 = idx % (BK / 4);
            int mm = idx / (BK / 4);
            float4 v = *(const float4*)(A + (size_t)(bm0 + mm) * K + k0 + k4 * 4);
            As[k4 * 4 + 0][mm] = v.x;
            As[k4 * 4 + 1][mm] = v.y;
            As[k4 * 4 + 2][mm] = v.z;
            As[k4 * 4 + 3][mm] = v.w;
        }
        constexpr int BV = BK * BN / 4 / 256;
#pragma unroll
        for (int r = 0; r < BV; ++r) {
            int idx = tid + r * 256;
            int n4 = idx % (BN / 4);
            int kk = idx / (BN / 4);
            float4 v = *(const float4*)(B + (size_t)(k0 + kk) * N + bn0 + n4 * 4);
            *(float4*)&Bs[kk][n4 * 4] = v;
        }
        __syncthreads();
#pragma unroll
        for (int kk = 0; kk < BK; ++kk) {
            float a[TM], b[TN];
#pragma unroll
            for (int i = 0; i < TM; i += 4)
                *(float4*)&a[i] = *(const float4*)&As[kk][ty * TM + i];
#pragma unroll
            for (int j = 0; j < TN; j += 4)
                *(float4*)&b[j] = *(const float4*)&Bs[kk][tx * TN + j];
#pragma unroll
            for (int i = 0; i < TM; ++i)
#pragma unroll
                for (int j = 0; j < TN; ++j)
                    acc[i][j] = fmaf(a[i], b[j], acc[i][j]);
        }
    }
    float* Cb = C;
    if (SPLITK) Cb += (size_t)blockIdx.z * M * N;
#pragma unroll
    for (int i = 0; i < TM; ++i) {
        int m = bm0 + ty * TM + i;
#pragma unroll
        for (int j = 0; j < TN; j += 4) {
            int n = bn0 + tx * TN + j;
            float4 v;
            v.x = acc[i][j + 0]; v.y = acc[i][j + 1];
            v.z = acc[i][j + 2]; v.w = acc[i][j + 3];
            *(float4*)(Cb + (size_t)m * N + n) = v;
        }
    }
}

__global__ __launch_bounds__(256)
void skinny_gemm_kernel(const float* __restrict__ A, const float* __restrict__ B,
                        float* __restrict__ P, int M, int N, int K, int kchunk)
{
    __shared__ float As[32][36];
    const int tid = threadIdx.x;
    const int tx  = tid & 63;
    const int ty  = tid >> 6;
    const int bn0 = blockIdx.x * 64;
    const int kstart = blockIdx.y * kchunk;
    const int kend   = kstart + kchunk;
    float acc[8];
#pragma unroll
    for (int i = 0; i < 8; ++i) acc[i] = 0.f;
    for (int k0 = kstart; k0 < kend; k0 += 32) {
        __syncthreads();
        {
            int row = tid >> 3;
            int k4  = tid & 7;
            float4 v = *(const float4*)(A + (size_t)row * K + k0 + k4 * 4);
            *(float4*)&As[row][k4 * 4] = v;
        }
        __syncthreads();
#pragma unroll 8
        for (int kk = 0; kk < 32; ++kk) {
            float b = B[(size_t)(k0 + kk) * N + bn0 + tx];
#pragma unroll
            for (int i = 0; i < 8; ++i)
                acc[i] = fmaf(As[ty * 8 + i][kk], b, acc[i]);
        }
    }
    float* Pb = P + (size_t)blockIdx.y * M * N;
#pragma unroll
    for (int i = 0; i < 8; ++i)
        Pb[(size_t)(ty * 8 + i) * N + bn0 + tx] = acc[i];
}

__global__ __launch_bounds__(256)
void reduce_gelu_kernel(const float* __restrict__ P, const float* __restrict__ bias,
                        float* __restrict__ Y, int total, int chunks, int N)
{
    int idx = blockIdx.x * 256 + threadIdx.x;
    if (idx >= total) return;
    float s = 0.f;
    for (int c = 0; c < chunks; ++c) s += P[(size_t)c * total + idx];
    s += bias[idx % N];
    Y[idx] = gelu_f(s);
}

template<bool GELU>
__global__ __launch_bounds__(256)
void small_gemm_kernel(const float* __restrict__ A, const float* __restrict__ B,
                       const float* __restrict__ bias, float* __restrict__ C,
                       int M, int N, int K)
{
    int idx = blockIdx.x * 256 + threadIdx.x;
    if (idx >= M * N) return;
    int m = idx / N, n = idx % N;
    const float* a = A + (size_t)m * K;
    float s = 0.f;
    for (int k = 0; k < K; ++k) s = fmaf(a[k], B[(size_t)k * N + n], s);
    s += bias[n];
    if (GELU) s = gelu_f(s);
    C[idx] = s;
}

// ---------------------------------------------------------------------------
extern "C" void kernel_launch(void* const* d_in, const int* in_sizes, int n_in,
                              void* d_out, int out_size, void* d_ws, size_t ws_size,
                              hipStream_t stream)
{
    const float* images     = (const float*)d_in[0];
    const float* W_proj     = (const float*)d_in[1];
    const float* b_proj     = (const float*)d_in[2];
    const float* pos_emb    = (const float*)d_in[3];
    const float* ln1_g      = (const float*)d_in[4];
    const float* ln1_b      = (const float*)d_in[5];
    const float* qkv_w      = (const float*)d_in[6];
    const float* qkv_b      = (const float*)d_in[7];
    const float* attn_out_w = (const float*)d_in[8];
    const float* attn_out_b = (const float*)d_in[9];
    const float* ln2_g      = (const float*)d_in[10];
    const float* ln2_b      = (const float*)d_in[11];
    const float* mlp_w1     = (const float*)d_in[12];
    const float* mlp_b1     = (const float*)d_in[13];
    const float* mlp_w2     = (const float*)d_in[14];
    const float* mlp_b2     = (const float*)d_in[15];
    const float* lnf_g      = (const float*)d_in[16];
    const float* lnf_b      = (const float*)d_in[17];
    const float* hW1 = (const float*)d_in[18];
    const float* hb1 = (const float*)d_in[19];
    const float* hW2 = (const float*)d_in[20];
    const float* hb2 = (const float*)d_in[21];
    const float* hW3 = (const float*)d_in[22];
    const float* hb3 = (const float*)d_in[23];
    const float* hW4 = (const float*)d_in[24];
    const float* hb4 = (const float*)d_in[25];
    const float* hW5 = (const float*)d_in[26];
    const float* hb5 = (const float*)d_in[27];
    const float* bbW = (const float*)d_in[28];
    const float* bbb = (const float*)d_in[29];

    // ---- workspace layout ----
    uint8_t* wsb = (uint8_t*)d_ws;
    size_t off = 0;
    auto alloc = [&](size_t bytes) { uint8_t* p = wsb + off; off += (bytes + 255) & ~(size_t)255; return p; };
    float*    X    = (float*)alloc(8192ull * 512 * 4);
    float*    QKV  = (float*)alloc(8192ull * 1536 * 4);
    float*    T    = (float*)alloc(8192ull * 512 * 4);
    uint16_t* Xh   = (uint16_t*)alloc(8192ull * 512 * 2);
    uint16_t* Xl   = (uint16_t*)alloc(8192ull * 512 * 2);
    uint16_t* Ohp  = (uint16_t*)alloc(8192ull * 512 * 2);
    uint16_t* Olp  = (uint16_t*)alloc(8192ull * 512 * 2);
    uint16_t* Hh   = (uint16_t*)alloc(8192ull * 1024 * 2);
    uint16_t* Hl   = (uint16_t*)alloc(8192ull * 1024 * 2);
    uint16_t* Ph   = (uint16_t*)alloc(8192ull * 3072 * 2);
    uint16_t* Pl   = (uint16_t*)alloc(8192ull * 3072 * 2);
    uint16_t* WqH  = (uint16_t*)alloc(4ull * 1536 * 512 * 2);
    uint16_t* WqL  = (uint16_t*)alloc(4ull * 1536 * 512 * 2);
    uint16_t* WaH  = (uint16_t*)alloc(4ull * 512 * 512 * 2);
    uint16_t* WaL  = (uint16_t*)alloc(4ull * 512 * 512 * 2);
    uint16_t* WpH  = (uint16_t*)alloc(512ull * 3072 * 2);
    uint16_t* WpL  = (uint16_t*)alloc(512ull * 3072 * 2);
    uint16_t* W1H  = (uint16_t*)alloc(4ull * 1024 * 512 * 2);
    uint16_t* W1L  = (uint16_t*)alloc(4ull * 1024 * 512 * 2);
    uint16_t* W2H  = (uint16_t*)alloc(4ull * 512 * 1024 * 2);
    uint16_t* W2L  = (uint16_t*)alloc(4ull * 512 * 1024 * 2);
    float*    F1p  = (float*)alloc(64ull * 65536 * 4);
    float*    F1   = (float*)alloc(65536ull * 4);
    float*    P2   = (float*)alloc(64ull * 32768 * 4);
    float*    F2   = (float*)alloc(32768ull * 4);
    float*    P3   = (float*)alloc(32ull * 16384 * 4);
    float*    F3   = (float*)alloc(16384ull * 4);
    float*    P4   = (float*)alloc(16ull * 2048 * 4);
    float*    F4   = (float*)alloc(2048ull * 4);
    float*    F5   = (float*)alloc(1024ull * 4);

    dim3 blk(256);

    // ---- prep: convert weights + images to bf16 hi/lo planes ----
    img2planes_kernel<<<(8192 * 768 + 255) / 256, blk, 0, stream>>>(images, Ph, Pl);
    conv_direct_kernel<<<(4 * 1536 * 512 / 4 + 255) / 256, blk, 0, stream>>>(qkv_w, WqH, WqL, 4 * 1536 * 512 / 4);
    conv_direct_kernel<<<(4 * 512 * 512 / 4 + 255) / 256, blk, 0, stream>>>(attn_out_w, WaH, WaL, 4 * 512 * 512 / 4);
    conv_transpose_kernel<<<dim3(3072 / 32, 512 / 32, 1), blk, 0, stream>>>(W_proj, WpH, WpL, 3072, 512);
    conv_transpose_kernel<<<dim3(512 / 32, 1024 / 32, 4), blk, 0, stream>>>(mlp_w1, W1H, W1L, 512, 1024);
    conv_transpose_kernel<<<dim3(1024 / 32, 512 / 32, 4), blk, 0, stream>>>(mlp_w2, W2H, W2L, 1024, 512);

    // ---- patch embed: X = patches @ W_proj + b_proj + pos ----
    mfma_gemm<64, 128, true, false, false, true, true, false>
        <<<dim3(512 / 128, 8192 / 64), blk, 0, stream>>>(
            Ph, Pl, WpH, WpL, X, nullptr, nullptr, b_proj, nullptr, pos_emb, 8192, 512, 3072);

    for (int l = 0; l < 4; ++l) {
        ln_kernel<true><<<2048, blk, 0, stream>>>(X, ln1_g + l * 512, ln1_b + l * 512,
                                                  nullptr, Xh, Xl, 8192);
        mfma_gemm<128, 128, true, false, false, false, true, false>
            <<<dim3(1536 / 128, 8192 / 128), blk, 0, stream>>>(
                Xh, Xl, WqH + (size_t)l * 1536 * 512, WqL + (size_t)l * 1536 * 512,
                QKV, nullptr, nullptr, qkv_b + l * 1536, nullptr, nullptr, 8192, 1536, 512);
        attn_kernel<<<256, blk, 0, stream>>>(QKV, Ohp, Olp);
        mfma_gemm<64, 128, true, false, true, false, true, false>
            <<<dim3(512 / 128, 8192 / 64), blk, 0, stream>>>(
                Ohp, Olp, WaH + (size_t)l * 512 * 512, WaL + (size_t)l * 512 * 512,
                X, nullptr, nullptr, attn_out_b + l * 512, X, nullptr, 8192, 512, 512);
        ln_kernel<true><<<2048, blk, 0, stream>>>(X, ln2_g + l * 512, ln2_b + l * 512,
                                                  nullptr, Xh, Xl, 8192);
        mfma_gemm<128, 128, true, true, false, false, false, true>
            <<<dim3(1024 / 128, 8192 / 128), blk, 0, stream>>>(
                Xh, Xl, W1H + (size_t)l * 1024 * 512, W1L + (size_t)l * 1024 * 512,
                nullptr, Hh, Hl, mlp_b1 + l * 1024, nullptr, nullptr, 8192, 1024, 512);
        mfma_gemm<64, 128, true, true, true, false, true, false>
            <<<dim3(512 / 128, 8192 / 64), blk, 0, stream>>>(
                Hh, Hl, W2H + (size_t)l * 512 * 1024, W2L + (size_t)l * 512 * 1024,
                X, nullptr, nullptr, mlp_b2 + l * 512, X, nullptr, 8192, 512, 1024);
    }

    // ---- final LN -> fp32 T ([32, 131072]) ----
    ln_kernel<false><<<2048, blk, 0, stream>>>(X, lnf_g, lnf_b, T, nullptr, nullptr, 8192);

    // ---- MLP head ----
    gemm_kernel<32, 128, 32, 4, 4, true>
        <<<dim3(2048 / 128, 1, 64), blk, 0, stream>>>(
            T, hW1, F1p, 32, 2048, 131072, 131072 / 64);
    reduce_gelu_kernel<<<(65536 + 255) / 256, blk, 0, stream>>>(F1p, hb1, F1, 65536, 64, 2048);

    skinny_gemm_kernel<<<dim3(1024 / 64, 2048 / 32), blk, 0, stream>>>(F1, hW2, P2, 32, 1024, 2048, 32);
    reduce_gelu_kernel<<<(32768 + 255) / 256, blk, 0, stream>>>(P2, hb2, F2, 32768, 64, 1024);

    skinny_gemm_kernel<<<dim3(512 / 64, 1024 / 32), blk, 0, stream>>>(F2, hW3, P3, 32, 512, 1024, 32);
    reduce_gelu_kernel<<<(16384 + 255) / 256, blk, 0, stream>>>(P3, hb3, F3, 16384, 32, 512);

    skinny_gemm_kernel<<<dim3(64 / 64, 512 / 32), blk, 0, stream>>>(F3, hW4, P4, 32, 64, 512, 32);
    reduce_gelu_kernel<<<(2048 + 255) / 256, blk, 0, stream>>>(P4, hb4, F4, 2048, 16, 64);

    small_gemm_kernel<true><<<(32 * 32 + 255) / 256, blk, 0, stream>>>(F4, hW5, hb5, F5, 32, 32, 64);
    small_gemm_kernel<false><<<1, blk, 0, stream>>>(F5, bbW, bbb, (float*)d_out, 32, 4, 32);
}

// Round 6
// 1380.727 us; speedup vs baseline: 3.3192x; 1.3198x over previous
//
#include <hip/hip_runtime.h>
#include <cstdint>
#include <cstddef>

#define DEV __device__ __forceinline__

typedef float f32x4 __attribute__((ext_vector_type(4)));
typedef short s16x8 __attribute__((ext_vector_type(8)));

DEV float gelu_f(float x) { return 0.5f * x * (1.0f + erff(x * 0.70710678118654752f)); }

DEV uint32_t fbits(float x) { return __builtin_bit_cast(uint32_t, x); }
DEV float bcast_f(uint32_t u) { return __builtin_bit_cast(float, u); }

// split x into hi (bf16-truncate) and lo (bf16-truncate of residual)
DEV void split_bf16(float x, uint16_t& h, uint16_t& lo) {
    uint32_t xb = fbits(x);
    h = (uint16_t)(xb >> 16);
    float r = x - bcast_f(xb & 0xFFFF0000u);
    lo = (uint16_t)(fbits(r) >> 16);
}

// round-to-nearest-even bf16 (single-plane use)
DEV uint16_t bf16_rne(float x) {
    uint32_t u = fbits(x);
    return (uint16_t)((u + 0x7FFFu + ((u >> 16) & 1u)) >> 16);
}

DEV void gload16(const void* g, void* l) {
    __builtin_amdgcn_global_load_lds(
        (const __attribute__((address_space(1))) uint32_t*)g,
        (__attribute__((address_space(3))) uint32_t*)l, 16, 0, 0);
}

// ---------------------------------------------------------------------------
// Split-bf16 MFMA GEMM (unchanged structure; + XCD-aware block swizzle).
// ---------------------------------------------------------------------------
template<int BM, int BN, bool BIAS, bool GELU, bool RES, bool POS, bool OUTF32, bool OUTPL>
__global__ __launch_bounds__(256)
void mfma_gemm(const uint16_t* __restrict__ Ah, const uint16_t* __restrict__ Al,
               const uint16_t* __restrict__ Bh, const uint16_t* __restrict__ Bl,
               float* __restrict__ C, uint16_t* __restrict__ Chi, uint16_t* __restrict__ Clo,
               const float* __restrict__ bias, const float* __restrict__ res,
               const float* __restrict__ pos, int M, int N, int K)
{
    constexpr int WTM = BM / 2, WTN = BN / 2;
    constexpr int FM = WTM / 16, FN = WTN / 16;
    constexpr int NA = BM / 16, NB = BN / 16;
    constexpr int TI = 2 * NA + 2 * NB;
    constexpr int TI4 = TI / 4;
    constexpr int HALF = (2 * BM + 2 * BN) * 64;
    constexpr int BNP = BN + 4;
    constexpr int SMEM_BYTES = (2 * HALF > BM * BNP * 4) ? 2 * HALF : BM * BNP * 4;

    __shared__ __align__(16) uint8_t smem[SMEM_BYTES];
    constexpr int offAh = 0, offAl = BM * 64, offBh = 2 * BM * 64, offBl = 2 * BM * 64 + BN * 64;

    const int tid = threadIdx.x;
    const int w = tid >> 6, l = tid & 63;
    const int wr = w >> 1, wc = w & 1;

    // XCD-aware bijective swizzle (all grids here are %8 == 0)
    const int gx = gridDim.x;
    const int nwg = gx * gridDim.y;
    const int lin = blockIdx.y * gx + blockIdx.x;
    const int cpx = nwg >> 3;
    const int swz = (lin & 7) * cpx + (lin >> 3);
    const int bxs = swz % gx, bys = swz / gx;
    const int bm0 = bys * BM, bn0 = bxs * BN;
    const size_t sK = (size_t)K * 2;

    const int srow  = l >> 2;
    const int sslot = (l & 3) ^ ((l >> 3) & 3);
    const uint8_t* gsrc[TI4];
    uint32_t loff[TI4];
#pragma unroll
    for (int j = 0; j < TI4; ++j) {
        int f = w * TI4 + j;
        int p = (f < NA) ? 0 : (f < 2 * NA) ? 1 : (f < 2 * NA + NB) ? 2 : 3;
        int c = f - (p == 0 ? 0 : p == 1 ? NA : p == 2 ? 2 * NA : 2 * NA + NB);
        const uint16_t* base = p == 0 ? Ah : p == 1 ? Al : p == 2 ? Bh : Bl;
        int rb = (p < 2) ? bm0 : bn0;
        gsrc[j] = (const uint8_t*)base + (size_t)(rb + c * 16 + srow) * sK + sslot * 16;
        loff[j] = (uint32_t)((p == 0 ? offAh : p == 1 ? offAl : p == 2 ? offBh : offBl) + c * 1024);
    }

    const int lr = l & 15;
    const int sl16 = ((l >> 4) ^ ((lr >> 1) & 3)) * 16;
    const int aofs = (wr * WTM + lr) * 64 + sl16;
    const int bofs = (wc * WTN + lr) * 64 + sl16;

    f32x4 acc[FM][FN];
#pragma unroll
    for (int m = 0; m < FM; ++m)
#pragma unroll
        for (int n = 0; n < FN; ++n) acc[m][n] = (f32x4){0.f, 0.f, 0.f, 0.f};

    {
        const uint8_t* s0 = smem;
#pragma unroll
        for (int j = 0; j < TI4; ++j)
            gload16(gsrc[j], (void*)(s0 + loff[j]));
    }
    asm volatile("s_waitcnt vmcnt(0)" ::: "memory");
    __builtin_amdgcn_s_barrier();

    int cur = 0;
    for (int k0 = 0; k0 < K; k0 += 32) {
        const bool more = (k0 + 32 < K);
        if (more) {
            const size_t kb = (size_t)(k0 + 32) * 2;
            uint8_t* dst = smem + (cur ^ 1) * HALF;
#pragma unroll
            for (int j = 0; j < TI4; ++j)
                gload16(gsrc[j] + kb, dst + loff[j]);
        }
        const uint8_t* sb = smem + cur * HALF;
        s16x8 ah[FM], al[FM], bh[FN], bl[FN];
#pragma unroll
        for (int m = 0; m < FM; ++m) {
            ah[m] = *(const s16x8*)(sb + offAh + aofs + m * 1024);
            al[m] = *(const s16x8*)(sb + offAl + aofs + m * 1024);
        }
#pragma unroll
        for (int n = 0; n < FN; ++n) {
            bh[n] = *(const s16x8*)(sb + offBh + bofs + n * 1024);
            bl[n] = *(const s16x8*)(sb + offBl + bofs + n * 1024);
        }
#pragma unroll
        for (int m = 0; m < FM; ++m)
#pragma unroll
            for (int n = 0; n < FN; ++n)
                acc[m][n] = __builtin_amdgcn_mfma_f32_16x16x32_bf16(ah[m], bh[n], acc[m][n], 0, 0, 0);
#pragma unroll
        for (int m = 0; m < FM; ++m)
#pragma unroll
            for (int n = 0; n < FN; ++n)
                acc[m][n] = __builtin_amdgcn_mfma_f32_16x16x32_bf16(ah[m], bl[n], acc[m][n], 0, 0, 0);
#pragma unroll
        for (int m = 0; m < FM; ++m)
#pragma unroll
            for (int n = 0; n < FN; ++n)
                acc[m][n] = __builtin_amdgcn_mfma_f32_16x16x32_bf16(al[m], bh[n], acc[m][n], 0, 0, 0);

        if (more) {
            asm volatile("s_waitcnt vmcnt(0)" ::: "memory");
            __builtin_amdgcn_s_barrier();
        }
        cur ^= 1;
    }

    // ---- epilogue: bounce acc through LDS for coalesced stores ----
    __syncthreads();
    float* lf = (float*)smem;
    const int r4 = (l >> 4) * 4;
#pragma unroll
    for (int m = 0; m < FM; ++m) {
#pragma unroll
        for (int n = 0; n < FN; ++n) {
            int row = wr * WTM + m * 16 + r4;
            int col = wc * WTN + n * 16 + lr;
#pragma unroll
            for (int r = 0; r < 4; ++r)
                lf[(row + r) * BNP + col] = acc[m][n][r];
        }
    }
    __syncthreads();

    constexpr int C4PR = BN / 4;
    constexpr int RPP  = 256 / C4PR;
    constexpr int NP   = BM / RPP;
    const int rr = tid / C4PR, c4 = tid % C4PR;
    const int nn = bn0 + c4 * 4;

    float4 bv = {0.f, 0.f, 0.f, 0.f};
    if (BIAS) bv = *(const float4*)(bias + nn);

#pragma unroll
    for (int p = 0; p < NP; ++p) {
        int row = p * RPP + rr;
        int mm = bm0 + row;
        float4 v = *(const float4*)&lf[row * BNP + c4 * 4];
        float* vp = &v.x;
        const float* bp = &bv.x;
#pragma unroll
        for (int q = 0; q < 4; ++q) {
            float x = vp[q];
            if (BIAS) x += bp[q];
            if (GELU) x = gelu_f(x);
            vp[q] = x;
        }
        if (RES) {
            float4 rv = *(const float4*)(res + (size_t)mm * N + nn);
            v.x += rv.x; v.y += rv.y; v.z += rv.z; v.w += rv.w;
        }
        if (POS) {
            float4 pv = *(const float4*)(pos + (size_t)(mm & 255) * N + nn);
            v.x += pv.x; v.y += pv.y; v.z += pv.z; v.w += pv.w;
        }
        size_t o = (size_t)mm * N + nn;
        if (OUTF32) *(float4*)(C + o) = v;
        if (OUTPL) {
            ushort4 hh, ll;
            uint16_t h, lo;
            split_bf16(v.x, h, lo); hh.x = h; ll.x = lo;
            split_bf16(v.y, h, lo); hh.y = h; ll.y = lo;
            split_bf16(v.z, h, lo); hh.z = h; ll.z = lo;
            split_bf16(v.w, h, lo); hh.w = h; ll.w = lo;
            *(ushort4*)(Chi + o) = hh;
            *(ushort4*)(Clo + o) = ll;
        }
    }
}

// ---------------------------------------------------------------------------
// MFMA flash-style attention. One block per (b,h); 4 waves x 64 queries.
// Q/K/V converted to RNE-bf16 in LDS (144B padded rows -> <=2-way conflicts).
// S = QK^T and O = PV via mfma_f32_16x16x32_bf16 (verified fragment layout).
// Softmax fp32, no max-subtraction (|s| < ~1.5). O emitted as hi/lo planes.
// ---------------------------------------------------------------------------
__global__ __launch_bounds__(256)
void mfma_attn(const float* __restrict__ QKV, uint16_t* __restrict__ Oh,
               uint16_t* __restrict__ Ol)
{
    __shared__ __align__(16) uint8_t lds[92160];
    uint8_t* Qs = lds;              // [256][144B]  (64 d x bf16 + pad)
    uint8_t* Ks = lds + 36864;      // [64][144B]
    uint8_t* Vt = lds + 46080;      // [64][144B]   (rows = d, cols = k)
    uint8_t* Ps = lds + 55296;      // [256][144B]  (cols = k-local 64)

    const int tid = threadIdx.x;
    const int w = tid >> 6, l = tid & 63;
    const int lr = l & 15, lg = l >> 4;
    const int bh = blockIdx.x;
    const int b = bh >> 3, h = bh & 7;
    const float* base = QKV + (size_t)b * 256 * 1536 + h * 64;
    const int q0 = w * 64;

    // ---- stage Q: thread = token row ----
    {
        const float* qp = base + (size_t)tid * 1536;
#pragma unroll
        for (int s = 0; s < 8; ++s) {
            float4 a = *(const float4*)(qp + s * 8);
            float4 c = *(const float4*)(qp + s * 8 + 4);
            s16x8 v;
            v[0] = (short)bf16_rne(a.x); v[1] = (short)bf16_rne(a.y);
            v[2] = (short)bf16_rne(a.z); v[3] = (short)bf16_rne(a.w);
            v[4] = (short)bf16_rne(c.x); v[5] = (short)bf16_rne(c.y);
            v[6] = (short)bf16_rne(c.z); v[7] = (short)bf16_rne(c.w);
            *(s16x8*)(Qs + tid * 144 + s * 16) = v;
        }
    }

    f32x4 oacc[4][4];
    float lrun[4][4];
#pragma unroll
    for (int m = 0; m < 4; ++m)
#pragma unroll
        for (int n = 0; n < 4; ++n) { oacc[m][n] = (f32x4){0.f,0.f,0.f,0.f}; lrun[m][n] = 0.f; }

    for (int kt = 0; kt < 4; ++kt) {
        __syncthreads();   // prev tile reads done; (kt==0: Q writes done)
        // ---- stage K-tile: thread -> row tid>>2, slot pair ----
        {
            int r = tid >> 2, sp = (tid & 3) * 2;
            const float* kp = base + (size_t)(kt * 64 + r) * 1536 + 512;
#pragma unroll
            for (int ss = 0; ss < 2; ++ss) {
                int s = sp + ss;
                float4 a = *(const float4*)(kp + s * 8);
                float4 c = *(const float4*)(kp + s * 8 + 4);
                s16x8 v;
                v[0] = (short)bf16_rne(a.x); v[1] = (short)bf16_rne(a.y);
                v[2] = (short)bf16_rne(a.z); v[3] = (short)bf16_rne(a.w);
                v[4] = (short)bf16_rne(c.x); v[5] = (short)bf16_rne(c.y);
                v[6] = (short)bf16_rne(c.z); v[7] = (short)bf16_rne(c.w);
                *(s16x8*)(Ks + r * 144 + s * 16) = v;
            }
        }
        // ---- stage Vt-tile transposed: thread -> source row tid&63, d-range (tid>>6)*16 ----
        {
            int k = tid & 63, d0 = (tid >> 6) * 16;
            const float* vp = base + (size_t)(kt * 64 + k) * 1536 + 1024 + d0;
            float4 v0 = *(const float4*)(vp);
            float4 v1 = *(const float4*)(vp + 4);
            float4 v2 = *(const float4*)(vp + 8);
            float4 v3 = *(const float4*)(vp + 12);
            float vv[16] = {v0.x,v0.y,v0.z,v0.w, v1.x,v1.y,v1.z,v1.w,
                            v2.x,v2.y,v2.z,v2.w, v3.x,v3.y,v3.z,v3.w};
#pragma unroll
            for (int i = 0; i < 16; ++i)
                *(uint16_t*)(Vt + (d0 + i) * 144 + k * 2) = bf16_rne(vv[i]);
        }
        __syncthreads();   // staging visible

        // ---- S = Q K^T over d=64 (2 k-steps) ----
        f32x4 sacc[4][4];
#pragma unroll
        for (int m = 0; m < 4; ++m)
#pragma unroll
            for (int n = 0; n < 4; ++n) sacc[m][n] = (f32x4){0.f,0.f,0.f,0.f};
#pragma unroll
        for (int ks = 0; ks < 2; ++ks) {
            s16x8 qf[4], kf[4];
#pragma unroll
            for (int m = 0; m < 4; ++m)
                qf[m] = *(const s16x8*)(Qs + (q0 + m * 16 + lr) * 144 + ks * 64 + lg * 16);
#pragma unroll
            for (int n = 0; n < 4; ++n)
                kf[n] = *(const s16x8*)(Ks + (n * 16 + lr) * 144 + ks * 64 + lg * 16);
#pragma unroll
            for (int m = 0; m < 4; ++m)
#pragma unroll
                for (int n = 0; n < 4; ++n)
                    sacc[m][n] = __builtin_amdgcn_mfma_f32_16x16x32_bf16(qf[m], kf[n], sacc[m][n], 0, 0, 0);
        }

        // ---- exp + P write + denominator ----
        float dp[4][4];
#pragma unroll
        for (int m = 0; m < 4; ++m)
#pragma unroll
            for (int r = 0; r < 4; ++r) dp[m][r] = 0.f;
#pragma unroll
        for (int m = 0; m < 4; ++m) {
#pragma unroll
            for (int n = 0; n < 4; ++n) {
#pragma unroll
                for (int r = 0; r < 4; ++r) {
                    float e = __expf(sacc[m][n][r] * 0.125f);
                    dp[m][r] += e;
                    int q = q0 + m * 16 + lg * 4 + r;
                    int k = n * 16 + lr;
                    *(uint16_t*)(Ps + q * 144 + k * 2) = bf16_rne(e);
                }
            }
        }
#pragma unroll
        for (int m = 0; m < 4; ++m)
#pragma unroll
            for (int r = 0; r < 4; ++r) {
                float d = dp[m][r];
                d += __shfl_xor(d, 1);
                d += __shfl_xor(d, 2);
                d += __shfl_xor(d, 4);
                d += __shfl_xor(d, 8);
                lrun[m][r] += d;
            }

        asm volatile("s_waitcnt lgkmcnt(0)" ::: "memory");
        __builtin_amdgcn_sched_barrier(0);

        // ---- O += P V (contract k-local 64 = 2 k-steps) ----
#pragma unroll
        for (int ks = 0; ks < 2; ++ks) {
            s16x8 pf[4], vf[4];
#pragma unroll
            for (int m = 0; m < 4; ++m)
                pf[m] = *(const s16x8*)(Ps + (q0 + m * 16 + lr) * 144 + ks * 64 + lg * 16);
#pragma unroll
            for (int n = 0; n < 4; ++n)
                vf[n] = *(const s16x8*)(Vt + (n * 16 + lr) * 144 + ks * 64 + lg * 16);
#pragma unroll
            for (int m = 0; m < 4; ++m)
#pragma unroll
                for (int n = 0; n < 4; ++n)
                    oacc[m][n] = __builtin_amdgcn_mfma_f32_16x16x32_bf16(pf[m], vf[n], oacc[m][n], 0, 0, 0);
        }
    }

    // ---- normalize + bounce to LDS + coalesced hi/lo store ----
    float inv[4][4];
#pragma unroll
    for (int m = 0; m < 4; ++m)
#pragma unroll
        for (int r = 0; r < 4; ++r) inv[m][r] = 1.f / lrun[m][r];

    __syncthreads();   // all waves done with Qs/Ks/Vt/Ps reads
    float* OL = (float*)lds;       // [256][68 f32]
#pragma unroll
    for (int m = 0; m < 4; ++m)
#pragma unroll
        for (int n = 0; n < 4; ++n)
#pragma unroll
            for (int r = 0; r < 4; ++r) {
                int q = q0 + m * 16 + lg * 4 + r;
                int d = n * 16 + lr;
                OL[q * 68 + d] = oacc[m][n][r] * inv[m][r];
            }
    __syncthreads();

#pragma unroll
    for (int pass = 0; pass < 16; ++pass) {
        int q = pass * 16 + (tid >> 4);
        int d4 = tid & 15;
        f32x4 v = *(const f32x4*)(OL + q * 68 + d4 * 4);
        ushort4 hh, ll;
        uint16_t hv, lv;
        split_bf16(v[0], hv, lv); hh.x = hv; ll.x = lv;
        split_bf16(v[1], hv, lv); hh.y = hv; ll.y = lv;
        split_bf16(v[2], hv, lv); hh.z = hv; ll.z = lv;
        split_bf16(v[3], hv, lv); hh.w = hv; ll.w = lv;
        size_t o = (size_t)(b * 256 + q) * 512 + h * 64 + d4 * 4;
        *(ushort4*)(Oh + o) = hh;
        *(ushort4*)(Ol + o) = ll;
    }
}

// ---------------------------------------------------------------------------
// Prep: images -> patch-gathered bf16 hi/lo planes [8192][3072]
// ---------------------------------------------------------------------------
__global__ __launch_bounds__(256)
void img2planes_kernel(const float* __restrict__ img, uint16_t* __restrict__ Ph,
                       uint16_t* __restrict__ Pl)
{
    int idx = blockIdx.x * 256 + threadIdx.x;   // over 8192*768
    if (idx >= 8192 * 768) return;
    int m = idx / 768, q = idx - (idx / 768) * 768;
    int k = q * 4;
    int bb = m >> 8, n = m & 255;
    int ph = k / 96, rem = k - ph * 96;
    int prow = ((n >> 4) << 5) + ph;
    int pcol0 = (n & 15) << 5;
    const float* s = img + (((size_t)bb * 512 + prow) * 512 + pcol0) * 3 + rem;
    float4 v = *(const float4*)s;
    ushort4 hh, ll;
    uint16_t h, lo;
    split_bf16(v.x, h, lo); hh.x = h; ll.x = lo;
    split_bf16(v.y, h, lo); hh.y = h; ll.y = lo;
    split_bf16(v.z, h, lo); hh.z = h; ll.z = lo;
    split_bf16(v.w, h, lo); hh.w = h; ll.w = lo;
    size_t o = (size_t)m * 3072 + k;
    *(ushort4*)(Ph + o) = hh;
    *(ushort4*)(Pl + o) = ll;
}

__global__ __launch_bounds__(256)
void conv_direct_kernel(const float* __restrict__ src, uint16_t* __restrict__ dh,
                        uint16_t* __restrict__ dl, int total4)
{
    int idx = blockIdx.x * 256 + threadIdx.x;
    if (idx >= total4) return;
    float4 v = *(const float4*)(src + (size_t)idx * 4);
    ushort4 hh, ll;
    uint16_t h, lo;
    split_bf16(v.x, h, lo); hh.x = h; ll.x = lo;
    split_bf16(v.y, h, lo); hh.y = h; ll.y = lo;
    split_bf16(v.z, h, lo); hh.z = h; ll.z = lo;
    split_bf16(v.w, h, lo); hh.w = h; ll.w = lo;
    *(ushort4*)(dh + (size_t)idx * 4) = hh;
    *(ushort4*)(dl + (size_t)idx * 4) = ll;
}

__global__ __launch_bounds__(256)
void conv_transpose_kernel(const float* __restrict__ src, uint16_t* __restrict__ dh,
                           uint16_t* __restrict__ dl, int K, int N)
{
    __shared__ float t[32][33];
    int k0 = blockIdx.x * 32, n0 = blockIdx.y * 32;
    const float* s = src + (size_t)blockIdx.z * K * N;
    size_t dbase = (size_t)blockIdx.z * N * K;
    int tid = threadIdx.x;
    {
        int kk = tid / 8, n4 = tid % 8;
        float4 v = *(const float4*)(s + (size_t)(k0 + kk) * N + n0 + n4 * 4);
        t[kk][n4 * 4 + 0] = v.x; t[kk][n4 * 4 + 1] = v.y;
        t[kk][n4 * 4 + 2] = v.z; t[kk][n4 * 4 + 3] = v.w;
    }
    __syncthreads();
    int nn = tid / 8, k4 = tid % 8;
    ushort4 hh, ll;
    uint16_t h, lo;
    float x0 = t[k4 * 4 + 0][nn], x1 = t[k4 * 4 + 1][nn], x2 = t[k4 * 4 + 2][nn], x3 = t[k4 * 4 + 3][nn];
    split_bf16(x0, h, lo); hh.x = h; ll.x = lo;
    split_bf16(x1, h, lo); hh.y = h; ll.y = lo;
    split_bf16(x2, h, lo); hh.z = h; ll.z = lo;
    split_bf16(x3, h, lo); hh.w = h; ll.w = lo;
    size_t o = dbase + (size_t)(n0 + nn) * K + k0 + k4 * 4;
    *(ushort4*)(dh + o) = hh;
    *(ushort4*)(dl + o) = ll;
}

// ---------------------------------------------------------------------------
// LayerNorm over rows of 512; optionally emit bf16 hi/lo planes.
// ---------------------------------------------------------------------------
template<bool PLANES>
__global__ __launch_bounds__(256)
void ln_kernel(const float* __restrict__ X, const float* __restrict__ g,
               const float* __restrict__ b, float* __restrict__ Y,
               uint16_t* __restrict__ Yh, uint16_t* __restrict__ Yl, int nrows)
{
    int wave = threadIdx.x >> 6;
    int lane = threadIdx.x & 63;
    int row = blockIdx.x * 4 + wave;
    if (row >= nrows) return;
    const float* x = X + (size_t)row * 512;
    float4 v0 = ((const float4*)x)[lane];
    float4 v1 = ((const float4*)x)[lane + 64];
    float s  = v0.x + v0.y + v0.z + v0.w + v1.x + v1.y + v1.z + v1.w;
    float sq = v0.x*v0.x + v0.y*v0.y + v0.z*v0.z + v0.w*v0.w
             + v1.x*v1.x + v1.y*v1.y + v1.z*v1.z + v1.w*v1.w;
#pragma unroll
    for (int off = 32; off > 0; off >>= 1) {
        s  += __shfl_down(s, off);
        sq += __shfl_down(sq, off);
    }
    s  = __shfl(s, 0);
    sq = __shfl(sq, 0);
    float mean = s * (1.f / 512.f);
    float var  = sq * (1.f / 512.f) - mean * mean;
    float rinv = rsqrtf(var + 1e-6f);
    float4 g0 = ((const float4*)g)[lane], g1 = ((const float4*)g)[lane + 64];
    float4 b0 = ((const float4*)b)[lane], b1 = ((const float4*)b)[lane + 64];
    float4 o0, o1;
    o0.x = (v0.x - mean) * rinv * g0.x + b0.x;
    o0.y = (v0.y - mean) * rinv * g0.y + b0.y;
    o0.z = (v0.z - mean) * rinv * g0.z + b0.z;
    o0.w = (v0.w - mean) * rinv * g0.w + b0.w;
    o1.x = (v1.x - mean) * rinv * g1.x + b1.x;
    o1.y = (v1.y - mean) * rinv * g1.y + b1.y;
    o1.z = (v1.z - mean) * rinv * g1.z + b1.z;
    o1.w = (v1.w - mean) * rinv * g1.w + b1.w;
    if (PLANES) {
        ushort4 hh0, ll0, hh1, ll1;
        uint16_t h, lo;
        split_bf16(o0.x, h, lo); hh0.x = h; ll0.x = lo;
        split_bf16(o0.y, h, lo); hh0.y = h; ll0.y = lo;
        split_bf16(o0.z, h, lo); hh0.z = h; ll0.z = lo;
        split_bf16(o0.w, h, lo); hh0.w = h; ll0.w = lo;
        split_bf16(o1.x, h, lo); hh1.x = h; ll1.x = lo;
        split_bf16(o1.y, h, lo); hh1.y = h; ll1.y = lo;
        split_bf16(o1.z, h, lo); hh1.z = h; ll1.z = lo;
        split_bf16(o1.w, h, lo); hh1.w = h; ll1.w = lo;
        size_t base = (size_t)row * 512;
        *(ushort4*)(Yh + base + lane * 4)       = hh0;
        *(ushort4*)(Yl + base + lane * 4)       = ll0;
        *(ushort4*)(Yh + base + 256 + lane * 4) = hh1;
        *(ushort4*)(Yl + base + 256 + lane * 4) = ll1;
    } else {
        float* y = Y + (size_t)row * 512;
        ((float4*)y)[lane]      = o0;
        ((float4*)y)[lane + 64] = o1;
    }
}

// ---------------------------------------------------------------------------
// fp32 tiled GEMM (kept for head layer 1 split-K)
// ---------------------------------------------------------------------------
template<int BM, int BN, int BK, int TM, int TN, bool SPLITK>
__global__ __launch_bounds__(256)
void gemm_kernel(const float* __restrict__ A, const float* __restrict__ B,
                 float* __restrict__ C, int M, int N, int K, int kchunk)
{
    constexpr int TX = BN / TN;
    constexpr int TY = BM / TM;
    static_assert(TX * TY == 256, "bad tile config");
    __shared__ float As[BK][BM + 4];
    __shared__ float Bs[BK][BN + 4];
    const int tid = threadIdx.x;
    const int tx  = tid % TX;
    const int ty  = tid / TX;
    const int bn0 = blockIdx.x * BN;
    const int bm0 = blockIdx.y * BM;
    int kstart = 0, kend = K;
    if (SPLITK) { kstart = blockIdx.z * kchunk; kend = kstart + kchunk; }
    float acc[TM][TN];
#pragma unroll
    for (int i = 0; i < TM; ++i)
#pragma unroll
        for (int j = 0; j < TN; ++j) acc[i][j] = 0.f;
    for (int k0 = kstart; k0 < kend; k0 += BK) {
        __syncthreads();
        constexpr int AV = BM * BK / 4 / 256;
#pragma unroll
        for (int r = 0; r < AV; ++r) {
            int idx = tid + r * 256;
            int k4 = idx % (BK / 4);
            int mm = idx / (BK / 4);
            float4 v = *(const float4*)(A + (size_t)(bm0 + mm) * K + k0 + k4 * 4);
            As[k4 * 4 + 0][mm] = v.x;
            As[k4 * 4 + 1][mm] = v.y;
            As[k4 * 4 + 2][mm] = v.z;
            As[k4 * 4 + 3][mm] = v.w;
        }
        constexpr int BV = BK * BN / 4 / 256;
#pragma unroll
        for (int r = 0; r < BV; ++r) {
            int idx = tid + r * 256;
            int n4 = idx % (BN / 4);
            int kk = idx / (BN / 4);
            float4 v = *(const float4*)(B + (size_t)(k0 + kk) * N + bn0 + n4 * 4);
            *(float4*)&Bs[kk][n4 * 4] = v;
        }
        __syncthreads();
#pragma unroll
        for (int kk = 0; kk < BK; ++kk) {
            float a[TM], b[TN];
#pragma unroll
            for (int i = 0; i < TM; i += 4)
                *(float4*)&a[i] = *(const float4*)&As[kk][ty * TM + i];
#pragma unroll
            for (int j = 0; j < TN; j += 4)
                *(float4*)&b[j] = *(const float4*)&Bs[kk][tx * TN + j];
#pragma unroll
            for (int i = 0; i < TM; ++i)
#pragma unroll
                for (int j = 0; j < TN; ++j)
                    acc[i][j] = fmaf(a[i], b[j], acc[i][j]);
        }
    }
    float* Cb = C;
    if (SPLITK) Cb += (size_t)blockIdx.z * M * N;
#pragma unroll
    for (int i = 0; i < TM; ++i) {
        int m = bm0 + ty * TM + i;
#pragma unroll
        for (int j = 0; j < TN; j += 4) {
            int n = bn0 + tx * TN + j;
            float4 v;
            v.x = acc[i][j + 0]; v.y = acc[i][j + 1];
            v.z = acc[i][j + 2]; v.w = acc[i][j + 3];
            *(float4*)(Cb + (size_t)m * N + n) = v;
        }
    }
}

__global__ __launch_bounds__(256)
void skinny_gemm_kernel(const float* __restrict__ A, const float* __restrict__ B,
                        float* __restrict__ P, int M, int N, int K, int kchunk)
{
    __shared__ float As[32][36];
    const int tid = threadIdx.x;
    const int tx  = tid & 63;
    const int ty  = tid >> 6;
    const int bn0 = blockIdx.x * 64;
    const int kstart = blockIdx.y * kchunk;
    const int kend   = kstart + kchunk;
    float acc[8];
#pragma unroll
    for (int i = 0; i < 8; ++i) acc[i] = 0.f;
    for (int k0 = kstart; k0 < kend; k0 += 32) {
        __syncthreads();
        {
            int row = tid >> 3;
            int k4  = tid & 7;
            float4 v = *(const float4*)(A + (size_t)row * K + k0 + k4 * 4);
            *(float4*)&As[row][k4 * 4] = v;
        }
        __syncthreads();
#pragma unroll 8
        for (int kk = 0; kk < 32; ++kk) {
            float b = B[(size_t)(k0 + kk) * N + bn0 + tx];
#pragma unroll
            for (int i = 0; i < 8; ++i)
                acc[i] = fmaf(As[ty * 8 + i][kk], b, acc[i]);
        }
    }
    float* Pb = P + (size_t)blockIdx.y * M * N;
#pragma unroll
    for (int i = 0; i < 8; ++i)
        Pb[(size_t)(ty * 8 + i) * N + bn0 + tx] = acc[i];
}

__global__ __launch_bounds__(256)
void reduce_gelu_kernel(const float* __restrict__ P, const float* __restrict__ bias,
                        float* __restrict__ Y, int total, int chunks, int N)
{
    int idx = blockIdx.x * 256 + threadIdx.x;
    if (idx >= total) return;
    float s = 0.f;
    for (int c = 0; c < chunks; ++c) s += P[(size_t)c * total + idx];
    s += bias[idx % N];
    Y[idx] = gelu_f(s);
}

template<bool GELU>
__global__ __launch_bounds__(256)
void small_gemm_kernel(const float* __restrict__ A, const float* __restrict__ B,
                       const float* __restrict__ bias, float* __restrict__ C,
                       int M, int N, int K)
{
    int idx = blockIdx.x * 256 + threadIdx.x;
    if (idx >= M * N) return;
    int m = idx / N, n = idx % N;
    const float* a = A + (size_t)m * K;
    float s = 0.f;
    for (int k = 0; k < K; ++k) s = fmaf(a[k], B[(size_t)k * N + n], s);
    s += bias[n];
    if (GELU) s = gelu_f(s);
    C[idx] = s;
}

// ---------------------------------------------------------------------------
extern "C" void kernel_launch(void* const* d_in, const int* in_sizes, int n_in,
                              void* d_out, int out_size, void* d_ws, size_t ws_size,
                              hipStream_t stream)
{
    const float* images     = (const float*)d_in[0];
    const float* W_proj     = (const float*)d_in[1];
    const float* b_proj     = (const float*)d_in[2];
    const float* pos_emb    = (const float*)d_in[3];
    const float* ln1_g      = (const float*)d_in[4];
    const float* ln1_b      = (const float*)d_in[5];
    const float* qkv_w      = (const float*)d_in[6];
    const float* qkv_b      = (const float*)d_in[7];
    const float* attn_out_w = (const float*)d_in[8];
    const float* attn_out_b = (const float*)d_in[9];
    const float* ln2_g      = (const float*)d_in[10];
    const float* ln2_b      = (const float*)d_in[11];
    const float* mlp_w1     = (const float*)d_in[12];
    const float* mlp_b1     = (const float*)d_in[13];
    const float* mlp_w2     = (const float*)d_in[14];
    const float* mlp_b2     = (const float*)d_in[15];
    const float* lnf_g      = (const float*)d_in[16];
    const float* lnf_b      = (const float*)d_in[17];
    const float* hW1 = (const float*)d_in[18];
    const float* hb1 = (const float*)d_in[19];
    const float* hW2 = (const float*)d_in[20];
    const float* hb2 = (const float*)d_in[21];
    const float* hW3 = (const float*)d_in[22];
    const float* hb3 = (const float*)d_in[23];
    const float* hW4 = (const float*)d_in[24];
    const float* hb4 = (const float*)d_in[25];
    const float* hW5 = (const float*)d_in[26];
    const float* hb5 = (const float*)d_in[27];
    const float* bbW = (const float*)d_in[28];
    const float* bbb = (const float*)d_in[29];

    // ---- workspace layout ----
    uint8_t* wsb = (uint8_t*)d_ws;
    size_t off = 0;
    auto alloc = [&](size_t bytes) { uint8_t* p = wsb + off; off += (bytes + 255) & ~(size_t)255; return p; };
    float*    X    = (float*)alloc(8192ull * 512 * 4);
    float*    QKV  = (float*)alloc(8192ull * 1536 * 4);
    float*    T    = (float*)alloc(8192ull * 512 * 4);
    uint16_t* Xh   = (uint16_t*)alloc(8192ull * 512 * 2);
    uint16_t* Xl   = (uint16_t*)alloc(8192ull * 512 * 2);
    uint16_t* Ohp  = (uint16_t*)alloc(8192ull * 512 * 2);
    uint16_t* Olp  = (uint16_t*)alloc(8192ull * 512 * 2);
    uint16_t* Hh   = (uint16_t*)alloc(8192ull * 1024 * 2);
    uint16_t* Hl   = (uint16_t*)alloc(8192ull * 1024 * 2);
    uint16_t* Ph   = (uint16_t*)alloc(8192ull * 3072 * 2);
    uint16_t* Pl   = (uint16_t*)alloc(8192ull * 3072 * 2);
    uint16_t* WqH  = (uint16_t*)alloc(4ull * 1536 * 512 * 2);
    uint16_t* WqL  = (uint16_t*)alloc(4ull * 1536 * 512 * 2);
    uint16_t* WaH  = (uint16_t*)alloc(4ull * 512 * 512 * 2);
    uint16_t* WaL  = (uint16_t*)alloc(4ull * 512 * 512 * 2);
    uint16_t* WpH  = (uint16_t*)alloc(512ull * 3072 * 2);
    uint16_t* WpL  = (uint16_t*)alloc(512ull * 3072 * 2);
    uint16_t* W1H  = (uint16_t*)alloc(4ull * 1024 * 512 * 2);
    uint16_t* W1L  = (uint16_t*)alloc(4ull * 1024 * 512 * 2);
    uint16_t* W2H  = (uint16_t*)alloc(4ull * 512 * 1024 * 2);
    uint16_t* W2L  = (uint16_t*)alloc(4ull * 512 * 1024 * 2);
    float*    F1p  = (float*)alloc(64ull * 65536 * 4);
    float*    F1   = (float*)alloc(65536ull * 4);
    float*    P2   = (float*)alloc(64ull * 32768 * 4);
    float*    F2   = (float*)alloc(32768ull * 4);
    float*    P3   = (float*)alloc(32ull * 16384 * 4);
    float*    F3   = (float*)alloc(16384ull * 4);
    float*    P4   = (float*)alloc(16ull * 2048 * 4);
    float*    F4   = (float*)alloc(2048ull * 4);
    float*    F5   = (float*)alloc(1024ull * 4);

    dim3 blk(256);

    // ---- prep: convert weights + images to bf16 hi/lo planes ----
    img2planes_kernel<<<(8192 * 768 + 255) / 256, blk, 0, stream>>>(images, Ph, Pl);
    conv_direct_kernel<<<(4 * 1536 * 512 / 4 + 255) / 256, blk, 0, stream>>>(qkv_w, WqH, WqL, 4 * 1536 * 512 / 4);
    conv_direct_kernel<<<(4 * 512 * 512 / 4 + 255) / 256, blk, 0, stream>>>(attn_out_w, WaH, WaL, 4 * 512 * 512 / 4);
    conv_transpose_kernel<<<dim3(3072 / 32, 512 / 32, 1), blk, 0, stream>>>(W_proj, WpH, WpL, 3072, 512);
    conv_transpose_kernel<<<dim3(512 / 32, 1024 / 32, 4), blk, 0, stream>>>(mlp_w1, W1H, W1L, 512, 1024);
    conv_transpose_kernel<<<dim3(1024 / 32, 512 / 32, 4), blk, 0, stream>>>(mlp_w2, W2H, W2L, 1024, 512);

    // ---- patch embed: X = patches @ W_proj + b_proj + pos ----
    mfma_gemm<64, 128, true, false, false, true, true, false>
        <<<dim3(512 / 128, 8192 / 64), blk, 0, stream>>>(
            Ph, Pl, WpH, WpL, X, nullptr, nullptr, b_proj, nullptr, pos_emb, 8192, 512, 3072);

    for (int l = 0; l < 4; ++l) {
        ln_kernel<true><<<2048, blk, 0, stream>>>(X, ln1_g + l * 512, ln1_b + l * 512,
                                                  nullptr, Xh, Xl, 8192);
        mfma_gemm<128, 128, true, false, false, false, true, false>
            <<<dim3(1536 / 128, 8192 / 128), blk, 0, stream>>>(
                Xh, Xl, WqH + (size_t)l * 1536 * 512, WqL + (size_t)l * 1536 * 512,
                QKV, nullptr, nullptr, qkv_b + l * 1536, nullptr, nullptr, 8192, 1536, 512);
        mfma_attn<<<256, blk, 0, stream>>>(QKV, Ohp, Olp);
        mfma_gemm<64, 128, true, false, true, false, true, false>
            <<<dim3(512 / 128, 8192 / 64), blk, 0, stream>>>(
                Ohp, Olp, WaH + (size_t)l * 512 * 512, WaL + (size_t)l * 512 * 512,
                X, nullptr, nullptr, attn_out_b + l * 512, X, nullptr, 8192, 512, 512);
        ln_kernel<true><<<2048, blk, 0, stream>>>(X, ln2_g + l * 512, ln2_b + l * 512,
                                                  nullptr, Xh, Xl, 8192);
        mfma_gemm<128, 128, true, true, false, false, false, true>
            <<<dim3(1024 / 128, 8192 / 128), blk, 0, stream>>>(
                Xh, Xl, W1H + (size_t)l * 1024 * 512, W1L + (size_t)l * 1024 * 512,
                nullptr, Hh, Hl, mlp_b1 + l * 1024, nullptr, nullptr, 8192, 1024, 512);
        mfma_gemm<64, 128, true, true, true, false, true, false>
            <<<dim3(512 / 128, 8192 / 64), blk, 0, stream>>>(
                Hh, Hl, W2H + (size_t)l * 512 * 1024, W2L + (size_t)l * 512 * 1024,
                X, nullptr, nullptr, mlp_b2 + l * 512, X, nullptr, 8192, 512, 1024);
    }

    // ---- final LN -> fp32 T ([32, 131072]) ----
    ln_kernel<false><<<2048, blk, 0, stream>>>(X, lnf_g, lnf_b, T, nullptr, nullptr, 8192);

    // ---- MLP head ----
    gemm_kernel<32, 128, 32, 4, 4, true>
        <<<dim3(2048 / 128, 1, 64), blk, 0, stream>>>(
            T, hW1, F1p, 32, 2048, 131072, 131072 / 64);
    reduce_gelu_kernel<<<(65536 + 255) / 256, blk, 0, stream>>>(F1p, hb1, F1, 65536, 64, 2048);

    skinny_gemm_kernel<<<dim3(1024 / 64, 2048 / 32), blk, 0, stream>>>(F1, hW2, P2, 32, 1024, 2048, 32);
    reduce_gelu_kernel<<<(32768 + 255) / 256, blk, 0, stream>>>(P2, hb2, F2, 32768, 64, 1024);

    skinny_gemm_kernel<<<dim3(512 / 64, 1024 / 32), blk, 0, stream>>>(F2, hW3, P3, 32, 512, 1024, 32);
    reduce_gelu_kernel<<<(16384 + 255) / 256, blk, 0, stream>>>(P3, hb3, F3, 16384, 32, 512);

    skinny_gemm_kernel<<<dim3(64 / 64, 512 / 32), blk, 0, stream>>>(F3, hW4, P4, 32, 64, 512, 32);
    reduce_gelu_kernel<<<(2048 + 255) / 256, blk, 0, stream>>>(P4, hb4, F4, 2048, 16, 64);

    small_gemm_kernel<true><<<(32 * 32 + 255) / 256, blk, 0, stream>>>(F4, hW5, hb5, F5, 32, 32, 64);
    small_gemm_kernel<false><<<1, blk, 0, stream>>>(F5, bbW, bbb, (float*)d_out, 32, 4, 32);
}

// Round 7
// 1365.117 us; speedup vs baseline: 3.3571x; 1.0114x over previous
//
#include <hip/hip_runtime.h>
#include <cstdint>
#include <cstddef>

#define DEV __device__ __forceinline__

typedef float f32x4 __attribute__((ext_vector_type(4)));
typedef short s16x8 __attribute__((ext_vector_type(8)));

DEV float gelu_f(float x) { return 0.5f * x * (1.0f + erff(x * 0.70710678118654752f)); }

DEV uint32_t fbits(float x) { return __builtin_bit_cast(uint32_t, x); }
DEV float bcast_f(uint32_t u) { return __builtin_bit_cast(float, u); }

// split x into hi (bf16-truncate) and lo (bf16-truncate of residual)
DEV void split_bf16(float x, uint16_t& h, uint16_t& lo) {
    uint32_t xb = fbits(x);
    h = (uint16_t)(xb >> 16);
    float r = x - bcast_f(xb & 0xFFFF0000u);
    lo = (uint16_t)(fbits(r) >> 16);
}

// round-to-nearest-even bf16 (single-plane use)
DEV uint16_t bf16_rne(float x) {
    uint32_t u = fbits(x);
    return (uint16_t)((u + 0x7FFFu + ((u >> 16) & 1u)) >> 16);
}

DEV void gload16(const void* g, void* l) {
    __builtin_amdgcn_global_load_lds(
        (const __attribute__((address_space(1))) uint32_t*)g,
        (__attribute__((address_space(3))) uint32_t*)l, 16, 0, 0);
}

// ---------------------------------------------------------------------------
// Split-bf16 MFMA GEMM.  A-planes [M][K] bf16 hi/lo, B-planes [N][K] bf16
// hi/lo (k-major).  C = A@B^T with fp32 accumulate via 3 MFMA passes.
// 2-phase double-buffered pipeline; XCD-aware block swizzle; LDS-bounce
// epilogue (coalesced stores).  Output modes: fp32 / hi+lo planes / RNE bf16.
// ---------------------------------------------------------------------------
template<int BM, int BN, bool BIAS, bool GELU, bool RES, bool POS,
         bool OUTF32, bool OUTPL, bool OUTB16>
__global__ __launch_bounds__(256)
void mfma_gemm(const uint16_t* __restrict__ Ah, const uint16_t* __restrict__ Al,
               const uint16_t* __restrict__ Bh, const uint16_t* __restrict__ Bl,
               float* __restrict__ C, uint16_t* __restrict__ Chi, uint16_t* __restrict__ Clo,
               const float* __restrict__ bias, const float* __restrict__ res,
               const float* __restrict__ pos, int M, int N, int K)
{
    constexpr int WTM = BM / 2, WTN = BN / 2;
    constexpr int FM = WTM / 16, FN = WTN / 16;
    constexpr int NA = BM / 16, NB = BN / 16;
    constexpr int TI = 2 * NA + 2 * NB;
    constexpr int TI4 = TI / 4;
    constexpr int HALF = (2 * BM + 2 * BN) * 64;
    constexpr int BNP = BN + 4;
    constexpr int SMEM_BYTES = (2 * HALF > BM * BNP * 4) ? 2 * HALF : BM * BNP * 4;

    __shared__ __align__(16) uint8_t smem[SMEM_BYTES];
    constexpr int offAh = 0, offAl = BM * 64, offBh = 2 * BM * 64, offBl = 2 * BM * 64 + BN * 64;

    const int tid = threadIdx.x;
    const int w = tid >> 6, l = tid & 63;
    const int wr = w >> 1, wc = w & 1;

    // XCD-aware bijective swizzle (all grids here are %8 == 0)
    const int gx = gridDim.x;
    const int nwg = gx * gridDim.y;
    const int lin = blockIdx.y * gx + blockIdx.x;
    const int cpx = nwg >> 3;
    const int swz = (lin & 7) * cpx + (lin >> 3);
    const int bxs = swz % gx, bys = swz / gx;
    const int bm0 = bys * BM, bn0 = bxs * BN;
    const size_t sK = (size_t)K * 2;

    const int srow  = l >> 2;
    const int sslot = (l & 3) ^ ((l >> 3) & 3);
    const uint8_t* gsrc[TI4];
    uint32_t loff[TI4];
#pragma unroll
    for (int j = 0; j < TI4; ++j) {
        int f = w * TI4 + j;
        int p = (f < NA) ? 0 : (f < 2 * NA) ? 1 : (f < 2 * NA + NB) ? 2 : 3;
        int c = f - (p == 0 ? 0 : p == 1 ? NA : p == 2 ? 2 * NA : 2 * NA + NB);
        const uint16_t* base = p == 0 ? Ah : p == 1 ? Al : p == 2 ? Bh : Bl;
        int rb = (p < 2) ? bm0 : bn0;
        gsrc[j] = (const uint8_t*)base + (size_t)(rb + c * 16 + srow) * sK + sslot * 16;
        loff[j] = (uint32_t)((p == 0 ? offAh : p == 1 ? offAl : p == 2 ? offBh : offBl) + c * 1024);
    }

    const int lr = l & 15;
    const int sl16 = ((l >> 4) ^ ((lr >> 1) & 3)) * 16;
    const int aofs = (wr * WTM + lr) * 64 + sl16;
    const int bofs = (wc * WTN + lr) * 64 + sl16;

    f32x4 acc[FM][FN];
#pragma unroll
    for (int m = 0; m < FM; ++m)
#pragma unroll
        for (int n = 0; n < FN; ++n) acc[m][n] = (f32x4){0.f, 0.f, 0.f, 0.f};

    {
        const uint8_t* s0 = smem;
#pragma unroll
        for (int j = 0; j < TI4; ++j)
            gload16(gsrc[j], (void*)(s0 + loff[j]));
    }
    asm volatile("s_waitcnt vmcnt(0)" ::: "memory");
    __builtin_amdgcn_s_barrier();

    int cur = 0;
    for (int k0 = 0; k0 < K; k0 += 32) {
        const bool more = (k0 + 32 < K);
        if (more) {
            const size_t kb = (size_t)(k0 + 32) * 2;
            uint8_t* dst = smem + (cur ^ 1) * HALF;
#pragma unroll
            for (int j = 0; j < TI4; ++j)
                gload16(gsrc[j] + kb, dst + loff[j]);
        }
        const uint8_t* sb = smem + cur * HALF;
        s16x8 ah[FM], al[FM], bh[FN], bl[FN];
#pragma unroll
        for (int m = 0; m < FM; ++m) {
            ah[m] = *(const s16x8*)(sb + offAh + aofs + m * 1024);
            al[m] = *(const s16x8*)(sb + offAl + aofs + m * 1024);
        }
#pragma unroll
        for (int n = 0; n < FN; ++n) {
            bh[n] = *(const s16x8*)(sb + offBh + bofs + n * 1024);
            bl[n] = *(const s16x8*)(sb + offBl + bofs + n * 1024);
        }
#pragma unroll
        for (int m = 0; m < FM; ++m)
#pragma unroll
            for (int n = 0; n < FN; ++n)
                acc[m][n] = __builtin_amdgcn_mfma_f32_16x16x32_bf16(ah[m], bh[n], acc[m][n], 0, 0, 0);
#pragma unroll
        for (int m = 0; m < FM; ++m)
#pragma unroll
            for (int n = 0; n < FN; ++n)
                acc[m][n] = __builtin_amdgcn_mfma_f32_16x16x32_bf16(ah[m], bl[n], acc[m][n], 0, 0, 0);
#pragma unroll
        for (int m = 0; m < FM; ++m)
#pragma unroll
            for (int n = 0; n < FN; ++n)
                acc[m][n] = __builtin_amdgcn_mfma_f32_16x16x32_bf16(al[m], bh[n], acc[m][n], 0, 0, 0);

        if (more) {
            asm volatile("s_waitcnt vmcnt(0)" ::: "memory");
            __builtin_amdgcn_s_barrier();
        }
        cur ^= 1;
    }

    // ---- epilogue: bounce acc through LDS for coalesced stores ----
    __syncthreads();
    float* lf = (float*)smem;
    const int r4 = (l >> 4) * 4;
#pragma unroll
    for (int m = 0; m < FM; ++m) {
#pragma unroll
        for (int n = 0; n < FN; ++n) {
            int row = wr * WTM + m * 16 + r4;
            int col = wc * WTN + n * 16 + lr;
#pragma unroll
            for (int r = 0; r < 4; ++r)
                lf[(row + r) * BNP + col] = acc[m][n][r];
        }
    }
    __syncthreads();

    constexpr int C4PR = BN / 4;
    constexpr int RPP  = 256 / C4PR;
    constexpr int NP   = BM / RPP;
    const int rr = tid / C4PR, c4 = tid % C4PR;
    const int nn = bn0 + c4 * 4;

    float4 bv = {0.f, 0.f, 0.f, 0.f};
    if (BIAS) bv = *(const float4*)(bias + nn);

#pragma unroll
    for (int p = 0; p < NP; ++p) {
        int row = p * RPP + rr;
        int mm = bm0 + row;
        float4 v = *(const float4*)&lf[row * BNP + c4 * 4];
        float* vp = &v.x;
        const float* bp = &bv.x;
#pragma unroll
        for (int q = 0; q < 4; ++q) {
            float x = vp[q];
            if (BIAS) x += bp[q];
            if (GELU) x = gelu_f(x);
            vp[q] = x;
        }
        if (RES) {
            float4 rv = *(const float4*)(res + (size_t)mm * N + nn);
            v.x += rv.x; v.y += rv.y; v.z += rv.z; v.w += rv.w;
        }
        if (POS) {
            float4 pv = *(const float4*)(pos + (size_t)(mm & 255) * N + nn);
            v.x += pv.x; v.y += pv.y; v.z += pv.z; v.w += pv.w;
        }
        size_t o = (size_t)mm * N + nn;
        if (OUTF32) *(float4*)(C + o) = v;
        if (OUTB16) {
            ushort4 hh;
            hh.x = bf16_rne(v.x); hh.y = bf16_rne(v.y);
            hh.z = bf16_rne(v.z); hh.w = bf16_rne(v.w);
            *(ushort4*)(Chi + o) = hh;
        }
        if (OUTPL) {
            ushort4 hh, ll;
            uint16_t h, lo;
            split_bf16(v.x, h, lo); hh.x = h; ll.x = lo;
            split_bf16(v.y, h, lo); hh.y = h; ll.y = lo;
            split_bf16(v.z, h, lo); hh.z = h; ll.z = lo;
            split_bf16(v.w, h, lo); hh.w = h; ll.w = lo;
            *(ushort4*)(Chi + o) = hh;
            *(ushort4*)(Clo + o) = ll;
        }
    }
}

// ---------------------------------------------------------------------------
// MFMA flash-style attention over RNE-bf16 QKV [8192][1536] u16.
// One block per (b,h); 4 waves x 64 queries. K/V staged in padded LDS.
// Softmax fp32, no max-subtraction. O emitted as hi/lo planes.
// ---------------------------------------------------------------------------
__global__ __launch_bounds__(256)
void mfma_attn(const uint16_t* __restrict__ QKVb, uint16_t* __restrict__ Oh,
               uint16_t* __restrict__ Ol)
{
    __shared__ __align__(16) uint8_t lds[92160];
    uint8_t* Qs = lds;              // [256][144B]  (64 d x bf16 + pad)
    uint8_t* Ks = lds + 36864;      // [64][144B]
    uint8_t* Vt = lds + 46080;      // [64][144B]   (rows = d, cols = k)
    uint8_t* Ps = lds + 55296;      // [256][144B]  (cols = k-local 64)

    const int tid = threadIdx.x;
    const int w = tid >> 6, l = tid & 63;
    const int lr = l & 15, lg = l >> 4;
    const int bh = blockIdx.x;
    const int b = bh >> 3, h = bh & 7;
    const uint16_t* base = QKVb + (size_t)b * 256 * 1536 + h * 64;
    const int q0 = w * 64;

    // ---- stage Q: thread = token row (bf16 direct copy) ----
    {
        const uint16_t* qp = base + (size_t)tid * 1536;
#pragma unroll
        for (int s = 0; s < 8; ++s)
            *(s16x8*)(Qs + tid * 144 + s * 16) = *(const s16x8*)(qp + s * 8);
    }

    f32x4 oacc[4][4];
    float lrun[4][4];
#pragma unroll
    for (int m = 0; m < 4; ++m)
#pragma unroll
        for (int n = 0; n < 4; ++n) { oacc[m][n] = (f32x4){0.f,0.f,0.f,0.f}; lrun[m][n] = 0.f; }

    for (int kt = 0; kt < 4; ++kt) {
        __syncthreads();   // prev tile reads done; (kt==0: Q writes done)
        // ---- stage K-tile ----
        {
            int r = tid >> 2, sp = (tid & 3) * 2;
            const uint16_t* kp = base + (size_t)(kt * 64 + r) * 1536 + 512;
#pragma unroll
            for (int ss = 0; ss < 2; ++ss) {
                int s = sp + ss;
                *(s16x8*)(Ks + r * 144 + s * 16) = *(const s16x8*)(kp + s * 8);
            }
        }
        // ---- stage Vt-tile transposed ----
        {
            int k = tid & 63, d0 = (tid >> 6) * 16;
            const uint16_t* vp = base + (size_t)(kt * 64 + k) * 1536 + 1024 + d0;
            s16x8 a = *(const s16x8*)(vp);
            s16x8 c = *(const s16x8*)(vp + 8);
#pragma unroll
            for (int i = 0; i < 8; ++i) {
                *(uint16_t*)(Vt + (d0 + i) * 144 + k * 2)     = (uint16_t)a[i];
                *(uint16_t*)(Vt + (d0 + 8 + i) * 144 + k * 2) = (uint16_t)c[i];
            }
        }
        __syncthreads();   // staging visible

        // ---- S = Q K^T over d=64 (2 k-steps) ----
        f32x4 sacc[4][4];
#pragma unroll
        for (int m = 0; m < 4; ++m)
#pragma unroll
            for (int n = 0; n < 4; ++n) sacc[m][n] = (f32x4){0.f,0.f,0.f,0.f};
#pragma unroll
        for (int ks = 0; ks < 2; ++ks) {
            s16x8 qf[4], kf[4];
#pragma unroll
            for (int m = 0; m < 4; ++m)
                qf[m] = *(const s16x8*)(Qs + (q0 + m * 16 + lr) * 144 + ks * 64 + lg * 16);
#pragma unroll
            for (int n = 0; n < 4; ++n)
                kf[n] = *(const s16x8*)(Ks + (n * 16 + lr) * 144 + ks * 64 + lg * 16);
#pragma unroll
            for (int m = 0; m < 4; ++m)
#pragma unroll
                for (int n = 0; n < 4; ++n)
                    sacc[m][n] = __builtin_amdgcn_mfma_f32_16x16x32_bf16(qf[m], kf[n], sacc[m][n], 0, 0, 0);
        }

        // ---- exp + P write + denominator ----
        float dp[4][4];
#pragma unroll
        for (int m = 0; m < 4; ++m)
#pragma unroll
            for (int r = 0; r < 4; ++r) dp[m][r] = 0.f;
#pragma unroll
        for (int m = 0; m < 4; ++m) {
#pragma unroll
            for (int n = 0; n < 4; ++n) {
#pragma unroll
                for (int r = 0; r < 4; ++r) {
                    float e = __expf(sacc[m][n][r] * 0.125f);
                    dp[m][r] += e;
                    int q = q0 + m * 16 + lg * 4 + r;
                    int k = n * 16 + lr;
                    *(uint16_t*)(Ps + q * 144 + k * 2) = bf16_rne(e);
                }
            }
        }
#pragma unroll
        for (int m = 0; m < 4; ++m)
#pragma unroll
            for (int r = 0; r < 4; ++r) {
                float d = dp[m][r];
                d += __shfl_xor(d, 1);
                d += __shfl_xor(d, 2);
                d += __shfl_xor(d, 4);
                d += __shfl_xor(d, 8);
                lrun[m][r] += d;
            }

        asm volatile("s_waitcnt lgkmcnt(0)" ::: "memory");
        __builtin_amdgcn_sched_barrier(0);

        // ---- O += P V ----
#pragma unroll
        for (int ks = 0; ks < 2; ++ks) {
            s16x8 pf[4], vf[4];
#pragma unroll
            for (int m = 0; m < 4; ++m)
                pf[m] = *(const s16x8*)(Ps + (q0 + m * 16 + lr) * 144 + ks * 64 + lg * 16);
#pragma unroll
            for (int n = 0; n < 4; ++n)
                vf[n] = *(const s16x8*)(Vt + (n * 16 + lr) * 144 + ks * 64 + lg * 16);
#pragma unroll
            for (int m = 0; m < 4; ++m)
#pragma unroll
                for (int n = 0; n < 4; ++n)
                    oacc[m][n] = __builtin_amdgcn_mfma_f32_16x16x32_bf16(pf[m], vf[n], oacc[m][n], 0, 0, 0);
        }
    }

    // ---- normalize + bounce to LDS + coalesced hi/lo store ----
    float inv[4][4];
#pragma unroll
    for (int m = 0; m < 4; ++m)
#pragma unroll
        for (int r = 0; r < 4; ++r) inv[m][r] = 1.f / lrun[m][r];

    __syncthreads();
    float* OL = (float*)lds;       // [256][68 f32]
#pragma unroll
    for (int m = 0; m < 4; ++m)
#pragma unroll
        for (int n = 0; n < 4; ++n)
#pragma unroll
            for (int r = 0; r < 4; ++r) {
                int q = q0 + m * 16 + lg * 4 + r;
                int d = n * 16 + lr;
                OL[q * 68 + d] = oacc[m][n][r] * inv[m][r];
            }
    __syncthreads();

#pragma unroll
    for (int pass = 0; pass < 16; ++pass) {
        int q = pass * 16 + (tid >> 4);
        int d4 = tid & 15;
        f32x4 v = *(const f32x4*)(OL + q * 68 + d4 * 4);
        ushort4 hh, ll;
        uint16_t hv, lv;
        split_bf16(v[0], hv, lv); hh.x = hv; ll.x = lv;
        split_bf16(v[1], hv, lv); hh.y = hv; ll.y = lv;
        split_bf16(v[2], hv, lv); hh.z = hv; ll.z = lv;
        split_bf16(v[3], hv, lv); hh.w = hv; ll.w = lv;
        size_t o = (size_t)(b * 256 + q) * 512 + h * 64 + d4 * 4;
        *(ushort4*)(Oh + o) = hh;
        *(ushort4*)(Ol + o) = ll;
    }
}

// ---------------------------------------------------------------------------
// Prep: images -> patch-gathered bf16 hi/lo planes [8192][3072]
// ---------------------------------------------------------------------------
__global__ __launch_bounds__(256)
void img2planes_kernel(const float* __restrict__ img, uint16_t* __restrict__ Ph,
                       uint16_t* __restrict__ Pl)
{
    int idx = blockIdx.x * 256 + threadIdx.x;   // over 8192*768
    if (idx >= 8192 * 768) return;
    int m = idx / 768, q = idx - (idx / 768) * 768;
    int k = q * 4;
    int bb = m >> 8, n = m & 255;
    int ph = k / 96, rem = k - ph * 96;
    int prow = ((n >> 4) << 5) + ph;
    int pcol0 = (n & 15) << 5;
    const float* s = img + (((size_t)bb * 512 + prow) * 512 + pcol0) * 3 + rem;
    float4 v = *(const float4*)s;
    ushort4 hh, ll;
    uint16_t h, lo;
    split_bf16(v.x, h, lo); hh.x = h; ll.x = lo;
    split_bf16(v.y, h, lo); hh.y = h; ll.y = lo;
    split_bf16(v.z, h, lo); hh.z = h; ll.z = lo;
    split_bf16(v.w, h, lo); hh.w = h; ll.w = lo;
    size_t o = (size_t)m * 3072 + k;
    *(ushort4*)(Ph + o) = hh;
    *(ushort4*)(Pl + o) = ll;
}

__global__ __launch_bounds__(256)
void conv_direct_kernel(const float* __restrict__ src, uint16_t* __restrict__ dh,
                        uint16_t* __restrict__ dl, int total4)
{
    int idx = blockIdx.x * 256 + threadIdx.x;
    if (idx >= total4) return;
    float4 v = *(const float4*)(src + (size_t)idx * 4);
    ushort4 hh, ll;
    uint16_t h, lo;
    split_bf16(v.x, h, lo); hh.x = h; ll.x = lo;
    split_bf16(v.y, h, lo); hh.y = h; ll.y = lo;
    split_bf16(v.z, h, lo); hh.z = h; ll.z = lo;
    split_bf16(v.w, h, lo); hh.w = h; ll.w = lo;
    *(ushort4*)(dh + (size_t)idx * 4) = hh;
    *(ushort4*)(dl + (size_t)idx * 4) = ll;
}

__global__ __launch_bounds__(256)
void conv_transpose_kernel(const float* __restrict__ src, uint16_t* __restrict__ dh,
                           uint16_t* __restrict__ dl, int K, int N)
{
    __shared__ float t[32][33];
    int k0 = blockIdx.x * 32, n0 = blockIdx.y * 32;
    const float* s = src + (size_t)blockIdx.z * K * N;
    size_t dbase = (size_t)blockIdx.z * N * K;
    int tid = threadIdx.x;
    {
        int kk = tid / 8, n4 = tid % 8;
        float4 v = *(const float4*)(s + (size_t)(k0 + kk) * N + n0 + n4 * 4);
        t[kk][n4 * 4 + 0] = v.x; t[kk][n4 * 4 + 1] = v.y;
        t[kk][n4 * 4 + 2] = v.z; t[kk][n4 * 4 + 3] = v.w;
    }
    __syncthreads();
    int nn = tid / 8, k4 = tid % 8;
    ushort4 hh, ll;
    uint16_t h, lo;
    float x0 = t[k4 * 4 + 0][nn], x1 = t[k4 * 4 + 1][nn], x2 = t[k4 * 4 + 2][nn], x3 = t[k4 * 4 + 3][nn];
    split_bf16(x0, h, lo); hh.x = h; ll.x = lo;
    split_bf16(x1, h, lo); hh.y = h; ll.y = lo;
    split_bf16(x2, h, lo); hh.z = h; ll.z = lo;
    split_bf16(x3, h, lo); hh.w = h; ll.w = lo;
    size_t o = dbase + (size_t)(n0 + nn) * K + k0 + k4 * 4;
    *(ushort4*)(dh + o) = hh;
    *(ushort4*)(dl + o) = ll;
}

// ---------------------------------------------------------------------------
// LayerNorm over rows of 512; optionally emit bf16 hi/lo planes.
// ---------------------------------------------------------------------------
template<bool PLANES>
__global__ __launch_bounds__(256)
void ln_kernel(const float* __restrict__ X, const float* __restrict__ g,
               const float* __restrict__ b, float* __restrict__ Y,
               uint16_t* __restrict__ Yh, uint16_t* __restrict__ Yl, int nrows)
{
    int wave = threadIdx.x >> 6;
    int lane = threadIdx.x & 63;
    int row = blockIdx.x * 4 + wave;
    if (row >= nrows) return;
    const float* x = X + (size_t)row * 512;
    float4 v0 = ((const float4*)x)[lane];
    float4 v1 = ((const float4*)x)[lane + 64];
    float s  = v0.x + v0.y + v0.z + v0.w + v1.x + v1.y + v1.z + v1.w;
    float sq = v0.x*v0.x + v0.y*v0.y + v0.z*v0.z + v0.w*v0.w
             + v1.x*v1.x + v1.y*v1.y + v1.z*v1.z + v1.w*v1.w;
#pragma unroll
    for (int off = 32; off > 0; off >>= 1) {
        s  += __shfl_down(s, off);
        sq += __shfl_down(sq, off);
    }
    s  = __shfl(s, 0);
    sq = __shfl(sq, 0);
    float mean = s * (1.f / 512.f);
    float var  = sq * (1.f / 512.f) - mean * mean;
    float rinv = rsqrtf(var + 1e-6f);
    float4 g0 = ((const float4*)g)[lane], g1 = ((const float4*)g)[lane + 64];
    float4 b0 = ((const float4*)b)[lane], b1 = ((const float4*)b)[lane + 64];
    float4 o0, o1;
    o0.x = (v0.x - mean) * rinv * g0.x + b0.x;
    o0.y = (v0.y - mean) * rinv * g0.y + b0.y;
    o0.z = (v0.z - mean) * rinv * g0.z + b0.z;
    o0.w = (v0.w - mean) * rinv * g0.w + b0.w;
    o1.x = (v1.x - mean) * rinv * g1.x + b1.x;
    o1.y = (v1.y - mean) * rinv * g1.y + b1.y;
    o1.z = (v1.z - mean) * rinv * g1.z + b1.z;
    o1.w = (v1.w - mean) * rinv * g1.w + b1.w;
    if (PLANES) {
        ushort4 hh0, ll0, hh1, ll1;
        uint16_t h, lo;
        split_bf16(o0.x, h, lo); hh0.x = h; ll0.x = lo;
        split_bf16(o0.y, h, lo); hh0.y = h; ll0.y = lo;
        split_bf16(o0.z, h, lo); hh0.z = h; ll0.z = lo;
        split_bf16(o0.w, h, lo); hh0.w = h; ll0.w = lo;
        split_bf16(o1.x, h, lo); hh1.x = h; ll1.x = lo;
        split_bf16(o1.y, h, lo); hh1.y = h; ll1.y = lo;
        split_bf16(o1.z, h, lo); hh1.z = h; ll1.z = lo;
        split_bf16(o1.w, h, lo); hh1.w = h; ll1.w = lo;
        size_t base = (size_t)row * 512;
        *(ushort4*)(Yh + base + lane * 4)       = hh0;
        *(ushort4*)(Yl + base + lane * 4)       = ll0;
        *(ushort4*)(Yh + base + 256 + lane * 4) = hh1;
        *(ushort4*)(Yl + base + 256 + lane * 4) = ll1;
    } else {
        float* y = Y + (size_t)row * 512;
        ((float4*)y)[lane]      = o0;
        ((float4*)y)[lane + 64] = o1;
    }
}

// ---------------------------------------------------------------------------
// fp32 tiled GEMM (kept for head layer 1 split-K)
// ---------------------------------------------------------------------------
template<int BM, int BN, int BK, int TM, int TN, bool SPLITK>
__global__ __launch_bounds__(256)
void gemm_kernel(const float* __restrict__ A, const float* __restrict__ B,
                 float* __restrict__ C, int M, int N, int K, int kchunk)
{
    constexpr int TX = BN / TN;
    constexpr int TY = BM / TM;
    static_assert(TX * TY == 256, "bad tile config");
    __shared__ float As[BK][BM + 4];
    __shared__ float Bs[BK][BN + 4];
    const int tid = threadIdx.x;
    const int tx  = tid % TX;
    const int ty  = tid / TX;
    const int bn0 = blockIdx.x * BN;
    const int bm0 = blockIdx.y * BM;
    int kstart = 0, kend = K;
    if (SPLITK) { kstart = blockIdx.z * kchunk; kend = kstart + kchunk; }
    float acc[TM][TN];
#pragma unroll
    for (int i = 0; i < TM; ++i)
#pragma unroll
        for (int j = 0; j < TN; ++j) acc[i][j] = 0.f;
    for (int k0 = kstart; k0 < kend; k0 += BK) {
        __syncthreads();
        constexpr int AV = BM * BK / 4 / 256;
#pragma unroll
        for (int r = 0; r < AV; ++r) {
            int idx = tid + r * 256;
            int k4 = idx % (BK / 4);
            int mm = idx / (BK / 4);
            float4 v = *(const float4*)(A + (size_t)(bm0 + mm) * K + k0 + k4 * 4);
            As[k4 * 4 + 0][mm] = v.x;
            As[k4 * 4 + 1][mm] = v.y;
            As[k4 * 4 + 2][mm] = v.z;
            As[k4 * 4 + 3][mm] = v.w;
        }
        constexpr int BV = BK * BN / 4 / 256;
#pragma unroll
        for (int r = 0; r < BV; ++r) {
            int idx = tid + r * 256;
            int n4 = idx % (BN / 4);
            int kk = idx / (BN / 4);
            float4 v = *(const float4*)(B + (size_t)(k0 + kk) * N + bn0 + n4 * 4);
            *(float4*)&Bs[kk][n4 * 4] = v;
        }
        __syncthreads();
#pragma unroll
        for (int kk = 0; kk < BK; ++kk) {
            float a[TM], b[TN];
#pragma unroll
            for (int i = 0; i < TM; i += 4)
                *(float4*)&a[i] = *(const float4*)&As[kk][ty * TM + i];
#pragma unroll
            for (int j = 0; j < TN; j += 4)
                *(float4*)&b[j] = *(const float4*)&Bs[kk][tx * TN + j];
#pragma unroll
            for (int i = 0; i < TM; ++i)
#pragma unroll
                for (int j = 0; j < TN; ++j)
                    acc[i][j] = fmaf(a[i], b[j], acc[i][j]);
        }
    }
    float* Cb = C;
    if (SPLITK) Cb += (size_t)blockIdx.z * M * N;
#pragma unroll
    for (int i = 0; i < TM; ++i) {
        int m = bm0 + ty * TM + i;
#pragma unroll
        for (int j = 0; j < TN; j += 4) {
            int n = bn0 + tx * TN + j;
            float4 v;
            v.x = acc[i][j + 0]; v.y = acc[i][j + 1];
            v.z = acc[i][j + 2]; v.w = acc[i][j + 3];
            *(float4*)(Cb + (size_t)m * N + n) = v;
        }
    }
}

__global__ __launch_bounds__(256)
void skinny_gemm_kernel(const float* __restrict__ A, const float* __restrict__ B,
                        float* __restrict__ P, int M, int N, int K, int kchunk)
{
    __shared__ float As[32][36];
    const int tid = threadIdx.x;
    const int tx  = tid & 63;
    const int ty  = tid >> 6;
    const int bn0 = blockIdx.x * 64;
    const int kstart = blockIdx.y * kchunk;
    const int kend   = kstart + kchunk;
    float acc[8];
#pragma unroll
    for (int i = 0; i < 8; ++i) acc[i] = 0.f;
    for (int k0 = kstart; k0 < kend; k0 += 32) {
        __syncthreads();
        {
            int row = tid >> 3;
            int k4  = tid & 7;
            float4 v = *(const float4*)(A + (size_t)row * K + k0 + k4 * 4);
            *(float4*)&As[row][k4 * 4] = v;
        }
        __syncthreads();
#pragma unroll 8
        for (int kk = 0; kk < 32; ++kk) {
            float b = B[(size_t)(k0 + kk) * N + bn0 + tx];
#pragma unroll
            for (int i = 0; i < 8; ++i)
                acc[i] = fmaf(As[ty * 8 + i][kk], b, acc[i]);
        }
    }
    float* Pb = P + (size_t)blockIdx.y * M * N;
#pragma unroll
    for (int i = 0; i < 8; ++i)
        Pb[(size_t)(ty * 8 + i) * N + bn0 + tx] = acc[i];
}

__global__ __launch_bounds__(256)
void reduce_gelu_kernel(const float* __restrict__ P, const float* __restrict__ bias,
                        float* __restrict__ Y, int total, int chunks, int N)
{
    int idx = blockIdx.x * 256 + threadIdx.x;
    if (idx >= total) return;
    float s = 0.f;
    for (int c = 0; c < chunks; ++c) s += P[(size_t)c * total + idx];
    s += bias[idx % N];
    Y[idx] = gelu_f(s);
}

template<bool GELU>
__global__ __launch_bounds__(256)
void small_gemm_kernel(const float* __restrict__ A, const float* __restrict__ B,
                       const float* __restrict__ bias, float* __restrict__ C,
                       int M, int N, int K)
{
    int idx = blockIdx.x * 256 + threadIdx.x;
    if (idx >= M * N) return;
    int m = idx / N, n = idx % N;
    const float* a = A + (size_t)m * K;
    float s = 0.f;
    for (int k = 0; k < K; ++k) s = fmaf(a[k], B[(size_t)k * N + n], s);
    s += bias[n];
    if (GELU) s = gelu_f(s);
    C[idx] = s;
}

// ---------------------------------------------------------------------------
extern "C" void kernel_launch(void* const* d_in, const int* in_sizes, int n_in,
                              void* d_out, int out_size, void* d_ws, size_t ws_size,
                              hipStream_t stream)
{
    const float* images     = (const float*)d_in[0];
    const float* W_proj     = (const float*)d_in[1];
    const float* b_proj     = (const float*)d_in[2];
    const float* pos_emb    = (const float*)d_in[3];
    const float* ln1_g      = (const float*)d_in[4];
    const float* ln1_b      = (const float*)d_in[5];
    const float* qkv_w      = (const float*)d_in[6];
    const float* qkv_b      = (const float*)d_in[7];
    const float* attn_out_w = (const float*)d_in[8];
    const float* attn_out_b = (const float*)d_in[9];
    const float* ln2_g      = (const float*)d_in[10];
    const float* ln2_b      = (const float*)d_in[11];
    const float* mlp_w1     = (const float*)d_in[12];
    const float* mlp_b1     = (const float*)d_in[13];
    const float* mlp_w2     = (const float*)d_in[14];
    const float* mlp_b2     = (const float*)d_in[15];
    const float* lnf_g      = (const float*)d_in[16];
    const float* lnf_b      = (const float*)d_in[17];
    const float* hW1 = (const float*)d_in[18];
    const float* hb1 = (const float*)d_in[19];
    const float* hW2 = (const float*)d_in[20];
    const float* hb2 = (const float*)d_in[21];
    const float* hW3 = (const float*)d_in[22];
    const float* hb3 = (const float*)d_in[23];
    const float* hW4 = (const float*)d_in[24];
    const float* hb4 = (const float*)d_in[25];
    const float* hW5 = (const float*)d_in[26];
    const float* hb5 = (const float*)d_in[27];
    const float* bbW = (const float*)d_in[28];
    const float* bbb = (const float*)d_in[29];

    // ---- workspace layout ----
    uint8_t* wsb = (uint8_t*)d_ws;
    size_t off = 0;
    auto alloc = [&](size_t bytes) { uint8_t* p = wsb + off; off += (bytes + 255) & ~(size_t)255; return p; };
    float*    X    = (float*)alloc(8192ull * 512 * 4);
    uint16_t* QKVb = (uint16_t*)alloc(8192ull * 1536 * 2);
    float*    T    = (float*)alloc(8192ull * 512 * 4);
    uint16_t* Xh   = (uint16_t*)alloc(8192ull * 512 * 2);
    uint16_t* Xl   = (uint16_t*)alloc(8192ull * 512 * 2);
    uint16_t* Ohp  = (uint16_t*)alloc(8192ull * 512 * 2);
    uint16_t* Olp  = (uint16_t*)alloc(8192ull * 512 * 2);
    uint16_t* Hh   = (uint16_t*)alloc(8192ull * 1024 * 2);
    uint16_t* Hl   = (uint16_t*)alloc(8192ull * 1024 * 2);
    uint16_t* Ph   = (uint16_t*)alloc(8192ull * 3072 * 2);
    uint16_t* Pl   = (uint16_t*)alloc(8192ull * 3072 * 2);
    uint16_t* WqH  = (uint16_t*)alloc(4ull * 1536 * 512 * 2);
    uint16_t* WqL  = (uint16_t*)alloc(4ull * 1536 * 512 * 2);
    uint16_t* WaH  = (uint16_t*)alloc(4ull * 512 * 512 * 2);
    uint16_t* WaL  = (uint16_t*)alloc(4ull * 512 * 512 * 2);
    uint16_t* WpH  = (uint16_t*)alloc(512ull * 3072 * 2);
    uint16_t* WpL  = (uint16_t*)alloc(512ull * 3072 * 2);
    uint16_t* W1H  = (uint16_t*)alloc(4ull * 1024 * 512 * 2);
    uint16_t* W1L  = (uint16_t*)alloc(4ull * 1024 * 512 * 2);
    uint16_t* W2H  = (uint16_t*)alloc(4ull * 512 * 1024 * 2);
    uint16_t* W2L  = (uint16_t*)alloc(4ull * 512 * 1024 * 2);
    float*    F1p  = (float*)alloc(128ull * 65536 * 4);
    float*    F1   = (float*)alloc(65536ull * 4);
    float*    P2   = (float*)alloc(64ull * 32768 * 4);
    float*    F2   = (float*)alloc(32768ull * 4);
    float*    P3   = (float*)alloc(32ull * 16384 * 4);
    float*    F3   = (float*)alloc(16384ull * 4);
    float*    P4   = (float*)alloc(16ull * 2048 * 4);
    float*    F4   = (float*)alloc(2048ull * 4);
    float*    F5   = (float*)alloc(1024ull * 4);

    dim3 blk(256);

    // ---- prep: convert weights + images to bf16 hi/lo planes ----
    img2planes_kernel<<<(8192 * 768 + 255) / 256, blk, 0, stream>>>(images, Ph, Pl);
    conv_direct_kernel<<<(4 * 1536 * 512 / 4 + 255) / 256, blk, 0, stream>>>(qkv_w, WqH, WqL, 4 * 1536 * 512 / 4);
    conv_direct_kernel<<<(4 * 512 * 512 / 4 + 255) / 256, blk, 0, stream>>>(attn_out_w, WaH, WaL, 4 * 512 * 512 / 4);
    conv_transpose_kernel<<<dim3(3072 / 32, 512 / 32, 1), blk, 0, stream>>>(W_proj, WpH, WpL, 3072, 512);
    conv_transpose_kernel<<<dim3(512 / 32, 1024 / 32, 4), blk, 0, stream>>>(mlp_w1, W1H, W1L, 512, 1024);
    conv_transpose_kernel<<<dim3(1024 / 32, 512 / 32, 4), blk, 0, stream>>>(mlp_w2, W2H, W2L, 1024, 512);

    // ---- patch embed: X = patches @ W_proj + b_proj + pos ----
    mfma_gemm<64, 128, true, false, false, true, true, false, false>
        <<<dim3(512 / 128, 8192 / 64), blk, 0, stream>>>(
            Ph, Pl, WpH, WpL, X, nullptr, nullptr, b_proj, nullptr, pos_emb, 8192, 512, 3072);

    for (int l = 0; l < 4; ++l) {
        ln_kernel<true><<<2048, blk, 0, stream>>>(X, ln1_g + l * 512, ln1_b + l * 512,
                                                  nullptr, Xh, Xl, 8192);
        // qkv -> RNE bf16 (attn consumes bf16 directly)
        mfma_gemm<128, 128, true, false, false, false, false, false, true>
            <<<dim3(1536 / 128, 8192 / 128), blk, 0, stream>>>(
                Xh, Xl, WqH + (size_t)l * 1536 * 512, WqL + (size_t)l * 1536 * 512,
                nullptr, QKVb, nullptr, qkv_b + l * 1536, nullptr, nullptr, 8192, 1536, 512);
        mfma_attn<<<256, blk, 0, stream>>>(QKVb, Ohp, Olp);
        mfma_gemm<64, 128, true, false, true, false, true, false, false>
            <<<dim3(512 / 128, 8192 / 64), blk, 0, stream>>>(
                Ohp, Olp, WaH + (size_t)l * 512 * 512, WaL + (size_t)l * 512 * 512,
                X, nullptr, nullptr, attn_out_b + l * 512, X, nullptr, 8192, 512, 512);
        ln_kernel<true><<<2048, blk, 0, stream>>>(X, ln2_g + l * 512, ln2_b + l * 512,
                                                  nullptr, Xh, Xl, 8192);
        mfma_gemm<128, 128, true, true, false, false, false, true, false>
            <<<dim3(1024 / 128, 8192 / 128), blk, 0, stream>>>(
                Xh, Xl, W1H + (size_t)l * 1024 * 512, W1L + (size_t)l * 1024 * 512,
                nullptr, Hh, Hl, mlp_b1 + l * 1024, nullptr, nullptr, 8192, 1024, 512);
        mfma_gemm<64, 128, true, true, true, false, true, false, false>
            <<<dim3(512 / 128, 8192 / 64), blk, 0, stream>>>(
                Hh, Hl, W2H + (size_t)l * 512 * 1024, W2L + (size_t)l * 512 * 1024,
                X, nullptr, nullptr, mlp_b2 + l * 512, X, nullptr, 8192, 512, 1024);
    }

    // ---- final LN -> fp32 T ([32, 131072]) ----
    ln_kernel<false><<<2048, blk, 0, stream>>>(X, lnf_g, lnf_b, T, nullptr, nullptr, 8192);

    // ---- MLP head ----
    gemm_kernel<32, 128, 32, 4, 4, true>
        <<<dim3(2048 / 128, 1, 128), blk, 0, stream>>>(
            T, hW1, F1p, 32, 2048, 131072, 131072 / 128);
    reduce_gelu_kernel<<<(65536 + 255) / 256, blk, 0, stream>>>(F1p, hb1, F1, 65536, 128, 2048);

    skinny_gemm_kernel<<<dim3(1024 / 64, 2048 / 32), blk, 0, stream>>>(F1, hW2, P2, 32, 1024, 2048, 32);
    reduce_gelu_kernel<<<(32768 + 255) / 256, blk, 0, stream>>>(P2, hb2, F2, 32768, 64, 1024);

    skinny_gemm_kernel<<<dim3(512 / 64, 1024 / 32), blk, 0, stream>>>(F2, hW3, P3, 32, 512, 1024, 32);
    reduce_gelu_kernel<<<(16384 + 255) / 256, blk, 0, stream>>>(P3, hb3, F3, 16384, 32, 512);

    skinny_gemm_kernel<<<dim3(64 / 64, 512 / 32), blk, 0, stream>>>(F3, hW4, P4, 32, 64, 512, 32);
    reduce_gelu_kernel<<<(2048 + 255) / 256, blk, 0, stream>>>(P4, hb4, F4, 2048, 16, 64);

    small_gemm_kernel<true><<<(32 * 32 + 255) / 256, blk, 0, stream>>>(F4, hW5, hb5, F5, 32, 32, 64);
    small_gemm_kernel<false><<<1, blk, 0, stream>>>(F5, bbW, bbb, (float*)d_out, 32, 4, 32);
}

// Round 8
// 1059.599 us; speedup vs baseline: 4.3251x; 1.2883x over previous
//
#include <hip/hip_runtime.h>
#include <cstdint>
#include <cstddef>

#define DEV __device__ __forceinline__

typedef float f32x4 __attribute__((ext_vector_type(4)));
typedef short s16x8 __attribute__((ext_vector_type(8)));

DEV float gelu_f(float x) { return 0.5f * x * (1.0f + erff(x * 0.70710678118654752f)); }

DEV uint32_t fbits(float x) { return __builtin_bit_cast(uint32_t, x); }

// round-to-nearest-even bf16
DEV uint16_t bf16_rne(float x) {
    uint32_t u = fbits(x);
    return (uint16_t)((u + 0x7FFFu + ((u >> 16) & 1u)) >> 16);
}

DEV void gload16(const void* g, void* l) {
    __builtin_amdgcn_global_load_lds(
        (const __attribute__((address_space(1))) uint32_t*)g,
        (__attribute__((address_space(3))) uint32_t*)l, 16, 0, 0);
}

// ---------------------------------------------------------------------------
// 1-pass bf16 MFMA GEMM.  A [M][K] bf16 (RNE), B [N][K] bf16 (RNE, k-major).
// C = A@B^T, fp32 accumulate.  2-phase double-buffered global_load_lds
// pipeline; XCD-aware block swizzle; LDS-bounce epilogue (coalesced stores).
// Output: fp32 and/or RNE bf16.
// ---------------------------------------------------------------------------
template<int BM, int BN, bool BIAS, bool GELU, bool RES, bool POS,
         bool OUTF32, bool OUTB16>
__global__ __launch_bounds__(256)
void mfma_gemm(const uint16_t* __restrict__ Ah, const uint16_t* __restrict__ Bh,
               float* __restrict__ C, uint16_t* __restrict__ Cb,
               const float* __restrict__ bias, const float* __restrict__ res,
               const float* __restrict__ pos, int M, int N, int K)
{
    constexpr int WTM = BM / 2, WTN = BN / 2;
    constexpr int FM = WTM / 16, FN = WTN / 16;
    constexpr int NA = BM / 16, NB = BN / 16;      // 1KB chunks per plane
    constexpr int TI = NA + NB;                    // gloads per K-step
    constexpr int TI4 = TI / 4;                    // per wave
    constexpr int HALF = (BM + BN) * 64;           // bytes per K-step
    constexpr int BNP = BN + 4;
    constexpr int SMEM_BYTES = (2 * HALF > BM * BNP * 4) ? 2 * HALF : BM * BNP * 4;

    __shared__ __align__(16) uint8_t smem[SMEM_BYTES];
    constexpr int offB = BM * 64;

    const int tid = threadIdx.x;
    const int w = tid >> 6, l = tid & 63;
    const int wr = w >> 1, wc = w & 1;

    // XCD-aware bijective swizzle (all grids here are %8 == 0)
    const int gx = gridDim.x;
    const int nwg = gx * gridDim.y;
    const int lin = blockIdx.y * gx + blockIdx.x;
    const int cpx = nwg >> 3;
    const int swz = (lin & 7) * cpx + (lin >> 3);
    const int bxs = swz % gx, bys = swz / gx;
    const int bm0 = bys * BM, bn0 = bxs * BN;
    const size_t sK = (size_t)K * 2;

    const int srow  = l >> 2;
    const int sslot = (l & 3) ^ ((l >> 3) & 3);
    const uint8_t* gsrc[TI4];
    uint32_t loff[TI4];
#pragma unroll
    for (int j = 0; j < TI4; ++j) {
        int f = w * TI4 + j;
        int p = (f < NA) ? 0 : 1;
        int c = p ? (f - NA) : f;
        const uint16_t* base = p ? Bh : Ah;
        int rb = p ? bn0 : bm0;
        gsrc[j] = (const uint8_t*)base + (size_t)(rb + c * 16 + srow) * sK + sslot * 16;
        loff[j] = (uint32_t)((p ? offB : 0) + c * 1024);
    }

    const int lr = l & 15;
    const int sl16 = ((l >> 4) ^ ((lr >> 1) & 3)) * 16;
    const int aofs = (wr * WTM + lr) * 64 + sl16;
    const int bofs = (wc * WTN + lr) * 64 + sl16;

    f32x4 acc[FM][FN];
#pragma unroll
    for (int m = 0; m < FM; ++m)
#pragma unroll
        for (int n = 0; n < FN; ++n) acc[m][n] = (f32x4){0.f, 0.f, 0.f, 0.f};

    {
        const uint8_t* s0 = smem;
#pragma unroll
        for (int j = 0; j < TI4; ++j)
            gload16(gsrc[j], (void*)(s0 + loff[j]));
    }
    asm volatile("s_waitcnt vmcnt(0)" ::: "memory");
    __builtin_amdgcn_s_barrier();

    int cur = 0;
    for (int k0 = 0; k0 < K; k0 += 32) {
        const bool more = (k0 + 32 < K);
        if (more) {
            const size_t kb = (size_t)(k0 + 32) * 2;
            uint8_t* dst = smem + (cur ^ 1) * HALF;
#pragma unroll
            for (int j = 0; j < TI4; ++j)
                gload16(gsrc[j] + kb, dst + loff[j]);
        }
        const uint8_t* sb = smem + cur * HALF;
        s16x8 af[FM], bf[FN];
#pragma unroll
        for (int m = 0; m < FM; ++m)
            af[m] = *(const s16x8*)(sb + aofs + m * 1024);
#pragma unroll
        for (int n = 0; n < FN; ++n)
            bf[n] = *(const s16x8*)(sb + offB + bofs + n * 1024);
#pragma unroll
        for (int m = 0; m < FM; ++m)
#pragma unroll
            for (int n = 0; n < FN; ++n)
                acc[m][n] = __builtin_amdgcn_mfma_f32_16x16x32_bf16(af[m], bf[n], acc[m][n], 0, 0, 0);

        if (more) {
            asm volatile("s_waitcnt vmcnt(0)" ::: "memory");
            __builtin_amdgcn_s_barrier();
        }
        cur ^= 1;
    }

    // ---- epilogue: bounce acc through LDS for coalesced stores ----
    __syncthreads();
    float* lf = (float*)smem;
    const int r4 = (l >> 4) * 4;
#pragma unroll
    for (int m = 0; m < FM; ++m) {
#pragma unroll
        for (int n = 0; n < FN; ++n) {
            int row = wr * WTM + m * 16 + r4;
            int col = wc * WTN + n * 16 + lr;
#pragma unroll
            for (int r = 0; r < 4; ++r)
                lf[(row + r) * BNP + col] = acc[m][n][r];
        }
    }
    __syncthreads();

    constexpr int C4PR = BN / 4;
    constexpr int RPP  = 256 / C4PR;
    constexpr int NP   = BM / RPP;
    const int rr = tid / C4PR, c4 = tid % C4PR;
    const int nn = bn0 + c4 * 4;

    float4 bv = {0.f, 0.f, 0.f, 0.f};
    if (BIAS) bv = *(const float4*)(bias + nn);

#pragma unroll
    for (int p = 0; p < NP; ++p) {
        int row = p * RPP + rr;
        int mm = bm0 + row;
        float4 v = *(const float4*)&lf[row * BNP + c4 * 4];
        float* vp = &v.x;
        const float* bp = &bv.x;
#pragma unroll
        for (int q = 0; q < 4; ++q) {
            float x = vp[q];
            if (BIAS) x += bp[q];
            if (GELU) x = gelu_f(x);
            vp[q] = x;
        }
        if (RES) {
            float4 rv = *(const float4*)(res + (size_t)mm * N + nn);
            v.x += rv.x; v.y += rv.y; v.z += rv.z; v.w += rv.w;
        }
        if (POS) {
            float4 pv = *(const float4*)(pos + (size_t)(mm & 255) * N + nn);
            v.x += pv.x; v.y += pv.y; v.z += pv.z; v.w += pv.w;
        }
        size_t o = (size_t)mm * N + nn;
        if (OUTF32) *(float4*)(C + o) = v;
        if (OUTB16) {
            ushort4 hh;
            hh.x = bf16_rne(v.x); hh.y = bf16_rne(v.y);
            hh.z = bf16_rne(v.z); hh.w = bf16_rne(v.w);
            *(ushort4*)(Cb + o) = hh;
        }
    }
}

// ---------------------------------------------------------------------------
// MFMA flash-style attention over RNE-bf16 QKV [8192][1536] u16.
// One block per (b,h); 4 waves x 64 queries. K/V staged in padded LDS.
// Softmax fp32, no max-subtraction. O emitted as RNE bf16.
// ---------------------------------------------------------------------------
__global__ __launch_bounds__(256)
void mfma_attn(const uint16_t* __restrict__ QKVb, uint16_t* __restrict__ Oh)
{
    __shared__ __align__(16) uint8_t lds[92160];
    uint8_t* Qs = lds;              // [256][144B]
    uint8_t* Ks = lds + 36864;      // [64][144B]
    uint8_t* Vt = lds + 46080;      // [64][144B]   (rows = d, cols = k)
    uint8_t* Ps = lds + 55296;      // [256][144B]

    const int tid = threadIdx.x;
    const int w = tid >> 6, l = tid & 63;
    const int lr = l & 15, lg = l >> 4;
    const int bh = blockIdx.x;
    const int b = bh >> 3, h = bh & 7;
    const uint16_t* base = QKVb + (size_t)b * 256 * 1536 + h * 64;
    const int q0 = w * 64;

    {
        const uint16_t* qp = base + (size_t)tid * 1536;
#pragma unroll
        for (int s = 0; s < 8; ++s)
            *(s16x8*)(Qs + tid * 144 + s * 16) = *(const s16x8*)(qp + s * 8);
    }

    f32x4 oacc[4][4];
    float lrun[4][4];
#pragma unroll
    for (int m = 0; m < 4; ++m)
#pragma unroll
        for (int n = 0; n < 4; ++n) { oacc[m][n] = (f32x4){0.f,0.f,0.f,0.f}; lrun[m][n] = 0.f; }

    for (int kt = 0; kt < 4; ++kt) {
        __syncthreads();
        {
            int r = tid >> 2, sp = (tid & 3) * 2;
            const uint16_t* kp = base + (size_t)(kt * 64 + r) * 1536 + 512;
#pragma unroll
            for (int ss = 0; ss < 2; ++ss) {
                int s = sp + ss;
                *(s16x8*)(Ks + r * 144 + s * 16) = *(const s16x8*)(kp + s * 8);
            }
        }
        {
            int k = tid & 63, d0 = (tid >> 6) * 16;
            const uint16_t* vp = base + (size_t)(kt * 64 + k) * 1536 + 1024 + d0;
            s16x8 a = *(const s16x8*)(vp);
            s16x8 c = *(const s16x8*)(vp + 8);
#pragma unroll
            for (int i = 0; i < 8; ++i) {
                *(uint16_t*)(Vt + (d0 + i) * 144 + k * 2)     = (uint16_t)a[i];
                *(uint16_t*)(Vt + (d0 + 8 + i) * 144 + k * 2) = (uint16_t)c[i];
            }
        }
        __syncthreads();

        // ---- S = Q K^T ----
        f32x4 sacc[4][4];
#pragma unroll
        for (int m = 0; m < 4; ++m)
#pragma unroll
            for (int n = 0; n < 4; ++n) sacc[m][n] = (f32x4){0.f,0.f,0.f,0.f};
#pragma unroll
        for (int ks = 0; ks < 2; ++ks) {
            s16x8 qf[4], kf[4];
#pragma unroll
            for (int m = 0; m < 4; ++m)
                qf[m] = *(const s16x8*)(Qs + (q0 + m * 16 + lr) * 144 + ks * 64 + lg * 16);
#pragma unroll
            for (int n = 0; n < 4; ++n)
                kf[n] = *(const s16x8*)(Ks + (n * 16 + lr) * 144 + ks * 64 + lg * 16);
#pragma unroll
            for (int m = 0; m < 4; ++m)
#pragma unroll
                for (int n = 0; n < 4; ++n)
                    sacc[m][n] = __builtin_amdgcn_mfma_f32_16x16x32_bf16(qf[m], kf[n], sacc[m][n], 0, 0, 0);
        }

        // ---- exp + P write + denominator ----
        float dp[4][4];
#pragma unroll
        for (int m = 0; m < 4; ++m)
#pragma unroll
            for (int r = 0; r < 4; ++r) dp[m][r] = 0.f;
#pragma unroll
        for (int m = 0; m < 4; ++m) {
#pragma unroll
            for (int n = 0; n < 4; ++n) {
#pragma unroll
                for (int r = 0; r < 4; ++r) {
                    float e = __expf(sacc[m][n][r] * 0.125f);
                    dp[m][r] += e;
                    int q = q0 + m * 16 + lg * 4 + r;
                    int k = n * 16 + lr;
                    *(uint16_t*)(Ps + q * 144 + k * 2) = bf16_rne(e);
                }
            }
        }
#pragma unroll
        for (int m = 0; m < 4; ++m)
#pragma unroll
            for (int r = 0; r < 4; ++r) {
                float d = dp[m][r];
                d += __shfl_xor(d, 1);
                d += __shfl_xor(d, 2);
                d += __shfl_xor(d, 4);
                d += __shfl_xor(d, 8);
                lrun[m][r] += d;
            }

        asm volatile("s_waitcnt lgkmcnt(0)" ::: "memory");
        __builtin_amdgcn_sched_barrier(0);

        // ---- O += P V ----
#pragma unroll
        for (int ks = 0; ks < 2; ++ks) {
            s16x8 pf[4], vf[4];
#pragma unroll
            for (int m = 0; m < 4; ++m)
                pf[m] = *(const s16x8*)(Ps + (q0 + m * 16 + lr) * 144 + ks * 64 + lg * 16);
#pragma unroll
            for (int n = 0; n < 4; ++n)
                vf[n] = *(const s16x8*)(Vt + (n * 16 + lr) * 144 + ks * 64 + lg * 16);
#pragma unroll
            for (int m = 0; m < 4; ++m)
#pragma unroll
                for (int n = 0; n < 4; ++n)
                    oacc[m][n] = __builtin_amdgcn_mfma_f32_16x16x32_bf16(pf[m], vf[n], oacc[m][n], 0, 0, 0);
        }
    }

    // ---- normalize + bounce to LDS + coalesced store ----
    float inv[4][4];
#pragma unroll
    for (int m = 0; m < 4; ++m)
#pragma unroll
        for (int r = 0; r < 4; ++r) inv[m][r] = 1.f / lrun[m][r];

    __syncthreads();
    float* OL = (float*)lds;       // [256][68 f32]
#pragma unroll
    for (int m = 0; m < 4; ++m)
#pragma unroll
        for (int n = 0; n < 4; ++n)
#pragma unroll
            for (int r = 0; r < 4; ++r) {
                int q = q0 + m * 16 + lg * 4 + r;
                int d = n * 16 + lr;
                OL[q * 68 + d] = oacc[m][n][r] * inv[m][r];
            }
    __syncthreads();

#pragma unroll
    for (int pass = 0; pass < 16; ++pass) {
        int q = pass * 16 + (tid >> 4);
        int d4 = tid & 15;
        f32x4 v = *(const f32x4*)(OL + q * 68 + d4 * 4);
        ushort4 hh;
        hh.x = bf16_rne(v[0]); hh.y = bf16_rne(v[1]);
        hh.z = bf16_rne(v[2]); hh.w = bf16_rne(v[3]);
        size_t o = (size_t)(b * 256 + q) * 512 + h * 64 + d4 * 4;
        *(ushort4*)(Oh + o) = hh;
    }
}

// ---------------------------------------------------------------------------
// Prep: images -> patch-gathered RNE bf16 [8192][3072]
// ---------------------------------------------------------------------------
__global__ __launch_bounds__(256)
void img2planes_kernel(const float* __restrict__ img, uint16_t* __restrict__ Ph)
{
    int idx = blockIdx.x * 256 + threadIdx.x;   // over 8192*768
    if (idx >= 8192 * 768) return;
    int m = idx / 768, q = idx - (idx / 768) * 768;
    int k = q * 4;
    int bb = m >> 8, n = m & 255;
    int ph = k / 96, rem = k - ph * 96;
    int prow = ((n >> 4) << 5) + ph;
    int pcol0 = (n & 15) << 5;
    const float* s = img + (((size_t)bb * 512 + prow) * 512 + pcol0) * 3 + rem;
    float4 v = *(const float4*)s;
    ushort4 hh;
    hh.x = bf16_rne(v.x); hh.y = bf16_rne(v.y);
    hh.z = bf16_rne(v.z); hh.w = bf16_rne(v.w);
    *(ushort4*)(Ph + (size_t)m * 3072 + k) = hh;
}

__global__ __launch_bounds__(256)
void conv_direct_kernel(const float* __restrict__ src, uint16_t* __restrict__ dh, int total4)
{
    int idx = blockIdx.x * 256 + threadIdx.x;
    if (idx >= total4) return;
    float4 v = *(const float4*)(src + (size_t)idx * 4);
    ushort4 hh;
    hh.x = bf16_rne(v.x); hh.y = bf16_rne(v.y);
    hh.z = bf16_rne(v.z); hh.w = bf16_rne(v.w);
    *(ushort4*)(dh + (size_t)idx * 4) = hh;
}

__global__ __launch_bounds__(256)
void conv_transpose_kernel(const float* __restrict__ src, uint16_t* __restrict__ dh,
                           int K, int N)
{
    __shared__ float t[32][33];
    int k0 = blockIdx.x * 32, n0 = blockIdx.y * 32;
    const float* s = src + (size_t)blockIdx.z * K * N;
    size_t dbase = (size_t)blockIdx.z * N * K;
    int tid = threadIdx.x;
    {
        int kk = tid / 8, n4 = tid % 8;
        float4 v = *(const float4*)(s + (size_t)(k0 + kk) * N + n0 + n4 * 4);
        t[kk][n4 * 4 + 0] = v.x; t[kk][n4 * 4 + 1] = v.y;
        t[kk][n4 * 4 + 2] = v.z; t[kk][n4 * 4 + 3] = v.w;
    }
    __syncthreads();
    int nn = tid / 8, k4 = tid % 8;
    ushort4 hh;
    hh.x = bf16_rne(t[k4 * 4 + 0][nn]);
    hh.y = bf16_rne(t[k4 * 4 + 1][nn]);
    hh.z = bf16_rne(t[k4 * 4 + 2][nn]);
    hh.w = bf16_rne(t[k4 * 4 + 3][nn]);
    *(ushort4*)(dh + dbase + (size_t)(n0 + nn) * K + k0 + k4 * 4) = hh;
}

// ---------------------------------------------------------------------------
// LayerNorm over rows of 512; optionally emit RNE bf16.
// ---------------------------------------------------------------------------
template<bool PLANES>
__global__ __launch_bounds__(256)
void ln_kernel(const float* __restrict__ X, const float* __restrict__ g,
               const float* __restrict__ b, float* __restrict__ Y,
               uint16_t* __restrict__ Yh, int nrows)
{
    int wave = threadIdx.x >> 6;
    int lane = threadIdx.x & 63;
    int row = blockIdx.x * 4 + wave;
    if (row >= nrows) return;
    const float* x = X + (size_t)row * 512;
    float4 v0 = ((const float4*)x)[lane];
    float4 v1 = ((const float4*)x)[lane + 64];
    float s  = v0.x + v0.y + v0.z + v0.w + v1.x + v1.y + v1.z + v1.w;
    float sq = v0.x*v0.x + v0.y*v0.y + v0.z*v0.z + v0.w*v0.w
             + v1.x*v1.x + v1.y*v1.y + v1.z*v1.z + v1.w*v1.w;
#pragma unroll
    for (int off = 32; off > 0; off >>= 1) {
        s  += __shfl_down(s, off);
        sq += __shfl_down(sq, off);
    }
    s  = __shfl(s, 0);
    sq = __shfl(sq, 0);
    float mean = s * (1.f / 512.f);
    float var  = sq * (1.f / 512.f) - mean * mean;
    float rinv = rsqrtf(var + 1e-6f);
    float4 g0 = ((const float4*)g)[lane], g1 = ((const float4*)g)[lane + 64];
    float4 b0 = ((const float4*)b)[lane], b1 = ((const float4*)b)[lane + 64];
    float4 o0, o1;
    o0.x = (v0.x - mean) * rinv * g0.x + b0.x;
    o0.y = (v0.y - mean) * rinv * g0.y + b0.y;
    o0.z = (v0.z - mean) * rinv * g0.z + b0.z;
    o0.w = (v0.w - mean) * rinv * g0.w + b0.w;
    o1.x = (v1.x - mean) * rinv * g1.x + b1.x;
    o1.y = (v1.y - mean) * rinv * g1.y + b1.y;
    o1.z = (v1.z - mean) * rinv * g1.z + b1.z;
    o1.w = (v1.w - mean) * rinv * g1.w + b1.w;
    if (PLANES) {
        ushort4 hh0, hh1;
        hh0.x = bf16_rne(o0.x); hh0.y = bf16_rne(o0.y);
        hh0.z = bf16_rne(o0.z); hh0.w = bf16_rne(o0.w);
        hh1.x = bf16_rne(o1.x); hh1.y = bf16_rne(o1.y);
        hh1.z = bf16_rne(o1.z); hh1.w = bf16_rne(o1.w);
        size_t base = (size_t)row * 512;
        *(ushort4*)(Yh + base + lane * 4)       = hh0;
        *(ushort4*)(Yh + base + 256 + lane * 4) = hh1;
    } else {
        float* y = Y + (size_t)row * 512;
        ((float4*)y)[lane]      = o0;
        ((float4*)y)[lane + 64] = o1;
    }
}

// ---------------------------------------------------------------------------
// fp32 tiled GEMM (head layer 1 split-K)
// ---------------------------------------------------------------------------
template<int BM, int BN, int BK, int TM, int TN, bool SPLITK>
__global__ __launch_bounds__(256)
void gemm_kernel(const float* __restrict__ A, const float* __restrict__ B,
                 float* __restrict__ C, int M, int N, int K, int kchunk)
{
    constexpr int TX = BN / TN;
    constexpr int TY = BM / TM;
    static_assert(TX * TY == 256, "bad tile config");
    __shared__ float As[BK][BM + 4];
    __shared__ float Bs[BK][BN + 4];
    const int tid = threadIdx.x;
    const int tx  = tid % TX;
    const int ty  = tid / TX;
    const int bn0 = blockIdx.x * BN;
    const int bm0 = blockIdx.y * BM;
    int kstart = 0, kend = K;
    if (SPLITK) { kstart = blockIdx.z * kchunk; kend = kstart + kchunk; }
    float acc[TM][TN];
#pragma unroll
    for (int i = 0; i < TM; ++i)
#pragma unroll
        for (int j = 0; j < TN; ++j) acc[i][j] = 0.f;
    for (int k0 = kstart; k0 < kend; k0 += BK) {
        __syncthreads();
        constexpr int AV = BM * BK / 4 / 256;
#pragma unroll
        for (int r = 0; r < AV; ++r) {
            int idx = tid + r * 256;
            int k4 = idx % (BK / 4);
            int mm = idx / (BK / 4);
            float4 v = *(const float4*)(A + (size_t)(bm0 + mm) * K + k0 + k4 * 4);
            As[k4 * 4 + 0][mm] = v.x;
            As[k4 * 4 + 1][mm] = v.y;
            As[k4 * 4 + 2][mm] = v.z;
            As[k4 * 4 + 3][mm] = v.w;
        }
        constexpr int BV = BK * BN / 4 / 256;
#pragma unroll
        for (int r = 0; r < BV; ++r) {
            int idx = tid + r * 256;
            int n4 = idx % (BN / 4);
            int kk = idx / (BN / 4);
            float4 v = *(const float4*)(B + (size_t)(k0 + kk) * N + bn0 + n4 * 4);
            *(float4*)&Bs[kk][n4 * 4] = v;
        }
        __syncthreads();
#pragma unroll
        for (int kk = 0; kk < BK; ++kk) {
            float a[TM], b[TN];
#pragma unroll
            for (int i = 0; i < TM; i += 4)
                *(float4*)&a[i] = *(const float4*)&As[kk][ty * TM + i];
#pragma unroll
            for (int j = 0; j < TN; j += 4)
                *(float4*)&b[j] = *(const float4*)&Bs[kk][tx * TN + j];
#pragma unroll
            for (int i = 0; i < TM; ++i)
#pragma unroll
                for (int j = 0; j < TN; ++j)
                    acc[i][j] = fmaf(a[i], b[j], acc[i][j]);
        }
    }
    float* Cb = C;
    if (SPLITK) Cb += (size_t)blockIdx.z * M * N;
#pragma unroll
    for (int i = 0; i < TM; ++i) {
        int m = bm0 + ty * TM + i;
#pragma unroll
        for (int j = 0; j < TN; j += 4) {
            int n = bn0 + tx * TN + j;
            float4 v;
            v.x = acc[i][j + 0]; v.y = acc[i][j + 1];
            v.z = acc[i][j + 2]; v.w = acc[i][j + 3];
            *(float4*)(Cb + (size_t)m * N + n) = v;
        }
    }
}

__global__ __launch_bounds__(256)
void skinny_gemm_kernel(const float* __restrict__ A, const float* __restrict__ B,
                        float* __restrict__ P, int M, int N, int K, int kchunk)
{
    __shared__ float As[32][36];
    const int tid = threadIdx.x;
    const int tx  = tid & 63;
    const int ty  = tid >> 6;
    const int bn0 = blockIdx.x * 64;
    const int kstart = blockIdx.y * kchunk;
    const int kend   = kstart + kchunk;
    float acc[8];
#pragma unroll
    for (int i = 0; i < 8; ++i) acc[i] = 0.f;
    for (int k0 = kstart; k0 < kend; k0 += 32) {
        __syncthreads();
        {
            int row = tid >> 3;
            int k4  = tid & 7;
            float4 v = *(const float4*)(A + (size_t)row * K + k0 + k4 * 4);
            *(float4*)&As[row][k4 * 4] = v;
        }
        __syncthreads();
#pragma unroll 8
        for (int kk = 0; kk < 32; ++kk) {
            float b = B[(size_t)(k0 + kk) * N + bn0 + tx];
#pragma unroll
            for (int i = 0; i < 8; ++i)
                acc[i] = fmaf(As[ty * 8 + i][kk], b, acc[i]);
        }
    }
    float* Pb = P + (size_t)blockIdx.y * M * N;
#pragma unroll
    for (int i = 0; i < 8; ++i)
        Pb[(size_t)(ty * 8 + i) * N + bn0 + tx] = acc[i];
}

__global__ __launch_bounds__(256)
void reduce_gelu_kernel(const float* __restrict__ P, const float* __restrict__ bias,
                        float* __restrict__ Y, int total, int chunks, int N)
{
    int idx = blockIdx.x * 256 + threadIdx.x;
    if (idx >= total) return;
    float s = 0.f;
    for (int c = 0; c < chunks; ++c) s += P[(size_t)c * total + idx];
    s += bias[idx % N];
    Y[idx] = gelu_f(s);
}

template<bool GELU>
__global__ __launch_bounds__(256)
void small_gemm_kernel(const float* __restrict__ A, const float* __restrict__ B,
                       const float* __restrict__ bias, float* __restrict__ C,
                       int M, int N, int K)
{
    int idx = blockIdx.x * 256 + threadIdx.x;
    if (idx >= M * N) return;
    int m = idx / N, n = idx % N;
    const float* a = A + (size_t)m * K;
    float s = 0.f;
    for (int k = 0; k < K; ++k) s = fmaf(a[k], B[(size_t)k * N + n], s);
    s += bias[n];
    if (GELU) s = gelu_f(s);
    C[idx] = s;
}

// ---------------------------------------------------------------------------
extern "C" void kernel_launch(void* const* d_in, const int* in_sizes, int n_in,
                              void* d_out, int out_size, void* d_ws, size_t ws_size,
                              hipStream_t stream)
{
    const float* images     = (const float*)d_in[0];
    const float* W_proj     = (const float*)d_in[1];
    const float* b_proj     = (const float*)d_in[2];
    const float* pos_emb    = (const float*)d_in[3];
    const float* ln1_g      = (const float*)d_in[4];
    const float* ln1_b      = (const float*)d_in[5];
    const float* qkv_w      = (const float*)d_in[6];
    const float* qkv_b      = (const float*)d_in[7];
    const float* attn_out_w = (const float*)d_in[8];
    const float* attn_out_b = (const float*)d_in[9];
    const float* ln2_g      = (const float*)d_in[10];
    const float* ln2_b      = (const float*)d_in[11];
    const float* mlp_w1     = (const float*)d_in[12];
    const float* mlp_b1     = (const float*)d_in[13];
    const float* mlp_w2     = (const float*)d_in[14];
    const float* mlp_b2     = (const float*)d_in[15];
    const float* lnf_g      = (const float*)d_in[16];
    const float* lnf_b      = (const float*)d_in[17];
    const float* hW1 = (const float*)d_in[18];
    const float* hb1 = (const float*)d_in[19];
    const float* hW2 = (const float*)d_in[20];
    const float* hb2 = (const float*)d_in[21];
    const float* hW3 = (const float*)d_in[22];
    const float* hb3 = (const float*)d_in[23];
    const float* hW4 = (const float*)d_in[24];
    const float* hb4 = (const float*)d_in[25];
    const float* hW5 = (const float*)d_in[26];
    const float* hb5 = (const float*)d_in[27];
    const float* bbW = (const float*)d_in[28];
    const float* bbb = (const float*)d_in[29];

    // ---- workspace layout ----
    uint8_t* wsb = (uint8_t*)d_ws;
    size_t off = 0;
    auto alloc = [&](size_t bytes) { uint8_t* p = wsb + off; off += (bytes + 255) & ~(size_t)255; return p; };
    float*    X    = (float*)alloc(8192ull * 512 * 4);
    uint16_t* QKVb = (uint16_t*)alloc(8192ull * 1536 * 2);
    float*    T    = (float*)alloc(8192ull * 512 * 4);
    uint16_t* Xh   = (uint16_t*)alloc(8192ull * 512 * 2);
    uint16_t* Ohp  = (uint16_t*)alloc(8192ull * 512 * 2);
    uint16_t* Hh   = (uint16_t*)alloc(8192ull * 1024 * 2);
    uint16_t* Ph   = (uint16_t*)alloc(8192ull * 3072 * 2);
    uint16_t* WqH  = (uint16_t*)alloc(4ull * 1536 * 512 * 2);
    uint16_t* WaH  = (uint16_t*)alloc(4ull * 512 * 512 * 2);
    uint16_t* WpH  = (uint16_t*)alloc(512ull * 3072 * 2);
    uint16_t* W1H  = (uint16_t*)alloc(4ull * 1024 * 512 * 2);
    uint16_t* W2H  = (uint16_t*)alloc(4ull * 512 * 1024 * 2);
    float*    F1p  = (float*)alloc(128ull * 65536 * 4);
    float*    F1   = (float*)alloc(65536ull * 4);
    float*    P2   = (float*)alloc(64ull * 32768 * 4);
    float*    F2   = (float*)alloc(32768ull * 4);
    float*    P3   = (float*)alloc(32ull * 16384 * 4);
    float*    F3   = (float*)alloc(16384ull * 4);
    float*    P4   = (float*)alloc(16ull * 2048 * 4);
    float*    F4   = (float*)alloc(2048ull * 4);
    float*    F5   = (float*)alloc(1024ull * 4);

    dim3 blk(256);

    // ---- prep: convert weights + images to RNE bf16 ----
    img2planes_kernel<<<(8192 * 768 + 255) / 256, blk, 0, stream>>>(images, Ph);
    conv_direct_kernel<<<(4 * 1536 * 512 / 4 + 255) / 256, blk, 0, stream>>>(qkv_w, WqH, 4 * 1536 * 512 / 4);
    conv_direct_kernel<<<(4 * 512 * 512 / 4 + 255) / 256, blk, 0, stream>>>(attn_out_w, WaH, 4 * 512 * 512 / 4);
    conv_transpose_kernel<<<dim3(3072 / 32, 512 / 32, 1), blk, 0, stream>>>(W_proj, WpH, 3072, 512);
    conv_transpose_kernel<<<dim3(512 / 32, 1024 / 32, 4), blk, 0, stream>>>(mlp_w1, W1H, 512, 1024);
    conv_transpose_kernel<<<dim3(1024 / 32, 512 / 32, 4), blk, 0, stream>>>(mlp_w2, W2H, 1024, 512);

    // ---- patch embed: X = patches @ W_proj + b_proj + pos ----
    mfma_gemm<64, 128, true, false, false, true, true, false>
        <<<dim3(512 / 128, 8192 / 64), blk, 0, stream>>>(
            Ph, WpH, X, nullptr, b_proj, nullptr, pos_emb, 8192, 512, 3072);

    for (int l = 0; l < 4; ++l) {
        ln_kernel<true><<<2048, blk, 0, stream>>>(X, ln1_g + l * 512, ln1_b + l * 512,
                                                  nullptr, Xh, 8192);
        // qkv -> RNE bf16
        mfma_gemm<128, 128, true, false, false, false, false, true>
            <<<dim3(1536 / 128, 8192 / 128), blk, 0, stream>>>(
                Xh, WqH + (size_t)l * 1536 * 512, nullptr, QKVb,
                qkv_b + l * 1536, nullptr, nullptr, 8192, 1536, 512);
        mfma_attn<<<256, blk, 0, stream>>>(QKVb, Ohp);
        mfma_gemm<64, 128, true, false, true, false, true, false>
            <<<dim3(512 / 128, 8192 / 64), blk, 0, stream>>>(
                Ohp, WaH + (size_t)l * 512 * 512, X, nullptr,
                attn_out_b + l * 512, X, nullptr, 8192, 512, 512);
        ln_kernel<true><<<2048, blk, 0, stream>>>(X, ln2_g + l * 512, ln2_b + l * 512,
                                                  nullptr, Xh, 8192);
        mfma_gemm<128, 128, true, true, false, false, false, true>
            <<<dim3(1024 / 128, 8192 / 128), blk, 0, stream>>>(
                Xh, W1H + (size_t)l * 1024 * 512, nullptr, Hh,
                mlp_b1 + l * 1024, nullptr, nullptr, 8192, 1024, 512);
        mfma_gemm<64, 128, true, true, true, false, true, false>
            <<<dim3(512 / 128, 8192 / 64), blk, 0, stream>>>(
                Hh, W2H + (size_t)l * 512 * 1024, X, nullptr,
                mlp_b2 + l * 512, X, nullptr, 8192, 512, 1024);
    }

    // ---- final LN -> fp32 T ([32, 131072]) ----
    ln_kernel<false><<<2048, blk, 0, stream>>>(X, lnf_g, lnf_b, T, nullptr, 8192);

    // ---- MLP head ----
    gemm_kernel<32, 128, 32, 4, 4, true>
        <<<dim3(2048 / 128, 1, 128), blk, 0, stream>>>(
            T, hW1, F1p, 32, 2048, 131072, 131072 / 128);
    reduce_gelu_kernel<<<(65536 + 255) / 256, blk, 0, stream>>>(F1p, hb1, F1, 65536, 128, 2048);

    skinny_gemm_kernel<<<dim3(1024 / 64, 2048 / 32), blk, 0, stream>>>(F1, hW2, P2, 32, 1024, 2048, 32);
    reduce_gelu_kernel<<<(32768 + 255) / 256, blk, 0, stream>>>(P2, hb2, F2, 32768, 64, 1024);

    skinny_gemm_kernel<<<dim3(512 / 64, 1024 / 32), blk, 0, stream>>>(F2, hW3, P3, 32, 512, 1024, 32);
    reduce_gelu_kernel<<<(16384 + 255) / 256, blk, 0, stream>>>(P3, hb3, F3, 16384, 32, 512);

    skinny_gemm_kernel<<<dim3(64 / 64, 512 / 32), blk, 0, stream>>>(F3, hW4, P4, 32, 64, 512, 32);
    reduce_gelu_kernel<<<(2048 + 255) / 256, blk, 0, stream>>>(P4, hb4, F4, 2048, 16, 64);

    small_gemm_kernel<true><<<(32 * 32 + 255) / 256, blk, 0, stream>>>(F4, hW5, hb5, F5, 32, 32, 64);
    small_gemm_kernel<false><<<1, blk, 0, stream>>>(F5, bbW, bbb, (float*)d_out, 32, 4, 32);
}